// Round 3
// baseline (3022.280 us; speedup 1.0000x reference)
//
#include <hip/hip_runtime.h>
#include <cstdint>
#include <cstddef>
#include <math.h>

typedef uint16_t u16;
typedef __attribute__((ext_vector_type(8))) short short8;
typedef __attribute__((ext_vector_type(4))) float f32x4;

#define TOK 8192
#define CDIM 768
#define FDIM 3072

#define GLDS16(g, l) __builtin_amdgcn_global_load_lds((const __attribute__((address_space(1))) uint32_t*)(g), (__attribute__((address_space(3))) uint32_t*)(l), 16, 0, 0)

__device__ __forceinline__ u16 f2bf(float f) {
  union { float f; uint32_t u; } v; v.f = f;
  uint32_t u = v.u;
  return (u16)((u + 0x7FFFu + ((u >> 16) & 1u)) >> 16);
}

__device__ __forceinline__ float gelu_exact(float z) {
  return 0.5f * z * (1.0f + erff(z * 0.70710678118654752f));
}

__device__ __forceinline__ float softplus_f(float x) {
  return (x > 0.0f) ? (x + log1pf(expf(-x))) : log1pf(expf(x));
}

__device__ __forceinline__ float block_sum256(float v, float* sm) {
  #pragma unroll
  for (int m = 1; m < 64; m <<= 1) v += __shfl_xor(v, m);
  int w = threadIdx.x >> 6;
  if ((threadIdx.x & 63) == 0) sm[w] = v;
  __syncthreads();
  v = sm[0] + sm[1] + sm[2] + sm[3];
  __syncthreads();
  return v;
}

// ---------------- weight prep ----------------

__global__ __launch_bounds__(256) void pack_qkv(const float* __restrict__ wq,
    const float* __restrict__ wk, const float* __restrict__ wv, float* __restrict__ W) {
  int id = blockIdx.x * 256 + threadIdx.x;
  if (id >= 768 * 2304) return;
  int c = id / 2304, j = id - c * 2304;
  int which = j / 768, jj = j - which * 768;
  int hh = jj >> 6, d = jj & 63;
  const float* src = (which == 0) ? wq : (which == 1 ? wk : wv);
  W[id] = src[((size_t)hh * 768 + c) * 64 + d];
}

// src [K][N] fp32 (per expert via blockIdx.z) -> dst [N][K] bf16
__global__ __launch_bounds__(256) void transpose_cast(const float* __restrict__ src,
    u16* __restrict__ dst, int K, int N) {
  __shared__ float t[32][33];
  size_t eoff = (size_t)blockIdx.z * K * N;
  const float* S = src + eoff;
  u16* D = dst + eoff;
  int n0 = blockIdx.x * 32, k0 = blockIdx.y * 32;
  int tc = threadIdx.x & 31, tr = threadIdx.x >> 5;
  #pragma unroll
  for (int r = tr; r < 32; r += 8) t[r][tc] = S[(size_t)(k0 + r) * N + n0 + tc];
  __syncthreads();
  #pragma unroll
  for (int r = tr; r < 32; r += 8) D[(size_t)(n0 + r) * K + k0 + tc] = f2bf(t[tc][r]);
}

// ---------------- layernorms ----------------

__global__ __launch_bounds__(256) void ln1_k(const float* __restrict__ X,
    const float* __restrict__ g, const float* __restrict__ b, float* __restrict__ Y) {
  __shared__ float sm[4];
  size_t row = blockIdx.x;
  const float* x = X + row * 768;
  int t = threadIdx.x;
  float v0 = x[t], v1 = x[t + 256], v2 = x[t + 512];
  float mean = block_sum256(v0 + v1 + v2, sm) * (1.0f / 768.0f);
  float d0 = v0 - mean, d1 = v1 - mean, d2 = v2 - mean;
  float var = block_sum256(d0 * d0 + d1 * d1 + d2 * d2, sm) * (1.0f / 768.0f);
  float rstd = 1.0f / sqrtf(var + 1e-5f);
  float* y = Y + row * 768;
  y[t]       = d0 * rstd * g[t]       + b[t];
  y[t + 256] = d1 * rstd * g[t + 256] + b[t + 256];
  y[t + 512] = d2 * rstd * g[t + 512] + b[t + 512];
}

__global__ __launch_bounds__(256) void ln2_k(const float* __restrict__ X,
    const float* __restrict__ g, const float* __restrict__ b, float* __restrict__ H2,
    u16* __restrict__ H2b, float* __restrict__ OutInit) {
  __shared__ float sm[4];
  size_t row = blockIdx.x;
  const float* x = X + row * 768;
  int t = threadIdx.x;
  float v0 = x[t], v1 = x[t + 256], v2 = x[t + 512];
  float mean = block_sum256(v0 + v1 + v2, sm) * (1.0f / 768.0f);
  float d0 = v0 - mean, d1 = v1 - mean, d2 = v2 - mean;
  float var = block_sum256(d0 * d0 + d1 * d1 + d2 * d2, sm) * (1.0f / 768.0f);
  float rstd = 1.0f / sqrtf(var + 1e-5f);
  float y0 = d0 * rstd * g[t]       + b[t];
  float y1 = d1 * rstd * g[t + 256] + b[t + 256];
  float y2 = d2 * rstd * g[t + 512] + b[t + 512];
  float* h2r = H2 + row * 768;
  u16* hbr = H2b + row * 768;
  float* outr = OutInit + row * 768;
  h2r[t] = y0; h2r[t + 256] = y1; h2r[t + 512] = y2;
  hbr[t] = f2bf(y0); hbr[t + 256] = f2bf(y1); hbr[t + 512] = f2bf(y2);
  outr[t] = v0; outr[t + 256] = v1; outr[t + 512] = v2;
}

// ---------------- fp32 GEMM (pre-router path; accuracy-critical) ----------------
// A [M,K], Bm [K,N], C [M,N]; optional bias[N] + residual Res [M,N]

template<int BIAS_RES>
__global__ __launch_bounds__(256) void gemm_f32(const float* __restrict__ A,
    const float* __restrict__ Bm, const float* __restrict__ bias,
    const float* __restrict__ Res, float* __restrict__ Cout, int M, int N, int K) {
  __shared__ __align__(16) float As[16 * 132];
  __shared__ __align__(16) float Bs[16 * 128];
  const int tid = threadIdx.x;
  const int m0 = blockIdx.y << 7, n0 = blockIdx.x << 7;
  const int w = tid >> 6, l = tid & 63;
  const int tx = l & 15, ty = l >> 4;
  float acc[8][8] = {};
  const int arow = tid >> 1, ahalf = tid & 1;
  for (int k0 = 0; k0 < K; k0 += 16) {
    {
      const float* ga = A + (size_t)(m0 + arow) * K + k0 + ahalf * 8;
      float4 p0 = *(const float4*)ga;
      float4 p1 = *(const float4*)(ga + 4);
      int kk = ahalf * 8;
      As[(kk + 0) * 132 + arow] = p0.x; As[(kk + 1) * 132 + arow] = p0.y;
      As[(kk + 2) * 132 + arow] = p0.z; As[(kk + 3) * 132 + arow] = p0.w;
      As[(kk + 4) * 132 + arow] = p1.x; As[(kk + 5) * 132 + arow] = p1.y;
      As[(kk + 6) * 132 + arow] = p1.z; As[(kk + 7) * 132 + arow] = p1.w;
      int f = tid; int bk = f >> 5, c4 = (f & 31) << 2;
      *(float4*)&Bs[bk * 128 + c4] = *(const float4*)(Bm + (size_t)(k0 + bk) * N + n0 + c4);
      f = tid + 256; bk = f >> 5; c4 = (f & 31) << 2;
      *(float4*)&Bs[bk * 128 + c4] = *(const float4*)(Bm + (size_t)(k0 + bk) * N + n0 + c4);
    }
    __syncthreads();
    #pragma unroll
    for (int k = 0; k < 16; k++) {
      float a8[8], b8[8];
      *(float4*)&a8[0] = *(const float4*)&As[k * 132 + w * 32 + ty * 8];
      *(float4*)&a8[4] = *(const float4*)&As[k * 132 + w * 32 + ty * 8 + 4];
      *(float4*)&b8[0] = *(const float4*)&Bs[k * 128 + tx * 8];
      *(float4*)&b8[4] = *(const float4*)&Bs[k * 128 + tx * 8 + 4];
      #pragma unroll
      for (int i = 0; i < 8; i++)
        #pragma unroll
        for (int j = 0; j < 8; j++)
          acc[i][j] = fmaf(a8[i], b8[j], acc[i][j]);
    }
    __syncthreads();
  }
  float bj[8];
  if (BIAS_RES) {
    #pragma unroll
    for (int j = 0; j < 8; j++) bj[j] = bias[n0 + tx * 8 + j];
  }
  #pragma unroll
  for (int i = 0; i < 8; i++) {
    size_t row = (size_t)m0 + w * 32 + ty * 8 + i;
    float* crow = Cout + row * N + n0 + tx * 8;
    float o8[8];
    #pragma unroll
    for (int j = 0; j < 8; j++) o8[j] = acc[i][j];
    if (BIAS_RES) {
      const float* rr = Res + row * N + n0 + tx * 8;
      float4 r0 = *(const float4*)rr, r1 = *(const float4*)(rr + 4);
      o8[0] += bj[0] + r0.x; o8[1] += bj[1] + r0.y; o8[2] += bj[2] + r0.z; o8[3] += bj[3] + r0.w;
      o8[4] += bj[4] + r1.x; o8[5] += bj[5] + r1.y; o8[6] += bj[6] + r1.z; o8[7] += bj[7] + r1.w;
    }
    *(float4*)crow = make_float4(o8[0], o8[1], o8[2], o8[3]);
    *(float4*)(crow + 4) = make_float4(o8[4], o8[5], o8[6], o8[7]);
  }
}

// ---------------- fp32 causal flash attention ----------------
// QKV [8192][2304] (q|k|v, head-major 64 each); O [8192][768]

__global__ __launch_bounds__(256) void attn_k(const float* __restrict__ QKV, float* __restrict__ O) {
  __shared__ __align__(16) float Qs[64 * 68];
  __shared__ __align__(16) float Ks[64 * 68];
  __shared__ __align__(16) float Vs[64 * 64];
  __shared__ __align__(16) float Ps[64 * 68];
  const int qt = blockIdx.x, hh = blockIdx.y, bb = blockIdx.z;
  const int tid = threadIdx.x, tx = tid & 15, ty = tid >> 4;
  const int q0 = qt * 64;
  const float scale = 0.03608439182435161f;  // 768^-0.5
  {
    int r = tid & 63, kg = (tid >> 6) * 16;
    const float* g = QKV + ((size_t)bb * 1024 + q0 + r) * 2304 + hh * 64 + kg;
    #pragma unroll
    for (int jj = 0; jj < 16; jj += 4) {
      float4 p = *(const float4*)(g + jj);
      Qs[(kg + jj + 0) * 68 + r] = p.x;
      Qs[(kg + jj + 1) * 68 + r] = p.y;
      Qs[(kg + jj + 2) * 68 + r] = p.z;
      Qs[(kg + jj + 3) * 68 + r] = p.w;
    }
  }
  float o[4][4] = {};
  float mrun[4], lrun[4] = {};
  #pragma unroll
  for (int i = 0; i < 4; i++) mrun[i] = -__builtin_inff();

  for (int st = 0; st <= qt; st++) {
    __syncthreads();
    {
      int r = tid & 63, kg = (tid >> 6) * 16;
      const float* g = QKV + ((size_t)bb * 1024 + st * 64 + r) * 2304 + 768 + hh * 64 + kg;
      #pragma unroll
      for (int jj = 0; jj < 16; jj += 4) {
        float4 p = *(const float4*)(g + jj);
        Ks[(kg + jj + 0) * 68 + r] = p.x;
        Ks[(kg + jj + 1) * 68 + r] = p.y;
        Ks[(kg + jj + 2) * 68 + r] = p.z;
        Ks[(kg + jj + 3) * 68 + r] = p.w;
      }
      #pragma unroll
      for (int kk = 0; kk < 4; kk++) {
        int f = tid + kk * 256;
        int s = f >> 4, j4 = (f & 15) << 2;
        *(float4*)&Vs[(s << 6) + j4] =
            *(const float4*)(QKV + ((size_t)bb * 1024 + st * 64 + s) * 2304 + 1536 + hh * 64 + j4);
      }
    }
    __syncthreads();
    float sc[4][4] = {};
    #pragma unroll 4
    for (int k = 0; k < 64; k++) {
      float4 qv = *(const float4*)&Qs[k * 68 + (ty << 2)];
      float4 kv = *(const float4*)&Ks[k * 68 + (tx << 2)];
      float qa[4] = {qv.x, qv.y, qv.z, qv.w};
      float kb[4] = {kv.x, kv.y, kv.z, kv.w};
      #pragma unroll
      for (int i = 0; i < 4; i++)
        #pragma unroll
        for (int j = 0; j < 4; j++)
          sc[i][j] = fmaf(qa[i], kb[j], sc[i][j]);
    }
    const bool diag = (st == qt);
    float mt[4];
    #pragma unroll
    for (int i = 0; i < 4; i++) {
      float mrow = -3.0e38f;
      #pragma unroll
      for (int j = 0; j < 4; j++) {
        float v = sc[i][j] * scale;
        if (diag && ((tx << 2) + j > (ty << 2) + i)) v = -__builtin_inff();
        sc[i][j] = v;
        mrow = fmaxf(mrow, v);
      }
      mt[i] = mrow;
    }
    #pragma unroll
    for (int mk = 1; mk < 16; mk <<= 1)
      #pragma unroll
      for (int i = 0; i < 4; i++) mt[i] = fmaxf(mt[i], __shfl_xor(mt[i], mk));
    float sfv[4], psum[4];
    #pragma unroll
    for (int i = 0; i < 4; i++) {
      float mnew = fmaxf(mrun[i], mt[i]);
      sfv[i] = expf(mrun[i] - mnew);
      mrun[i] = mnew;
      float rs = 0.0f;
      #pragma unroll
      for (int j = 0; j < 4; j++) {
        float pv = expf(sc[i][j] - mnew);
        sc[i][j] = pv;
        rs += pv;
      }
      psum[i] = rs;
    }
    #pragma unroll
    for (int mk = 1; mk < 16; mk <<= 1)
      #pragma unroll
      for (int i = 0; i < 4; i++) psum[i] += __shfl_xor(psum[i], mk);
    #pragma unroll
    for (int i = 0; i < 4; i++) {
      lrun[i] = lrun[i] * sfv[i] + psum[i];
      #pragma unroll
      for (int j = 0; j < 4; j++) o[i][j] *= sfv[i];
    }
    #pragma unroll
    for (int i = 0; i < 4; i++)
      #pragma unroll
      for (int j = 0; j < 4; j++)
        Ps[((tx << 2) + j) * 68 + (ty << 2) + i] = sc[i][j];
    __syncthreads();
    #pragma unroll 4
    for (int s2 = 0; s2 < 64; s2++) {
      float4 pv = *(const float4*)&Ps[s2 * 68 + (ty << 2)];
      float4 vv = *(const float4*)&Vs[(s2 << 6) + (tx << 2)];
      float pa[4] = {pv.x, pv.y, pv.z, pv.w};
      float vb4[4] = {vv.x, vv.y, vv.z, vv.w};
      #pragma unroll
      for (int i = 0; i < 4; i++)
        #pragma unroll
        for (int j = 0; j < 4; j++)
          o[i][j] = fmaf(pa[i], vb4[j], o[i][j]);
    }
  }
  #pragma unroll
  for (int i = 0; i < 4; i++) {
    float inv = 1.0f / lrun[i];
    *(float4*)&O[((size_t)bb * 1024 + q0 + (ty << 2) + i) * 768 + hh * 64 + (tx << 2)] =
        make_float4(o[i][0] * inv, o[i][1] * inv, o[i][2] * inv, o[i][3] * inv);
  }
}

// ---------------- router (fp32, exact top-2 semantics) ----------------

__global__ __launch_bounds__(256) void router_k(const float* __restrict__ h2,
    const float* __restrict__ w_route, const float* __restrict__ b_route,
    const float* __restrict__ w_noise, const float* __restrict__ b_noise,
    const float* __restrict__ rnoise, const float* __restrict__ tp, float* __restrict__ gate) {
  __shared__ float Wl[6144], Wn[6144];
  int t = threadIdx.x;
  for (int i = t; i < 1536; i += 256) {
    ((float4*)Wl)[i] = ((const float4*)w_route)[i];
    ((float4*)Wn)[i] = ((const float4*)w_noise)[i];
  }
  __syncthreads();
  int tok = blockIdx.x * 64 + (t >> 2);
  int sub = t & 3;
  const float* hr = h2 + (size_t)tok * 768;
  float aL[8] = {}, aN[8] = {};
  for (int i = 0; i < 192; i++) {
    int c = sub + (i << 2);
    float hv = hr[c];
    const float* wl = &Wl[c * 8];
    const float* wn = &Wn[c * 8];
    #pragma unroll
    for (int e = 0; e < 8; e++) { aL[e] = fmaf(hv, wl[e], aL[e]); aN[e] = fmaf(hv, wn[e], aN[e]); }
  }
  #pragma unroll
  for (int e = 0; e < 8; e++) {
    aL[e] += __shfl_xor(aL[e], 1); aL[e] += __shfl_xor(aL[e], 2);
    aN[e] += __shfl_xor(aN[e], 1); aN[e] += __shfl_xor(aN[e], 2);
  }
  if (sub == 0) {
    float temp = fminf(fmaxf(tp[0], 0.5f), 2.0f);
    float noisy[8];
    #pragma unroll
    for (int e = 0; e < 8; e++) {
      float lg = aL[e] + b_route[e];
      float ns = softplus_f(aN[e] + b_noise[e]);
      noisy[e] = lg + temp * rnoise[(size_t)tok * 8 + e] * ns;
    }
    int i1 = 0; float v1 = noisy[0];
    #pragma unroll
    for (int e = 1; e < 8; e++) if (noisy[e] > v1) { v1 = noisy[e]; i1 = e; }
    int i2 = -1; float v2 = 0.0f;
    #pragma unroll
    for (int e = 0; e < 8; e++) {
      if (e == i1) continue;
      if (i2 < 0 || noisy[e] > v2) { v2 = noisy[e]; i2 = e; }
    }
    float e2 = expf(v2 - v1);
    float denom = 1.0f + e2;
    float* gr = gate + (size_t)tok * 8;
    #pragma unroll
    for (int e = 0; e < 8; e++) gr[e] = 0.0f;
    gr[i1] = 1.0f / denom;
    gr[i2] = e2 / denom;
  }
}

// ---------------- bf16 MFMA GEMM (experts): A [M,K] bf16, BT [N,K] bf16 ----------------

template<int GELU_OUT, int BF16_OUT>
__global__ __launch_bounds__(256) void gemm_bf16_bt(const u16* __restrict__ A,
    const u16* __restrict__ BT, const float* __restrict__ bias, void* __restrict__ Cout,
    int M, int N, int K) {
  __shared__ __align__(16) u16 As[128 * 32];
  __shared__ __align__(16) u16 Bs[128 * 32];
  const int tid = threadIdx.x;
  const int l = tid & 63, w = tid >> 6;
  const int m0 = blockIdx.y << 7, n0 = blockIdx.x << 7;
  const int wr = w >> 1, wc = w & 1;
  f32x4 zero = {0.0f, 0.0f, 0.0f, 0.0f};
  f32x4 acc[4][4];
  #pragma unroll
  for (int mi = 0; mi < 4; mi++)
    #pragma unroll
    for (int ni = 0; ni < 4; ni++) acc[mi][ni] = zero;

  for (int k0 = 0; k0 < K; k0 += 32) {
    int c = (w << 7) + l;
    GLDS16(A + (size_t)(m0 + (c >> 2)) * K + k0 + ((c & 3) << 3), As + c * 8);
    GLDS16(BT + (size_t)(n0 + (c >> 2)) * K + k0 + ((c & 3) << 3), Bs + c * 8);
    c += 64;
    GLDS16(A + (size_t)(m0 + (c >> 2)) * K + k0 + ((c & 3) << 3), As + c * 8);
    GLDS16(BT + (size_t)(n0 + (c >> 2)) * K + k0 + ((c & 3) << 3), Bs + c * 8);
    __syncthreads();
    short8 av[4], bv[4];
    const int ra = (wr << 6) + (l & 15);
    const int rb = (wc << 6) + (l & 15);
    const int ko = (l >> 4) << 3;
    #pragma unroll
    for (int mi = 0; mi < 4; mi++) av[mi] = *(const short8*)(As + (ra + mi * 16) * 32 + ko);
    #pragma unroll
    for (int ni = 0; ni < 4; ni++) bv[ni] = *(const short8*)(Bs + (rb + ni * 16) * 32 + ko);
    #pragma unroll
    for (int mi = 0; mi < 4; mi++)
      #pragma unroll
      for (int ni = 0; ni < 4; ni++)
        acc[mi][ni] = __builtin_amdgcn_mfma_f32_16x16x32_bf16(av[mi], bv[ni], acc[mi][ni], 0, 0, 0);
    __syncthreads();
  }
  const int lr = (l >> 4) << 2;
  const int lc = l & 15;
  #pragma unroll
  for (int mi = 0; mi < 4; mi++) {
    #pragma unroll
    for (int ni = 0; ni < 4; ni++) {
      const int col = n0 + (wc << 6) + ni * 16 + lc;
      const float bv2 = bias ? bias[col] : 0.0f;
      #pragma unroll
      for (int v = 0; v < 4; v++) {
        const size_t row = (size_t)m0 + (wr << 6) + mi * 16 + lr + v;
        float val = acc[mi][ni][v] + bv2;
        if (GELU_OUT) val = gelu_exact(val);
        if (BF16_OUT) ((u16*)Cout)[row * N + col] = f2bf(val);
        else          ((float*)Cout)[row * N + col] = val;
      }
    }
  }
}

// ---------------- per-expert residual-LN + gated accumulate ----------------

__global__ __launch_bounds__(256) void combine_k(const float* __restrict__ U,
    const float* __restrict__ H2, const float* __restrict__ gate,
    const float* __restrict__ g, const float* __restrict__ b,
    float* __restrict__ Out, int eidx) {
  __shared__ float sm[4];
  size_t row = blockIdx.x;
  float gt = gate[row * 8 + eidx];
  if (gt == 0.0f) return;
  int t = threadIdx.x;
  const float* h = H2 + row * 768;
  const float* u = U + row * 768;
  float v0 = h[t] + u[t], v1 = h[t + 256] + u[t + 256], v2 = h[t + 512] + u[t + 512];
  float mean = block_sum256(v0 + v1 + v2, sm) * (1.0f / 768.0f);
  float d0 = v0 - mean, d1 = v1 - mean, d2 = v2 - mean;
  float var = block_sum256(d0 * d0 + d1 * d1 + d2 * d2, sm) * (1.0f / 768.0f);
  float rstd = 1.0f / sqrtf(var + 1e-5f);
  float* o = Out + row * 768;
  o[t]       += gt * (d0 * rstd * g[t]       + b[t]);
  o[t + 256] += gt * (d1 * rstd * g[t + 256] + b[t + 256]);
  o[t + 512] += gt * (d2 * rstd * g[t + 512] + b[t + 512]);
}

// ---------------- launch ----------------

extern "C" void kernel_launch(void* const* d_in, const int* in_sizes, int n_in,
                              void* d_out, int out_size, void* d_ws, size_t ws_size,
                              hipStream_t stream) {
  (void)in_sizes; (void)n_in; (void)out_size;
  const float* xin       = (const float*)d_in[0];
  const float* rnoise    = (const float*)d_in[1];
  const float* wq        = (const float*)d_in[2];
  const float* wk        = (const float*)d_in[3];
  const float* wv        = (const float*)d_in[4];
  const float* w_proj    = (const float*)d_in[5];
  const float* b_proj    = (const float*)d_in[6];
  const float* ln1_g     = (const float*)d_in[7];
  const float* ln1_b     = (const float*)d_in[8];
  const float* ln2_g     = (const float*)d_in[9];
  const float* ln2_b     = (const float*)d_in[10];
  const float* w_route   = (const float*)d_in[11];
  const float* b_route   = (const float*)d_in[12];
  const float* w_noise   = (const float*)d_in[13];
  const float* b_noise   = (const float*)d_in[14];
  const float* temp      = (const float*)d_in[15];
  const float* deep_w1   = (const float*)d_in[16];
  const float* deep_b1   = (const float*)d_in[17];
  const float* deep_w2   = (const float*)d_in[18];
  const float* deep_b2   = (const float*)d_in[19];
  const float* deep_w3   = (const float*)d_in[20];
  const float* deep_b3   = (const float*)d_in[21];
  const float* deep_ln_g = (const float*)d_in[22];
  const float* deep_ln_b = (const float*)d_in[23];
  const float* simple_w1 = (const float*)d_in[24];
  const float* simple_b1 = (const float*)d_in[25];
  const float* simple_w2 = (const float*)d_in[26];
  const float* simple_b2 = (const float*)d_in[27];
  const float* simple_ln_g = (const float*)d_in[28];
  const float* simple_ln_b = (const float*)d_in[29];

  char* ws = (char*)d_ws;
  size_t off = 0;
  auto alloc = [&](size_t bytes) -> char* {
    char* p = ws + off;
    off += (bytes + 255) & ~(size_t)255;
    return p;
  };
  float* wqkv = (float*)alloc(768ull * 2304 * 4);
  float* gate = (float*)alloc((size_t)TOK * 8 * 4);
  float* h2   = (float*)alloc((size_t)TOK * CDIM * 4);
  u16*   h2b  = (u16*)  alloc((size_t)TOK * CDIM * 2);
  float* x1   = (float*)alloc((size_t)TOK * CDIM * 4);
  float* hbuf = (float*)alloc((size_t)TOK * CDIM * 4);   // ln1 out; reused as U
  char*  big  = alloc((size_t)TOK * 2304 * 4 + (size_t)TOK * CDIM * 4); // QKV|O -> T1|T2
  float* QKV  = (float*)big;
  float* Obuf = (float*)(big + (size_t)TOK * 2304 * 4);
  u16* T1 = (u16*)big;
  u16* T2 = (u16*)(big + (size_t)TOK * FDIM * 2);
  float* Ubuf = hbuf;

  size_t wsz_all = (2ull * FDIM * CDIM + 2ull * FDIM * FDIM + 2ull * CDIM * FDIM +
                    6ull * FDIM * CDIM + 6ull * CDIM * FDIM) * 2 + 16 * 256;
  bool big_ws = ws_size >= off + wsz_all;
  u16 *dW1T = nullptr, *dW2T = nullptr, *dW3T = nullptr, *sW1T = nullptr, *sW2T = nullptr, *wbuf = nullptr;
  if (big_ws) {
    dW1T = (u16*)alloc(2ull * FDIM * CDIM * 2);
    dW2T = (u16*)alloc(2ull * FDIM * FDIM * 2);
    dW3T = (u16*)alloc(2ull * CDIM * FDIM * 2);
    sW1T = (u16*)alloc(6ull * FDIM * CDIM * 2);
    sW2T = (u16*)alloc(6ull * CDIM * FDIM * 2);
  } else {
    wbuf = (u16*)alloc((size_t)FDIM * FDIM * 2);
  }

  pack_qkv<<<dim3((768 * 2304 + 255) / 256), 256, 0, stream>>>(wq, wk, wv, wqkv);
  if (big_ws) {
    transpose_cast<<<dim3(FDIM / 32, CDIM / 32, 2), 256, 0, stream>>>(deep_w1, dW1T, CDIM, FDIM);
    transpose_cast<<<dim3(FDIM / 32, FDIM / 32, 2), 256, 0, stream>>>(deep_w2, dW2T, FDIM, FDIM);
    transpose_cast<<<dim3(CDIM / 32, FDIM / 32, 2), 256, 0, stream>>>(deep_w3, dW3T, FDIM, CDIM);
    transpose_cast<<<dim3(FDIM / 32, CDIM / 32, 6), 256, 0, stream>>>(simple_w1, sW1T, CDIM, FDIM);
    transpose_cast<<<dim3(CDIM / 32, FDIM / 32, 6), 256, 0, stream>>>(simple_w2, sW2T, FDIM, CDIM);
  }
  ln1_k<<<TOK, 256, 0, stream>>>(xin, ln1_g, ln1_b, hbuf);
  gemm_f32<0><<<dim3(2304 / 128, TOK / 128), 256, 0, stream>>>(hbuf, wqkv, nullptr, nullptr, QKV, TOK, 2304, CDIM);
  attn_k<<<dim3(16, 12, 8), 256, 0, stream>>>(QKV, Obuf);
  gemm_f32<1><<<dim3(CDIM / 128, TOK / 128), 256, 0, stream>>>(Obuf, w_proj, b_proj, xin, x1, TOK, CDIM, CDIM);
  ln2_k<<<TOK, 256, 0, stream>>>(x1, ln2_g, ln2_b, h2, h2b, (float*)d_out);
  router_k<<<128, 256, 0, stream>>>(h2, w_route, b_route, w_noise, b_noise, rnoise, temp, gate);

  for (int e = 0; e < 2; e++) {
    const u16* W1;
    if (big_ws) W1 = dW1T + (size_t)e * FDIM * CDIM;
    else {
      transpose_cast<<<dim3(FDIM / 32, CDIM / 32, 1), 256, 0, stream>>>(deep_w1 + (size_t)e * CDIM * FDIM, wbuf, CDIM, FDIM);
      W1 = wbuf;
    }
    gemm_bf16_bt<1, 1><<<dim3(FDIM / 128, TOK / 128), 256, 0, stream>>>(h2b, W1, deep_b1 + e * FDIM, (void*)T1, TOK, FDIM, CDIM);
    const u16* W2;
    if (big_ws) W2 = dW2T + (size_t)e * FDIM * FDIM;
    else {
      transpose_cast<<<dim3(FDIM / 32, FDIM / 32, 1), 256, 0, stream>>>(deep_w2 + (size_t)e * FDIM * FDIM, wbuf, FDIM, FDIM);
      W2 = wbuf;
    }
    gemm_bf16_bt<1, 1><<<dim3(FDIM / 128, TOK / 128), 256, 0, stream>>>(T1, W2, deep_b2 + e * FDIM, (void*)T2, TOK, FDIM, FDIM);
    const u16* W3;
    if (big_ws) W3 = dW3T + (size_t)e * CDIM * FDIM;
    else {
      transpose_cast<<<dim3(CDIM / 32, FDIM / 32, 1), 256, 0, stream>>>(deep_w3 + (size_t)e * FDIM * CDIM, wbuf, FDIM, CDIM);
      W3 = wbuf;
    }
    gemm_bf16_bt<0, 0><<<dim3(CDIM / 128, TOK / 128), 256, 0, stream>>>(T2, W3, deep_b3 + e * CDIM, (void*)Ubuf, TOK, CDIM, FDIM);
    combine_k<<<TOK, 256, 0, stream>>>(Ubuf, h2, gate, deep_ln_g + e * CDIM, deep_ln_b + e * CDIM, (float*)d_out, e);
  }
  for (int e = 0; e < 6; e++) {
    const u16* W1;
    if (big_ws) W1 = sW1T + (size_t)e * FDIM * CDIM;
    else {
      transpose_cast<<<dim3(FDIM / 32, CDIM / 32, 1), 256, 0, stream>>>(simple_w1 + (size_t)e * CDIM * FDIM, wbuf, CDIM, FDIM);
      W1 = wbuf;
    }
    gemm_bf16_bt<1, 1><<<dim3(FDIM / 128, TOK / 128), 256, 0, stream>>>(h2b, W1, simple_b1 + e * FDIM, (void*)T1, TOK, FDIM, CDIM);
    const u16* W2;
    if (big_ws) W2 = sW2T + (size_t)e * CDIM * FDIM;
    else {
      transpose_cast<<<dim3(CDIM / 32, FDIM / 32, 1), 256, 0, stream>>>(simple_w2 + (size_t)e * FDIM * CDIM, wbuf, FDIM, CDIM);
      W2 = wbuf;
    }
    gemm_bf16_bt<0, 0><<<dim3(CDIM / 128, TOK / 128), 256, 0, stream>>>(T1, W2, simple_b2 + e * CDIM, (void*)Ubuf, TOK, CDIM, FDIM);
    combine_k<<<TOK, 256, 0, stream>>>(Ubuf, h2, gate, simple_ln_g + e * CDIM, simple_ln_b + e * CDIM, (float*)d_out, 2 + e);
  }
}

// Round 4
// 2398.772 us; speedup vs baseline: 1.2599x; 1.2599x over previous
//
#include <hip/hip_runtime.h>
#include <cstdint>
#include <cstddef>
#include <math.h>

typedef uint16_t u16;
typedef __attribute__((ext_vector_type(8))) short short8;
typedef __attribute__((ext_vector_type(4))) float f32x4;

#define TOK 8192
#define CDIM 768
#define FDIM 3072

#define GLDS16(g, l) __builtin_amdgcn_global_load_lds((const __attribute__((address_space(1))) uint32_t*)(g), (__attribute__((address_space(3))) uint32_t*)(l), 16, 0, 0)

__device__ __forceinline__ u16 f2bf(float f) {
  union { float f; uint32_t u; } v; v.f = f;
  uint32_t u = v.u;
  return (u16)((u + 0x7FFFu + ((u >> 16) & 1u)) >> 16);
}

__device__ __forceinline__ float gelu_exact(float z) {
  return 0.5f * z * (1.0f + erff(z * 0.70710678118654752f));
}

__device__ __forceinline__ float softplus_f(float x) {
  return (x > 0.0f) ? (x + log1pf(expf(-x))) : log1pf(expf(x));
}

__device__ __forceinline__ float block_sum256(float v, float* sm) {
  #pragma unroll
  for (int m = 1; m < 64; m <<= 1) v += __shfl_xor(v, m);
  int w = threadIdx.x >> 6;
  if ((threadIdx.x & 63) == 0) sm[w] = v;
  __syncthreads();
  v = sm[0] + sm[1] + sm[2] + sm[3];
  __syncthreads();
  return v;
}

// ---------------- weight prep ----------------

__global__ __launch_bounds__(256) void pack_qkv(const float* __restrict__ wq,
    const float* __restrict__ wk, const float* __restrict__ wv, float* __restrict__ W) {
  int id = blockIdx.x * 256 + threadIdx.x;
  if (id >= 768 * 2304) return;
  int c = id / 2304, j = id - c * 2304;
  int which = j / 768, jj = j - which * 768;
  int hh = jj >> 6, d = jj & 63;
  const float* src = (which == 0) ? wq : (which == 1 ? wk : wv);
  W[id] = src[((size_t)hh * 768 + c) * 64 + d];
}

// src [K][N] fp32 (per expert via blockIdx.z) -> dst [N][K] bf16
__global__ __launch_bounds__(256) void transpose_cast(const float* __restrict__ src,
    u16* __restrict__ dst, int K, int N) {
  __shared__ float t[32][33];
  size_t eoff = (size_t)blockIdx.z * K * N;
  const float* S = src + eoff;
  u16* D = dst + eoff;
  int n0 = blockIdx.x * 32, k0 = blockIdx.y * 32;
  int tc = threadIdx.x & 31, tr = threadIdx.x >> 5;
  #pragma unroll
  for (int r = tr; r < 32; r += 8) t[r][tc] = S[(size_t)(k0 + r) * N + n0 + tc];
  __syncthreads();
  #pragma unroll
  for (int r = tr; r < 32; r += 8) D[(size_t)(n0 + r) * K + k0 + tc] = f2bf(t[tc][r]);
}

// ---------------- layernorms ----------------

__global__ __launch_bounds__(256) void ln1_k(const float* __restrict__ X,
    const float* __restrict__ g, const float* __restrict__ b, float* __restrict__ Y) {
  __shared__ float sm[4];
  size_t row = blockIdx.x;
  const float* x = X + row * 768;
  int t = threadIdx.x;
  float v0 = x[t], v1 = x[t + 256], v2 = x[t + 512];
  float mean = block_sum256(v0 + v1 + v2, sm) * (1.0f / 768.0f);
  float d0 = v0 - mean, d1 = v1 - mean, d2 = v2 - mean;
  float var = block_sum256(d0 * d0 + d1 * d1 + d2 * d2, sm) * (1.0f / 768.0f);
  float rstd = 1.0f / sqrtf(var + 1e-5f);
  float* y = Y + row * 768;
  y[t]       = d0 * rstd * g[t]       + b[t];
  y[t + 256] = d1 * rstd * g[t + 256] + b[t + 256];
  y[t + 512] = d2 * rstd * g[t + 512] + b[t + 512];
}

__global__ __launch_bounds__(256) void ln2_k(const float* __restrict__ X,
    const float* __restrict__ g, const float* __restrict__ b, float* __restrict__ H2,
    u16* __restrict__ H2b, float* __restrict__ OutInit) {
  __shared__ float sm[4];
  size_t row = blockIdx.x;
  const float* x = X + row * 768;
  int t = threadIdx.x;
  float v0 = x[t], v1 = x[t + 256], v2 = x[t + 512];
  float mean = block_sum256(v0 + v1 + v2, sm) * (1.0f / 768.0f);
  float d0 = v0 - mean, d1 = v1 - mean, d2 = v2 - mean;
  float var = block_sum256(d0 * d0 + d1 * d1 + d2 * d2, sm) * (1.0f / 768.0f);
  float rstd = 1.0f / sqrtf(var + 1e-5f);
  float y0 = d0 * rstd * g[t]       + b[t];
  float y1 = d1 * rstd * g[t + 256] + b[t + 256];
  float y2 = d2 * rstd * g[t + 512] + b[t + 512];
  float* h2r = H2 + row * 768;
  u16* hbr = H2b + row * 768;
  float* outr = OutInit + row * 768;
  h2r[t] = y0; h2r[t + 256] = y1; h2r[t + 512] = y2;
  hbr[t] = f2bf(y0); hbr[t + 256] = f2bf(y1); hbr[t + 512] = f2bf(y2);
  outr[t] = v0; outr[t + 256] = v1; outr[t + 512] = v2;
}

// ---------------- fp32 GEMM (pre-router path; accuracy-critical) ----------------

template<int BIAS_RES>
__global__ __launch_bounds__(256) void gemm_f32(const float* __restrict__ A,
    const float* __restrict__ Bm, const float* __restrict__ bias,
    const float* __restrict__ Res, float* __restrict__ Cout, int M, int N, int K) {
  __shared__ __align__(16) float As[16 * 132];
  __shared__ __align__(16) float Bs[16 * 128];
  const int tid = threadIdx.x;
  const int m0 = blockIdx.y << 7, n0 = blockIdx.x << 7;
  const int w = tid >> 6, l = tid & 63;
  const int tx = l & 15, ty = l >> 4;
  float acc[8][8] = {};
  const int arow = tid >> 1, ahalf = tid & 1;
  for (int k0 = 0; k0 < K; k0 += 16) {
    {
      const float* ga = A + (size_t)(m0 + arow) * K + k0 + ahalf * 8;
      float4 p0 = *(const float4*)ga;
      float4 p1 = *(const float4*)(ga + 4);
      int kk = ahalf * 8;
      As[(kk + 0) * 132 + arow] = p0.x; As[(kk + 1) * 132 + arow] = p0.y;
      As[(kk + 2) * 132 + arow] = p0.z; As[(kk + 3) * 132 + arow] = p0.w;
      As[(kk + 4) * 132 + arow] = p1.x; As[(kk + 5) * 132 + arow] = p1.y;
      As[(kk + 6) * 132 + arow] = p1.z; As[(kk + 7) * 132 + arow] = p1.w;
      int f = tid; int bk = f >> 5, c4 = (f & 31) << 2;
      *(float4*)&Bs[bk * 128 + c4] = *(const float4*)(Bm + (size_t)(k0 + bk) * N + n0 + c4);
      f = tid + 256; bk = f >> 5; c4 = (f & 31) << 2;
      *(float4*)&Bs[bk * 128 + c4] = *(const float4*)(Bm + (size_t)(k0 + bk) * N + n0 + c4);
    }
    __syncthreads();
    #pragma unroll
    for (int k = 0; k < 16; k++) {
      float a8[8], b8[8];
      *(float4*)&a8[0] = *(const float4*)&As[k * 132 + w * 32 + ty * 8];
      *(float4*)&a8[4] = *(const float4*)&As[k * 132 + w * 32 + ty * 8 + 4];
      *(float4*)&b8[0] = *(const float4*)&Bs[k * 128 + tx * 8];
      *(float4*)&b8[4] = *(const float4*)&Bs[k * 128 + tx * 8 + 4];
      #pragma unroll
      for (int i = 0; i < 8; i++)
        #pragma unroll
        for (int j = 0; j < 8; j++)
          acc[i][j] = fmaf(a8[i], b8[j], acc[i][j]);
    }
    __syncthreads();
  }
  float bj[8];
  if (BIAS_RES) {
    #pragma unroll
    for (int j = 0; j < 8; j++) bj[j] = bias[n0 + tx * 8 + j];
  }
  #pragma unroll
  for (int i = 0; i < 8; i++) {
    size_t row = (size_t)m0 + w * 32 + ty * 8 + i;
    float* crow = Cout + row * N + n0 + tx * 8;
    float o8[8];
    #pragma unroll
    for (int j = 0; j < 8; j++) o8[j] = acc[i][j];
    if (BIAS_RES) {
      const float* rr = Res + row * N + n0 + tx * 8;
      float4 r0 = *(const float4*)rr, r1 = *(const float4*)(rr + 4);
      o8[0] += bj[0] + r0.x; o8[1] += bj[1] + r0.y; o8[2] += bj[2] + r0.z; o8[3] += bj[3] + r0.w;
      o8[4] += bj[4] + r1.x; o8[5] += bj[5] + r1.y; o8[6] += bj[6] + r1.z; o8[7] += bj[7] + r1.w;
    }
    *(float4*)crow = make_float4(o8[0], o8[1], o8[2], o8[3]);
    *(float4*)(crow + 4) = make_float4(o8[4], o8[5], o8[6], o8[7]);
  }
}

// ---------------- fp32 causal flash attention ----------------

__global__ __launch_bounds__(256) void attn_k(const float* __restrict__ QKV, float* __restrict__ O) {
  __shared__ __align__(16) float Qs[64 * 68];
  __shared__ __align__(16) float Ks[64 * 68];
  __shared__ __align__(16) float Vs[64 * 64];
  __shared__ __align__(16) float Ps[64 * 68];
  const int qt = blockIdx.x, hh = blockIdx.y, bb = blockIdx.z;
  const int tid = threadIdx.x, tx = tid & 15, ty = tid >> 4;
  const int q0 = qt * 64;
  const float scale = 0.03608439182435161f;  // 768^-0.5
  {
    int r = tid & 63, kg = (tid >> 6) * 16;
    const float* g = QKV + ((size_t)bb * 1024 + q0 + r) * 2304 + hh * 64 + kg;
    #pragma unroll
    for (int jj = 0; jj < 16; jj += 4) {
      float4 p = *(const float4*)(g + jj);
      Qs[(kg + jj + 0) * 68 + r] = p.x;
      Qs[(kg + jj + 1) * 68 + r] = p.y;
      Qs[(kg + jj + 2) * 68 + r] = p.z;
      Qs[(kg + jj + 3) * 68 + r] = p.w;
    }
  }
  float o[4][4] = {};
  float mrun[4], lrun[4] = {};
  #pragma unroll
  for (int i = 0; i < 4; i++) mrun[i] = -__builtin_inff();

  for (int st = 0; st <= qt; st++) {
    __syncthreads();
    {
      int r = tid & 63, kg = (tid >> 6) * 16;
      const float* g = QKV + ((size_t)bb * 1024 + st * 64 + r) * 2304 + 768 + hh * 64 + kg;
      #pragma unroll
      for (int jj = 0; jj < 16; jj += 4) {
        float4 p = *(const float4*)(g + jj);
        Ks[(kg + jj + 0) * 68 + r] = p.x;
        Ks[(kg + jj + 1) * 68 + r] = p.y;
        Ks[(kg + jj + 2) * 68 + r] = p.z;
        Ks[(kg + jj + 3) * 68 + r] = p.w;
      }
      #pragma unroll
      for (int kk = 0; kk < 4; kk++) {
        int f = tid + kk * 256;
        int s = f >> 4, j4 = (f & 15) << 2;
        *(float4*)&Vs[(s << 6) + j4] =
            *(const float4*)(QKV + ((size_t)bb * 1024 + st * 64 + s) * 2304 + 1536 + hh * 64 + j4);
      }
    }
    __syncthreads();
    float sc[4][4] = {};
    #pragma unroll 4
    for (int k = 0; k < 64; k++) {
      float4 qv = *(const float4*)&Qs[k * 68 + (ty << 2)];
      float4 kv = *(const float4*)&Ks[k * 68 + (tx << 2)];
      float qa[4] = {qv.x, qv.y, qv.z, qv.w};
      float kb[4] = {kv.x, kv.y, kv.z, kv.w};
      #pragma unroll
      for (int i = 0; i < 4; i++)
        #pragma unroll
        for (int j = 0; j < 4; j++)
          sc[i][j] = fmaf(qa[i], kb[j], sc[i][j]);
    }
    const bool diag = (st == qt);
    float mt[4];
    #pragma unroll
    for (int i = 0; i < 4; i++) {
      float mrow = -3.0e38f;
      #pragma unroll
      for (int j = 0; j < 4; j++) {
        float v = sc[i][j] * scale;
        if (diag && ((tx << 2) + j > (ty << 2) + i)) v = -__builtin_inff();
        sc[i][j] = v;
        mrow = fmaxf(mrow, v);
      }
      mt[i] = mrow;
    }
    #pragma unroll
    for (int mk = 1; mk < 16; mk <<= 1)
      #pragma unroll
      for (int i = 0; i < 4; i++) mt[i] = fmaxf(mt[i], __shfl_xor(mt[i], mk));
    float sfv[4], psum[4];
    #pragma unroll
    for (int i = 0; i < 4; i++) {
      float mnew = fmaxf(mrun[i], mt[i]);
      sfv[i] = expf(mrun[i] - mnew);
      mrun[i] = mnew;
      float rs = 0.0f;
      #pragma unroll
      for (int j = 0; j < 4; j++) {
        float pv = expf(sc[i][j] - mnew);
        sc[i][j] = pv;
        rs += pv;
      }
      psum[i] = rs;
    }
    #pragma unroll
    for (int mk = 1; mk < 16; mk <<= 1)
      #pragma unroll
      for (int i = 0; i < 4; i++) psum[i] += __shfl_xor(psum[i], mk);
    #pragma unroll
    for (int i = 0; i < 4; i++) {
      lrun[i] = lrun[i] * sfv[i] + psum[i];
      #pragma unroll
      for (int j = 0; j < 4; j++) o[i][j] *= sfv[i];
    }
    // vectorized P store: register-transpose then ds_write_b128 (was 16 scalar 8-way-conflicted stores)
    {
      float pt[4][4];
      #pragma unroll
      for (int i = 0; i < 4; i++)
        #pragma unroll
        for (int j = 0; j < 4; j++) pt[j][i] = sc[i][j];
      #pragma unroll
      for (int j = 0; j < 4; j++)
        *(float4*)&Ps[((tx << 2) + j) * 68 + (ty << 2)] = *(const float4*)&pt[j][0];
    }
    __syncthreads();
    #pragma unroll 4
    for (int s2 = 0; s2 < 64; s2++) {
      float4 pv = *(const float4*)&Ps[s2 * 68 + (ty << 2)];
      float4 vv = *(const float4*)&Vs[(s2 << 6) + (tx << 2)];
      float pa[4] = {pv.x, pv.y, pv.z, pv.w};
      float vb4[4] = {vv.x, vv.y, vv.z, vv.w};
      #pragma unroll
      for (int i = 0; i < 4; i++)
        #pragma unroll
        for (int j = 0; j < 4; j++)
          o[i][j] = fmaf(pa[i], vb4[j], o[i][j]);
    }
  }
  #pragma unroll
  for (int i = 0; i < 4; i++) {
    float inv = 1.0f / lrun[i];
    *(float4*)&O[((size_t)bb * 1024 + q0 + (ty << 2) + i) * 768 + hh * 64 + (tx << 2)] =
        make_float4(o[i][0] * inv, o[i][1] * inv, o[i][2] * inv, o[i][3] * inv);
  }
}

// ---------------- router (fp32, exact top-2 semantics) ----------------

__global__ __launch_bounds__(256) void router_k(const float* __restrict__ h2,
    const float* __restrict__ w_route, const float* __restrict__ b_route,
    const float* __restrict__ w_noise, const float* __restrict__ b_noise,
    const float* __restrict__ rnoise, const float* __restrict__ tp, float* __restrict__ gate) {
  __shared__ float Wl[6144], Wn[6144];
  int t = threadIdx.x;
  for (int i = t; i < 1536; i += 256) {
    ((float4*)Wl)[i] = ((const float4*)w_route)[i];
    ((float4*)Wn)[i] = ((const float4*)w_noise)[i];
  }
  __syncthreads();
  int tok = blockIdx.x * 64 + (t >> 2);
  int sub = t & 3;
  const float* hr = h2 + (size_t)tok * 768;
  float aL[8] = {}, aN[8] = {};
  for (int i = 0; i < 192; i++) {
    int c = sub + (i << 2);
    float hv = hr[c];
    const float* wl = &Wl[c * 8];
    const float* wn = &Wn[c * 8];
    #pragma unroll
    for (int e = 0; e < 8; e++) { aL[e] = fmaf(hv, wl[e], aL[e]); aN[e] = fmaf(hv, wn[e], aN[e]); }
  }
  #pragma unroll
  for (int e = 0; e < 8; e++) {
    aL[e] += __shfl_xor(aL[e], 1); aL[e] += __shfl_xor(aL[e], 2);
    aN[e] += __shfl_xor(aN[e], 1); aN[e] += __shfl_xor(aN[e], 2);
  }
  if (sub == 0) {
    float temp = fminf(fmaxf(tp[0], 0.5f), 2.0f);
    float noisy[8];
    #pragma unroll
    for (int e = 0; e < 8; e++) {
      float lg = aL[e] + b_route[e];
      float ns = softplus_f(aN[e] + b_noise[e]);
      noisy[e] = lg + temp * rnoise[(size_t)tok * 8 + e] * ns;
    }
    int i1 = 0; float v1 = noisy[0];
    #pragma unroll
    for (int e = 1; e < 8; e++) if (noisy[e] > v1) { v1 = noisy[e]; i1 = e; }
    int i2 = -1; float v2 = 0.0f;
    #pragma unroll
    for (int e = 0; e < 8; e++) {
      if (e == i1) continue;
      if (i2 < 0 || noisy[e] > v2) { v2 = noisy[e]; i2 = e; }
    }
    float e2 = expf(v2 - v1);
    float denom = 1.0f + e2;
    float* gr = gate + (size_t)tok * 8;
    #pragma unroll
    for (int e = 0; e < 8; e++) gr[e] = 0.0f;
    gr[i1] = 1.0f / denom;
    gr[i2] = e2 / denom;
  }
}

// ---------------- routing compaction ----------------

__global__ void zero_counts(int* counts) {
  if (threadIdx.x < 8) counts[threadIdx.x] = 0;
}

__global__ __launch_bounds__(256) void assign_k(const float* __restrict__ gate,
    int* __restrict__ counts, int* __restrict__ idxbuf) {
  int tok = blockIdx.x * 256 + threadIdx.x;
  const float* gr = gate + (size_t)tok * 8;
  #pragma unroll
  for (int e = 0; e < 8; e++) {
    if (gr[e] > 0.0f) {
      int s = atomicAdd(&counts[e], 1);
      idxbuf[e * TOK + s] = tok;
    }
  }
}

// ---------------- bf16 MFMA GEMM over compacted rows ----------------
// A [*,K] bf16 (rows via ridx when GATHER, else compacted 0..cnt), BT [N,K] bf16.
// grid.y is max tiles; blocks beyond ceil(cnt/128) exit.

template<int GELU_OUT, int BF16_OUT, int GATHER>
__global__ __launch_bounds__(256) void gemm_bf16_cnt(const u16* __restrict__ A,
    const u16* __restrict__ BT, const float* __restrict__ bias, void* __restrict__ Cout,
    const int* __restrict__ ridx, const int* __restrict__ cntp, int N, int K) {
  const int cnt = *cntp;
  const int mtiles = (cnt + 127) >> 7;
  if ((int)blockIdx.y >= mtiles) return;
  __shared__ __align__(16) u16 As[128 * 32];
  __shared__ __align__(16) u16 Bs[128 * 32];
  const int tid = threadIdx.x;
  const int l = tid & 63, w = tid >> 6;
  const int m0 = blockIdx.y << 7, n0 = blockIdx.x << 7;
  const int wr = w >> 1, wc = w & 1;
  // each thread stages 2 fixed A-rows across all k-steps
  const int ca = (w << 7) + l, cb = ca + 64;
  const int ra_ = m0 + (ca >> 2), rb_ = m0 + (cb >> 2);
  size_t ga, gb;
  if (GATHER) {
    ga = (size_t)ridx[ra_ < cnt ? ra_ : 0];
    gb = (size_t)ridx[rb_ < cnt ? rb_ : 0];
  } else {
    ga = (size_t)ra_; gb = (size_t)rb_;
  }
  f32x4 zero = {0.0f, 0.0f, 0.0f, 0.0f};
  f32x4 acc[4][4];
  #pragma unroll
  for (int mi = 0; mi < 4; mi++)
    #pragma unroll
    for (int ni = 0; ni < 4; ni++) acc[mi][ni] = zero;

  for (int k0 = 0; k0 < K; k0 += 32) {
    GLDS16(A + ga * K + k0 + ((ca & 3) << 3), As + ca * 8);
    GLDS16(BT + (size_t)(n0 + (ca >> 2)) * K + k0 + ((ca & 3) << 3), Bs + ca * 8);
    GLDS16(A + gb * K + k0 + ((cb & 3) << 3), As + cb * 8);
    GLDS16(BT + (size_t)(n0 + (cb >> 2)) * K + k0 + ((cb & 3) << 3), Bs + cb * 8);
    __syncthreads();
    short8 av[4], bv[4];
    const int ra = (wr << 6) + (l & 15);
    const int rb = (wc << 6) + (l & 15);
    const int ko = (l >> 4) << 3;
    #pragma unroll
    for (int mi = 0; mi < 4; mi++) av[mi] = *(const short8*)(As + (ra + mi * 16) * 32 + ko);
    #pragma unroll
    for (int ni = 0; ni < 4; ni++) bv[ni] = *(const short8*)(Bs + (rb + ni * 16) * 32 + ko);
    #pragma unroll
    for (int mi = 0; mi < 4; mi++)
      #pragma unroll
      for (int ni = 0; ni < 4; ni++)
        acc[mi][ni] = __builtin_amdgcn_mfma_f32_16x16x32_bf16(av[mi], bv[ni], acc[mi][ni], 0, 0, 0);
    __syncthreads();
  }
  const int lr = (l >> 4) << 2;
  const int lc = l & 15;
  #pragma unroll
  for (int mi = 0; mi < 4; mi++) {
    #pragma unroll
    for (int ni = 0; ni < 4; ni++) {
      const int col = n0 + (wc << 6) + ni * 16 + lc;
      const float bv2 = bias ? bias[col] : 0.0f;
      #pragma unroll
      for (int v = 0; v < 4; v++) {
        const size_t row = (size_t)m0 + (wr << 6) + mi * 16 + lr + v;
        float val = acc[mi][ni][v] + bv2;
        if (GELU_OUT) val = gelu_exact(val);
        if (BF16_OUT) ((u16*)Cout)[row * N + col] = f2bf(val);
        else          ((float*)Cout)[row * N + col] = val;
      }
    }
  }
}

// ---------------- per-expert residual-LN + gated scatter-accumulate ----------------

__global__ __launch_bounds__(256) void combine_sc_k(const float* __restrict__ U,
    const float* __restrict__ H2, const float* __restrict__ gate,
    const int* __restrict__ ridx, const int* __restrict__ cntp,
    const float* __restrict__ g, const float* __restrict__ b,
    float* __restrict__ Out, int eidx) {
  __shared__ float sm[4];
  int pos = blockIdx.x;
  if (pos >= *cntp) return;
  size_t tok = (size_t)ridx[pos];
  float gt = gate[tok * 8 + eidx];
  int t = threadIdx.x;
  const float* h = H2 + tok * 768;
  const float* u = U + (size_t)pos * 768;
  float v0 = h[t] + u[t], v1 = h[t + 256] + u[t + 256], v2 = h[t + 512] + u[t + 512];
  float mean = block_sum256(v0 + v1 + v2, sm) * (1.0f / 768.0f);
  float d0 = v0 - mean, d1 = v1 - mean, d2 = v2 - mean;
  float var = block_sum256(d0 * d0 + d1 * d1 + d2 * d2, sm) * (1.0f / 768.0f);
  float rstd = 1.0f / sqrtf(var + 1e-5f);
  float* o = Out + tok * 768;
  o[t]       += gt * (d0 * rstd * g[t]       + b[t]);
  o[t + 256] += gt * (d1 * rstd * g[t + 256] + b[t + 256]);
  o[t + 512] += gt * (d2 * rstd * g[t + 512] + b[t + 512]);
}

// ---------------- launch ----------------

extern "C" void kernel_launch(void* const* d_in, const int* in_sizes, int n_in,
                              void* d_out, int out_size, void* d_ws, size_t ws_size,
                              hipStream_t stream) {
  (void)in_sizes; (void)n_in; (void)out_size;
  const float* xin       = (const float*)d_in[0];
  const float* rnoise    = (const float*)d_in[1];
  const float* wq        = (const float*)d_in[2];
  const float* wk        = (const float*)d_in[3];
  const float* wv        = (const float*)d_in[4];
  const float* w_proj    = (const float*)d_in[5];
  const float* b_proj    = (const float*)d_in[6];
  const float* ln1_g     = (const float*)d_in[7];
  const float* ln1_b     = (const float*)d_in[8];
  const float* ln2_g     = (const float*)d_in[9];
  const float* ln2_b     = (const float*)d_in[10];
  const float* w_route   = (const float*)d_in[11];
  const float* b_route   = (const float*)d_in[12];
  const float* w_noise   = (const float*)d_in[13];
  const float* b_noise   = (const float*)d_in[14];
  const float* temp      = (const float*)d_in[15];
  const float* deep_w1   = (const float*)d_in[16];
  const float* deep_b1   = (const float*)d_in[17];
  const float* deep_w2   = (const float*)d_in[18];
  const float* deep_b2   = (const float*)d_in[19];
  const float* deep_w3   = (const float*)d_in[20];
  const float* deep_b3   = (const float*)d_in[21];
  const float* deep_ln_g = (const float*)d_in[22];
  const float* deep_ln_b = (const float*)d_in[23];
  const float* simple_w1 = (const float*)d_in[24];
  const float* simple_b1 = (const float*)d_in[25];
  const float* simple_w2 = (const float*)d_in[26];
  const float* simple_b2 = (const float*)d_in[27];
  const float* simple_ln_g = (const float*)d_in[28];
  const float* simple_ln_b = (const float*)d_in[29];

  char* ws = (char*)d_ws;
  size_t off = 0;
  auto alloc = [&](size_t bytes) -> char* {
    char* p = ws + off;
    off += (bytes + 255) & ~(size_t)255;
    return p;
  };
  float* wqkv = (float*)alloc(768ull * 2304 * 4);
  float* gate = (float*)alloc((size_t)TOK * 8 * 4);
  int*   counts = (int*)alloc(8 * 4);
  int*   idxbuf = (int*)alloc(8ull * TOK * 4);
  float* h2   = (float*)alloc((size_t)TOK * CDIM * 4);
  u16*   h2b  = (u16*)  alloc((size_t)TOK * CDIM * 2);
  float* x1   = (float*)alloc((size_t)TOK * CDIM * 4);
  float* hbuf = (float*)alloc((size_t)TOK * CDIM * 4);   // ln1 out; reused as Uc
  char*  big  = alloc((size_t)TOK * 2304 * 4 + (size_t)TOK * CDIM * 4); // QKV|O -> T1c|T2c
  float* QKV  = (float*)big;
  float* Obuf = (float*)(big + (size_t)TOK * 2304 * 4);
  u16* T1c = (u16*)big;
  u16* T2c = (u16*)(big + (size_t)TOK * FDIM * 2);
  float* Uc = hbuf;

  size_t wsz_all = (2ull * FDIM * CDIM + 2ull * FDIM * FDIM + 2ull * CDIM * FDIM +
                    6ull * FDIM * CDIM + 6ull * CDIM * FDIM) * 2 + 16 * 256;
  bool big_ws = ws_size >= off + wsz_all;
  u16 *dW1T = nullptr, *dW2T = nullptr, *dW3T = nullptr, *sW1T = nullptr, *sW2T = nullptr, *wbuf = nullptr;
  if (big_ws) {
    dW1T = (u16*)alloc(2ull * FDIM * CDIM * 2);
    dW2T = (u16*)alloc(2ull * FDIM * FDIM * 2);
    dW3T = (u16*)alloc(2ull * CDIM * FDIM * 2);
    sW1T = (u16*)alloc(6ull * FDIM * CDIM * 2);
    sW2T = (u16*)alloc(6ull * CDIM * FDIM * 2);
  } else {
    wbuf = (u16*)alloc((size_t)FDIM * FDIM * 2);
  }

  zero_counts<<<1, 64, 0, stream>>>(counts);
  pack_qkv<<<dim3((768 * 2304 + 255) / 256), 256, 0, stream>>>(wq, wk, wv, wqkv);
  if (big_ws) {
    transpose_cast<<<dim3(FDIM / 32, CDIM / 32, 2), 256, 0, stream>>>(deep_w1, dW1T, CDIM, FDIM);
    transpose_cast<<<dim3(FDIM / 32, FDIM / 32, 2), 256, 0, stream>>>(deep_w2, dW2T, FDIM, FDIM);
    transpose_cast<<<dim3(CDIM / 32, FDIM / 32, 2), 256, 0, stream>>>(deep_w3, dW3T, FDIM, CDIM);
    transpose_cast<<<dim3(FDIM / 32, CDIM / 32, 6), 256, 0, stream>>>(simple_w1, sW1T, CDIM, FDIM);
    transpose_cast<<<dim3(CDIM / 32, FDIM / 32, 6), 256, 0, stream>>>(simple_w2, sW2T, FDIM, CDIM);
  }
  ln1_k<<<TOK, 256, 0, stream>>>(xin, ln1_g, ln1_b, hbuf);
  gemm_f32<0><<<dim3(2304 / 128, TOK / 128), 256, 0, stream>>>(hbuf, wqkv, nullptr, nullptr, QKV, TOK, 2304, CDIM);
  attn_k<<<dim3(16, 12, 8), 256, 0, stream>>>(QKV, Obuf);
  gemm_f32<1><<<dim3(CDIM / 128, TOK / 128), 256, 0, stream>>>(Obuf, w_proj, b_proj, xin, x1, TOK, CDIM, CDIM);
  ln2_k<<<TOK, 256, 0, stream>>>(x1, ln2_g, ln2_b, h2, h2b, (float*)d_out);
  router_k<<<128, 256, 0, stream>>>(h2, w_route, b_route, w_noise, b_noise, rnoise, temp, gate);
  assign_k<<<TOK / 256, 256, 0, stream>>>(gate, counts, idxbuf);

  const dim3 gF(FDIM / 128, TOK / 128);   // 24 x 64 (max tiles; early exit on cnt)
  const dim3 gC(CDIM / 128, TOK / 128);   // 6 x 64

  for (int e = 0; e < 2; e++) {
    const int* cp = counts + e;
    const int* ri = idxbuf + e * TOK;
    const u16* W1;
    if (big_ws) W1 = dW1T + (size_t)e * FDIM * CDIM;
    else {
      transpose_cast<<<dim3(FDIM / 32, CDIM / 32, 1), 256, 0, stream>>>(deep_w1 + (size_t)e * CDIM * FDIM, wbuf, CDIM, FDIM);
      W1 = wbuf;
    }
    gemm_bf16_cnt<1, 1, 1><<<gF, 256, 0, stream>>>(h2b, W1, deep_b1 + e * FDIM, (void*)T1c, ri, cp, FDIM, CDIM);
    const u16* W2;
    if (big_ws) W2 = dW2T + (size_t)e * FDIM * FDIM;
    else {
      transpose_cast<<<dim3(FDIM / 32, FDIM / 32, 1), 256, 0, stream>>>(deep_w2 + (size_t)e * FDIM * FDIM, wbuf, FDIM, FDIM);
      W2 = wbuf;
    }
    gemm_bf16_cnt<1, 1, 0><<<gF, 256, 0, stream>>>(T1c, W2, deep_b2 + e * FDIM, (void*)T2c, ri, cp, FDIM, FDIM);
    const u16* W3;
    if (big_ws) W3 = dW3T + (size_t)e * CDIM * FDIM;
    else {
      transpose_cast<<<dim3(CDIM / 32, FDIM / 32, 1), 256, 0, stream>>>(deep_w3 + (size_t)e * FDIM * CDIM, wbuf, FDIM, CDIM);
      W3 = wbuf;
    }
    gemm_bf16_cnt<0, 0, 0><<<gC, 256, 0, stream>>>(T2c, W3, deep_b3 + e * CDIM, (void*)Uc, ri, cp, CDIM, FDIM);
    combine_sc_k<<<TOK, 256, 0, stream>>>(Uc, h2, gate, ri, cp, deep_ln_g + e * CDIM, deep_ln_b + e * CDIM, (float*)d_out, e);
  }
  for (int e = 0; e < 6; e++) {
    const int* cp = counts + 2 + e;
    const int* ri = idxbuf + (size_t)(2 + e) * TOK;
    const u16* W1;
    if (big_ws) W1 = sW1T + (size_t)e * FDIM * CDIM;
    else {
      transpose_cast<<<dim3(FDIM / 32, CDIM / 32, 1), 256, 0, stream>>>(simple_w1 + (size_t)e * CDIM * FDIM, wbuf, CDIM, FDIM);
      W1 = wbuf;
    }
    gemm_bf16_cnt<1, 1, 1><<<gF, 256, 0, stream>>>(h2b, W1, simple_b1 + e * FDIM, (void*)T1c, ri, cp, FDIM, CDIM);
    const u16* W2;
    if (big_ws) W2 = sW2T + (size_t)e * CDIM * FDIM;
    else {
      transpose_cast<<<dim3(CDIM / 32, FDIM / 32, 1), 256, 0, stream>>>(simple_w2 + (size_t)e * FDIM * CDIM, wbuf, FDIM, CDIM);
      W2 = wbuf;
    }
    gemm_bf16_cnt<0, 0, 0><<<gC, 256, 0, stream>>>(T1c, W2, simple_b2 + e * CDIM, (void*)Uc, ri, cp, CDIM, FDIM);
    combine_sc_k<<<TOK, 256, 0, stream>>>(Uc, h2, gate, ri, cp, simple_ln_g + e * CDIM, simple_ln_b + e * CDIM, (float*)d_out, 2 + e);
  }
}

// Round 6
// 2106.399 us; speedup vs baseline: 1.4348x; 1.1388x over previous
//
#include <hip/hip_runtime.h>
#include <cstdint>
#include <cstddef>
#include <math.h>

typedef uint16_t u16;
typedef __attribute__((ext_vector_type(8))) short short8;
typedef __attribute__((ext_vector_type(4))) float f32x4;

#define TOK 8192
#define CDIM 768
#define FDIM 3072

#define GLDS16(g, l) __builtin_amdgcn_global_load_lds((const __attribute__((address_space(1))) uint32_t*)(g), (__attribute__((address_space(3))) uint32_t*)(l), 16, 0, 0)

__device__ __forceinline__ u16 f2bf(float f) {
  union { float f; uint32_t u; } v; v.f = f;
  uint32_t u = v.u;
  return (u16)((u + 0x7FFFu + ((u >> 16) & 1u)) >> 16);
}

__device__ __forceinline__ void split2(float y, u16& hi, u16& lo) {
  u16 h = f2bf(y);
  union { uint32_t u; float f; } hf; hf.u = ((uint32_t)h) << 16;
  hi = h;
  lo = f2bf(y - hf.f);
}

__device__ __forceinline__ float gelu_exact(float z) {
  return 0.5f * z * (1.0f + erff(z * 0.70710678118654752f));
}

__device__ __forceinline__ float softplus_f(float x) {
  return (x > 0.0f) ? (x + log1pf(expf(-x))) : log1pf(expf(x));
}

__device__ __forceinline__ float block_sum256(float v, float* sm) {
  #pragma unroll
  for (int m = 1; m < 64; m <<= 1) v += __shfl_xor(v, m);
  int w = threadIdx.x >> 6;
  if ((threadIdx.x & 63) == 0) sm[w] = v;
  __syncthreads();
  v = sm[0] + sm[1] + sm[2] + sm[3];
  __syncthreads();
  return v;
}

// ---------------- weight prep ----------------

__global__ __launch_bounds__(256) void pack_qkv(const float* __restrict__ wq,
    const float* __restrict__ wk, const float* __restrict__ wv, float* __restrict__ W) {
  int id = blockIdx.x * 256 + threadIdx.x;
  if (id >= 768 * 2304) return;
  int c = id / 2304, j = id - c * 2304;
  int which = j / 768, jj = j - which * 768;
  int hh = jj >> 6, d = jj & 63;
  const float* src = (which == 0) ? wq : (which == 1 ? wk : wv);
  W[id] = src[((size_t)hh * 768 + c) * 64 + d];
}

// src [K][N] fp32 -> dst [N][K] bf16 (single, for expert weights)
__global__ __launch_bounds__(256) void transpose_cast(const float* __restrict__ src,
    u16* __restrict__ dst, int K, int N) {
  __shared__ float t[32][33];
  size_t eoff = (size_t)blockIdx.z * K * N;
  const float* S = src + eoff;
  u16* D = dst + eoff;
  int n0 = blockIdx.x * 32, k0 = blockIdx.y * 32;
  int tc = threadIdx.x & 31, tr = threadIdx.x >> 5;
  #pragma unroll
  for (int r = tr; r < 32; r += 8) t[r][tc] = S[(size_t)(k0 + r) * N + n0 + tc];
  __syncthreads();
  #pragma unroll
  for (int r = tr; r < 32; r += 8) D[(size_t)(n0 + r) * K + k0 + tc] = f2bf(t[tc][r]);
}

// src [K][N] fp32 -> dst [N][K] bf16 hi + lo (split, for accuracy-critical weights)
__global__ __launch_bounds__(256) void transpose_split_k(const float* __restrict__ src,
    u16* __restrict__ Dhi, u16* __restrict__ Dlo, int K, int N) {
  __shared__ float t[32][33];
  int n0 = blockIdx.x * 32, k0 = blockIdx.y * 32;
  int tc = threadIdx.x & 31, tr = threadIdx.x >> 5;
  #pragma unroll
  for (int r = tr; r < 32; r += 8) t[r][tc] = src[(size_t)(k0 + r) * N + n0 + tc];
  __syncthreads();
  #pragma unroll
  for (int r = tr; r < 32; r += 8) {
    u16 hi, lo;
    split2(t[tc][r], hi, lo);
    size_t o = (size_t)(n0 + r) * K + k0 + tc;
    Dhi[o] = hi; Dlo[o] = lo;
  }
}

// ---------------- layernorms ----------------

__global__ __launch_bounds__(256) void ln1_split_k(const float* __restrict__ X,
    const float* __restrict__ g, const float* __restrict__ b,
    u16* __restrict__ Yhi, u16* __restrict__ Ylo) {
  __shared__ float sm[4];
  size_t row = blockIdx.x;
  const float* x = X + row * 768;
  int t = threadIdx.x;
  float v0 = x[t], v1 = x[t + 256], v2 = x[t + 512];
  float mean = block_sum256(v0 + v1 + v2, sm) * (1.0f / 768.0f);
  float d0 = v0 - mean, d1 = v1 - mean, d2 = v2 - mean;
  float var = block_sum256(d0 * d0 + d1 * d1 + d2 * d2, sm) * (1.0f / 768.0f);
  float rstd = 1.0f / sqrtf(var + 1e-5f);
  float y0 = d0 * rstd * g[t]       + b[t];
  float y1 = d1 * rstd * g[t + 256] + b[t + 256];
  float y2 = d2 * rstd * g[t + 512] + b[t + 512];
  u16 h, lo;
  split2(y0, h, lo); Yhi[row * 768 + t]       = h; Ylo[row * 768 + t]       = lo;
  split2(y1, h, lo); Yhi[row * 768 + t + 256] = h; Ylo[row * 768 + t + 256] = lo;
  split2(y2, h, lo); Yhi[row * 768 + t + 512] = h; Ylo[row * 768 + t + 512] = lo;
}

__global__ __launch_bounds__(256) void ln2_k(const float* __restrict__ X,
    const float* __restrict__ g, const float* __restrict__ b, float* __restrict__ H2,
    u16* __restrict__ H2b, float* __restrict__ OutInit) {
  __shared__ float sm[4];
  size_t row = blockIdx.x;
  const float* x = X + row * 768;
  int t = threadIdx.x;
  float v0 = x[t], v1 = x[t + 256], v2 = x[t + 512];
  float mean = block_sum256(v0 + v1 + v2, sm) * (1.0f / 768.0f);
  float d0 = v0 - mean, d1 = v1 - mean, d2 = v2 - mean;
  float var = block_sum256(d0 * d0 + d1 * d1 + d2 * d2, sm) * (1.0f / 768.0f);
  float rstd = 1.0f / sqrtf(var + 1e-5f);
  float y0 = d0 * rstd * g[t]       + b[t];
  float y1 = d1 * rstd * g[t + 256] + b[t + 256];
  float y2 = d2 * rstd * g[t + 512] + b[t + 512];
  float* h2r = H2 + row * 768;
  u16* hbr = H2b + row * 768;
  float* outr = OutInit + row * 768;
  h2r[t] = y0; h2r[t + 256] = y1; h2r[t + 512] = y2;
  hbr[t] = f2bf(y0); hbr[t + 256] = f2bf(y1); hbr[t + 512] = f2bf(y2);
  outr[t] = v0; outr[t + 256] = v1; outr[t + 512] = v2;
}

// ---------------- bf16x3 split MFMA GEMM (pre-router path; near-fp32 accuracy) ----------------
// C = (Ahi+Alo)·(Bhi+Blo)^T dropping lo·lo. A [M,K] hi/lo bf16, BT [N,K] hi/lo bf16.

template<int BIAS_RES>
__global__ __launch_bounds__(256) void gemm_bf16x3(
    const u16* __restrict__ Ahi, const u16* __restrict__ Alo,
    const u16* __restrict__ Bhi, const u16* __restrict__ Blo,
    const float* __restrict__ bias, const float* __restrict__ Res,
    float* __restrict__ Cout, int N, int K) {
  __shared__ __align__(16) u16 Ah[128 * 32];
  __shared__ __align__(16) u16 Al[128 * 32];
  __shared__ __align__(16) u16 Bh[128 * 32];
  __shared__ __align__(16) u16 Bl[128 * 32];
  const int tid = threadIdx.x;
  const int l = tid & 63, w = tid >> 6;
  const int m0 = blockIdx.y << 7, n0 = blockIdx.x << 7;
  const int wr = w >> 1, wc = w & 1;
  f32x4 zero = {0.0f, 0.0f, 0.0f, 0.0f};
  f32x4 acc[4][4];
  #pragma unroll
  for (int mi = 0; mi < 4; mi++)
    #pragma unroll
    for (int ni = 0; ni < 4; ni++) acc[mi][ni] = zero;

  const int c0 = (w << 7) + l, c1 = c0 + 64;
  for (int k0 = 0; k0 < K; k0 += 32) {
    {
      size_t ao0 = (size_t)(m0 + (c0 >> 2)) * K + k0 + ((c0 & 3) << 3);
      size_t bo0 = (size_t)(n0 + (c0 >> 2)) * K + k0 + ((c0 & 3) << 3);
      GLDS16(Ahi + ao0, Ah + c0 * 8);
      GLDS16(Alo + ao0, Al + c0 * 8);
      GLDS16(Bhi + bo0, Bh + c0 * 8);
      GLDS16(Blo + bo0, Bl + c0 * 8);
      size_t ao1 = (size_t)(m0 + (c1 >> 2)) * K + k0 + ((c1 & 3) << 3);
      size_t bo1 = (size_t)(n0 + (c1 >> 2)) * K + k0 + ((c1 & 3) << 3);
      GLDS16(Ahi + ao1, Ah + c1 * 8);
      GLDS16(Alo + ao1, Al + c1 * 8);
      GLDS16(Bhi + bo1, Bh + c1 * 8);
      GLDS16(Blo + bo1, Bl + c1 * 8);
    }
    __syncthreads();
    short8 avh[4], avl[4], bvh[4], bvl[4];
    const int ra = (wr << 6) + (l & 15);
    const int rb = (wc << 6) + (l & 15);
    const int ko = (l >> 4) << 3;
    #pragma unroll
    for (int mi = 0; mi < 4; mi++) {
      avh[mi] = *(const short8*)(Ah + (ra + mi * 16) * 32 + ko);
      avl[mi] = *(const short8*)(Al + (ra + mi * 16) * 32 + ko);
    }
    #pragma unroll
    for (int ni = 0; ni < 4; ni++) {
      bvh[ni] = *(const short8*)(Bh + (rb + ni * 16) * 32 + ko);
      bvl[ni] = *(const short8*)(Bl + (rb + ni * 16) * 32 + ko);
    }
    #pragma unroll
    for (int mi = 0; mi < 4; mi++)
      #pragma unroll
      for (int ni = 0; ni < 4; ni++) {
        acc[mi][ni] = __builtin_amdgcn_mfma_f32_16x16x32_bf16(avl[mi], bvh[ni], acc[mi][ni], 0, 0, 0);
        acc[mi][ni] = __builtin_amdgcn_mfma_f32_16x16x32_bf16(avh[mi], bvl[ni], acc[mi][ni], 0, 0, 0);
        acc[mi][ni] = __builtin_amdgcn_mfma_f32_16x16x32_bf16(avh[mi], bvh[ni], acc[mi][ni], 0, 0, 0);
      }
    __syncthreads();
  }
  const int lr = (l >> 4) << 2;
  const int lc = l & 15;
  #pragma unroll
  for (int mi = 0; mi < 4; mi++) {
    #pragma unroll
    for (int ni = 0; ni < 4; ni++) {
      const int col = n0 + (wc << 6) + ni * 16 + lc;
      const float bv2 = BIAS_RES ? bias[col] : 0.0f;
      #pragma unroll
      for (int v = 0; v < 4; v++) {
        const size_t row = (size_t)m0 + (wr << 6) + mi * 16 + lr + v;
        float val = acc[mi][ni][v] + bv2;
        if (BIAS_RES) val += Res[row * N + col];
        Cout[row * N + col] = val;
      }
    }
  }
}

// ---------------- fp32 causal flash attention ----------------
// QKV [8192][2304] (q|k|v head-major 64); out split bf16 hi/lo [8192][768]

__global__ __launch_bounds__(256) void attn_k(const float* __restrict__ QKV,
    u16* __restrict__ Ohi, u16* __restrict__ Olo) {
  __shared__ __align__(16) float Qs[64 * 68];
  __shared__ __align__(16) float Ks[64 * 68];   // reused as P buffer after scores
  __shared__ __align__(16) float Vs[64 * 64];
  const int qt = (int)gridDim.x - 1 - (int)blockIdx.x;  // big blocks first
  const int hh = blockIdx.y, bb = blockIdx.z;
  const int tid = threadIdx.x, tx = tid & 15, ty = tid >> 4;
  const int q0 = qt * 64;
  const float scale = 0.03608439182435161f;  // 768^-0.5
  {
    int r = tid & 63, kg = (tid >> 6) * 16;
    const float* g = QKV + ((size_t)bb * 1024 + q0 + r) * 2304 + hh * 64 + kg;
    #pragma unroll
    for (int jj = 0; jj < 16; jj += 4) {
      float4 p = *(const float4*)(g + jj);
      Qs[(kg + jj + 0) * 68 + r] = p.x;
      Qs[(kg + jj + 1) * 68 + r] = p.y;
      Qs[(kg + jj + 2) * 68 + r] = p.z;
      Qs[(kg + jj + 3) * 68 + r] = p.w;
    }
  }
  float o[4][4] = {};
  float mrun[4], lrun[4] = {};
  #pragma unroll
  for (int i = 0; i < 4; i++) mrun[i] = -__builtin_inff();

  for (int st = 0; st <= qt; st++) {
    __syncthreads();
    {
      int r = tid & 63, kg = (tid >> 6) * 16;
      const float* g = QKV + ((size_t)bb * 1024 + st * 64 + r) * 2304 + 768 + hh * 64 + kg;
      #pragma unroll
      for (int jj = 0; jj < 16; jj += 4) {
        float4 p = *(const float4*)(g + jj);
        Ks[(kg + jj + 0) * 68 + r] = p.x;
        Ks[(kg + jj + 1) * 68 + r] = p.y;
        Ks[(kg + jj + 2) * 68 + r] = p.z;
        Ks[(kg + jj + 3) * 68 + r] = p.w;
      }
      #pragma unroll
      for (int kk = 0; kk < 4; kk++) {
        int f = tid + kk * 256;
        int s = f >> 4, j4 = (f & 15) << 2;
        *(float4*)&Vs[(s << 6) + j4] =
            *(const float4*)(QKV + ((size_t)bb * 1024 + st * 64 + s) * 2304 + 1536 + hh * 64 + j4);
      }
    }
    __syncthreads();
    float sc[4][4] = {};
    #pragma unroll 4
    for (int k = 0; k < 64; k++) {
      float4 qv = *(const float4*)&Qs[k * 68 + (ty << 2)];
      float4 kv = *(const float4*)&Ks[k * 68 + (tx << 2)];
      float qa[4] = {qv.x, qv.y, qv.z, qv.w};
      float kb[4] = {kv.x, kv.y, kv.z, kv.w};
      #pragma unroll
      for (int i = 0; i < 4; i++)
        #pragma unroll
        for (int j = 0; j < 4; j++)
          sc[i][j] = fmaf(qa[i], kb[j], sc[i][j]);
    }
    const bool diag = (st == qt);
    float mt[4];
    #pragma unroll
    for (int i = 0; i < 4; i++) {
      float mrow = -3.0e38f;
      #pragma unroll
      for (int j = 0; j < 4; j++) {
        float v = sc[i][j] * scale;
        if (diag && ((tx << 2) + j > (ty << 2) + i)) v = -__builtin_inff();
        sc[i][j] = v;
        mrow = fmaxf(mrow, v);
      }
      mt[i] = mrow;
    }
    #pragma unroll
    for (int mk = 1; mk < 16; mk <<= 1)
      #pragma unroll
      for (int i = 0; i < 4; i++) mt[i] = fmaxf(mt[i], __shfl_xor(mt[i], mk));
    float sfv[4], psum[4];
    #pragma unroll
    for (int i = 0; i < 4; i++) {
      float mnew = fmaxf(mrun[i], mt[i]);
      sfv[i] = expf(mrun[i] - mnew);
      mrun[i] = mnew;
      float rs = 0.0f;
      #pragma unroll
      for (int j = 0; j < 4; j++) {
        float pv = expf(sc[i][j] - mnew);
        sc[i][j] = pv;
        rs += pv;
      }
      psum[i] = rs;
    }
    #pragma unroll
    for (int mk = 1; mk < 16; mk <<= 1)
      #pragma unroll
      for (int i = 0; i < 4; i++) psum[i] += __shfl_xor(psum[i], mk);
    #pragma unroll
    for (int i = 0; i < 4; i++) {
      lrun[i] = lrun[i] * sfv[i] + psum[i];
      #pragma unroll
      for (int j = 0; j < 4; j++) o[i][j] *= sfv[i];
    }
    __syncthreads();   // all threads done reading K from Ks
    {
      float pt[4][4];
      #pragma unroll
      for (int i = 0; i < 4; i++)
        #pragma unroll
        for (int j = 0; j < 4; j++) pt[j][i] = sc[i][j];
      #pragma unroll
      for (int j = 0; j < 4; j++)
        *(float4*)&Ks[((tx << 2) + j) * 68 + (ty << 2)] = *(const float4*)&pt[j][0];
    }
    __syncthreads();
    #pragma unroll 4
    for (int s2 = 0; s2 < 64; s2++) {
      float4 pv = *(const float4*)&Ks[s2 * 68 + (ty << 2)];
      float4 vv = *(const float4*)&Vs[(s2 << 6) + (tx << 2)];
      float pa[4] = {pv.x, pv.y, pv.z, pv.w};
      float vb4[4] = {vv.x, vv.y, vv.z, vv.w};
      #pragma unroll
      for (int i = 0; i < 4; i++)
        #pragma unroll
        for (int j = 0; j < 4; j++)
          o[i][j] = fmaf(pa[i], vb4[j], o[i][j]);
    }
  }
  #pragma unroll
  for (int i = 0; i < 4; i++) {
    float inv = 1.0f / lrun[i];
    ushort4 vh, vl;
    u16 h0, l0;
    split2(o[i][0] * inv, h0, l0); vh.x = h0; vl.x = l0;
    split2(o[i][1] * inv, h0, l0); vh.y = h0; vl.y = l0;
    split2(o[i][2] * inv, h0, l0); vh.z = h0; vl.z = l0;
    split2(o[i][3] * inv, h0, l0); vh.w = h0; vl.w = l0;
    size_t base = ((size_t)bb * 1024 + q0 + (ty << 2) + i) * 768 + hh * 64 + (tx << 2);
    *(ushort4*)&Ohi[base] = vh;
    *(ushort4*)&Olo[base] = vl;
  }
}

// ---------------- router (fp32, exact top-2 semantics) ----------------

__global__ __launch_bounds__(256) void router_k(const float* __restrict__ h2,
    const float* __restrict__ w_route, const float* __restrict__ b_route,
    const float* __restrict__ w_noise, const float* __restrict__ b_noise,
    const float* __restrict__ rnoise, const float* __restrict__ tp, float* __restrict__ gate) {
  __shared__ float Wl[6144], Wn[6144];
  int t = threadIdx.x;
  for (int i = t; i < 1536; i += 256) {
    ((float4*)Wl)[i] = ((const float4*)w_route)[i];
    ((float4*)Wn)[i] = ((const float4*)w_noise)[i];
  }
  __syncthreads();
  int tok = blockIdx.x * 64 + (t >> 2);
  int sub = t & 3;
  const float* hr = h2 + (size_t)tok * 768;
  float aL[8] = {}, aN[8] = {};
  for (int i = 0; i < 192; i++) {
    int c = sub + (i << 2);
    float hv = hr[c];
    const float* wl = &Wl[c * 8];
    const float* wn = &Wn[c * 8];
    #pragma unroll
    for (int e = 0; e < 8; e++) { aL[e] = fmaf(hv, wl[e], aL[e]); aN[e] = fmaf(hv, wn[e], aN[e]); }
  }
  #pragma unroll
  for (int e = 0; e < 8; e++) {
    aL[e] += __shfl_xor(aL[e], 1); aL[e] += __shfl_xor(aL[e], 2);
    aN[e] += __shfl_xor(aN[e], 1); aN[e] += __shfl_xor(aN[e], 2);
  }
  if (sub == 0) {
    float temp = fminf(fmaxf(tp[0], 0.5f), 2.0f);
    float noisy[8];
    #pragma unroll
    for (int e = 0; e < 8; e++) {
      float lg = aL[e] + b_route[e];
      float ns = softplus_f(aN[e] + b_noise[e]);
      noisy[e] = lg + temp * rnoise[(size_t)tok * 8 + e] * ns;
    }
    int i1 = 0; float v1 = noisy[0];
    #pragma unroll
    for (int e = 1; e < 8; e++) if (noisy[e] > v1) { v1 = noisy[e]; i1 = e; }
    int i2 = -1; float v2 = 0.0f;
    #pragma unroll
    for (int e = 0; e < 8; e++) {
      if (e == i1) continue;
      if (i2 < 0 || noisy[e] > v2) { v2 = noisy[e]; i2 = e; }
    }
    float e2 = expf(v2 - v1);
    float denom = 1.0f + e2;
    float* gr = gate + (size_t)tok * 8;
    #pragma unroll
    for (int e = 0; e < 8; e++) gr[e] = 0.0f;
    gr[i1] = 1.0f / denom;
    gr[i2] = e2 / denom;
  }
}

// ---------------- routing compaction ----------------

__global__ void zero_counts(int* counts) {
  if (threadIdx.x < 8) counts[threadIdx.x] = 0;
}

__global__ __launch_bounds__(256) void assign_k(const float* __restrict__ gate,
    int* __restrict__ counts, int* __restrict__ idxbuf) {
  int tok = blockIdx.x * 256 + threadIdx.x;
  const float* gr = gate + (size_t)tok * 8;
  #pragma unroll
  for (int e = 0; e < 8; e++) {
    if (gr[e] > 0.0f) {
      int s = atomicAdd(&counts[e], 1);
      idxbuf[e * TOK + s] = tok;
    }
  }
}

// ---------------- bf16 MFMA GEMM over compacted rows ----------------

template<int GELU_OUT, int BF16_OUT, int GATHER>
__global__ __launch_bounds__(256) void gemm_bf16_cnt(const u16* __restrict__ A,
    const u16* __restrict__ BT, const float* __restrict__ bias, void* __restrict__ Cout,
    const int* __restrict__ ridx, const int* __restrict__ cntp, int N, int K) {
  const int cnt = *cntp;
  const int mtiles = (cnt + 127) >> 7;
  if ((int)blockIdx.y >= mtiles) return;
  __shared__ __align__(16) u16 As[128 * 32];
  __shared__ __align__(16) u16 Bs[128 * 32];
  const int tid = threadIdx.x;
  const int l = tid & 63, w = tid >> 6;
  const int m0 = blockIdx.y << 7, n0 = blockIdx.x << 7;
  const int wr = w >> 1, wc = w & 1;
  const int ca = (w << 7) + l, cb = ca + 64;
  const int ra_ = m0 + (ca >> 2), rb_ = m0 + (cb >> 2);
  size_t ga, gb;
  if (GATHER) {
    ga = (size_t)ridx[ra_ < cnt ? ra_ : 0];
    gb = (size_t)ridx[rb_ < cnt ? rb_ : 0];
  } else {
    ga = (size_t)ra_; gb = (size_t)rb_;
  }
  f32x4 zero = {0.0f, 0.0f, 0.0f, 0.0f};
  f32x4 acc[4][4];
  #pragma unroll
  for (int mi = 0; mi < 4; mi++)
    #pragma unroll
    for (int ni = 0; ni < 4; ni++) acc[mi][ni] = zero;

  for (int k0 = 0; k0 < K; k0 += 32) {
    GLDS16(A + ga * K + k0 + ((ca & 3) << 3), As + ca * 8);
    GLDS16(BT + (size_t)(n0 + (ca >> 2)) * K + k0 + ((ca & 3) << 3), Bs + ca * 8);
    GLDS16(A + gb * K + k0 + ((cb & 3) << 3), As + cb * 8);
    GLDS16(BT + (size_t)(n0 + (cb >> 2)) * K + k0 + ((cb & 3) << 3), Bs + cb * 8);
    __syncthreads();
    short8 av[4], bv[4];
    const int ra = (wr << 6) + (l & 15);
    const int rb = (wc << 6) + (l & 15);
    const int ko = (l >> 4) << 3;
    #pragma unroll
    for (int mi = 0; mi < 4; mi++) av[mi] = *(const short8*)(As + (ra + mi * 16) * 32 + ko);
    #pragma unroll
    for (int ni = 0; ni < 4; ni++) bv[ni] = *(const short8*)(Bs + (rb + ni * 16) * 32 + ko);
    #pragma unroll
    for (int mi = 0; mi < 4; mi++)
      #pragma unroll
      for (int ni = 0; ni < 4; ni++)
        acc[mi][ni] = __builtin_amdgcn_mfma_f32_16x16x32_bf16(av[mi], bv[ni], acc[mi][ni], 0, 0, 0);
    __syncthreads();
  }
  const int lr = (l >> 4) << 2;
  const int lc = l & 15;
  #pragma unroll
  for (int mi = 0; mi < 4; mi++) {
    #pragma unroll
    for (int ni = 0; ni < 4; ni++) {
      const int col = n0 + (wc << 6) + ni * 16 + lc;
      const float bv2 = bias ? bias[col] : 0.0f;
      #pragma unroll
      for (int v = 0; v < 4; v++) {
        const size_t row = (size_t)m0 + (wr << 6) + mi * 16 + lr + v;
        float val = acc[mi][ni][v] + bv2;
        if (GELU_OUT) val = gelu_exact(val);
        if (BF16_OUT) ((u16*)Cout)[row * N + col] = f2bf(val);
        else          ((float*)Cout)[row * N + col] = val;
      }
    }
  }
}

// ---------------- per-expert residual-LN + gated scatter-accumulate ----------------

__global__ __launch_bounds__(256) void combine_sc_k(const float* __restrict__ U,
    const float* __restrict__ H2, const float* __restrict__ gate,
    const int* __restrict__ ridx, const int* __restrict__ cntp,
    const float* __restrict__ g, const float* __restrict__ b,
    float* __restrict__ Out, int eidx) {
  __shared__ float sm[4];
  int pos = blockIdx.x;
  if (pos >= *cntp) return;
  size_t tok = (size_t)ridx[pos];
  float gt = gate[tok * 8 + eidx];
  int t = threadIdx.x;
  const float* h = H2 + tok * 768;
  const float* u = U + (size_t)pos * 768;
  float v0 = h[t] + u[t], v1 = h[t + 256] + u[t + 256], v2 = h[t + 512] + u[t + 512];
  float mean = block_sum256(v0 + v1 + v2, sm) * (1.0f / 768.0f);
  float d0 = v0 - mean, d1 = v1 - mean, d2 = v2 - mean;
  float var = block_sum256(d0 * d0 + d1 * d1 + d2 * d2, sm) * (1.0f / 768.0f);
  float rstd = 1.0f / sqrtf(var + 1e-5f);
  float* o = Out + tok * 768;
  o[t]       += gt * (d0 * rstd * g[t]       + b[t]);
  o[t + 256] += gt * (d1 * rstd * g[t + 256] + b[t + 256]);
  o[t + 512] += gt * (d2 * rstd * g[t + 512] + b[t + 512]);
}

// ---------------- launch ----------------

extern "C" void kernel_launch(void* const* d_in, const int* in_sizes, int n_in,
                              void* d_out, int out_size, void* d_ws, size_t ws_size,
                              hipStream_t stream) {
  (void)in_sizes; (void)n_in; (void)out_size;
  const float* xin       = (const float*)d_in[0];
  const float* rnoise    = (const float*)d_in[1];
  const float* wq        = (const float*)d_in[2];
  const float* wk        = (const float*)d_in[3];
  const float* wv        = (const float*)d_in[4];
  const float* w_proj    = (const float*)d_in[5];
  const float* b_proj    = (const float*)d_in[6];
  const float* ln1_g     = (const float*)d_in[7];
  const float* ln1_b     = (const float*)d_in[8];
  const float* ln2_g     = (const float*)d_in[9];
  const float* ln2_b     = (const float*)d_in[10];
  const float* w_route   = (const float*)d_in[11];
  const float* b_route   = (const float*)d_in[12];
  const float* w_noise   = (const float*)d_in[13];
  const float* b_noise   = (const float*)d_in[14];
  const float* temp      = (const float*)d_in[15];
  const float* deep_w1   = (const float*)d_in[16];
  const float* deep_b1   = (const float*)d_in[17];
  const float* deep_w2   = (const float*)d_in[18];
  const float* deep_b2   = (const float*)d_in[19];
  const float* deep_w3   = (const float*)d_in[20];
  const float* deep_b3   = (const float*)d_in[21];
  const float* deep_ln_g = (const float*)d_in[22];
  const float* deep_ln_b = (const float*)d_in[23];
  const float* simple_w1 = (const float*)d_in[24];
  const float* simple_b1 = (const float*)d_in[25];
  const float* simple_w2 = (const float*)d_in[26];
  const float* simple_b2 = (const float*)d_in[27];
  const float* simple_ln_g = (const float*)d_in[28];
  const float* simple_ln_b = (const float*)d_in[29];

  char* ws = (char*)d_ws;
  size_t off = 0;
  auto alloc = [&](size_t bytes) -> char* {
    char* p = ws + off;
    off += (bytes + 255) & ~(size_t)255;
    return p;
  };
  float* gate = (float*)alloc((size_t)TOK * 8 * 4);
  int*   counts = (int*)alloc(8 * 4);
  int*   idxbuf = (int*)alloc(8ull * TOK * 4);
  float* h2   = (float*)alloc((size_t)TOK * CDIM * 4);
  u16*   h2b  = (u16*)  alloc((size_t)TOK * CDIM * 2);
  float* x1   = (float*)alloc((size_t)TOK * CDIM * 4);     // reused as Uc in expert phase
  // big region: QKV fp32 | Ohi | Olo  ->  later T1c | T2c
  char*  big  = alloc((size_t)TOK * 2304 * 4 + (size_t)TOK * CDIM * 2 * 2);
  float* QKV  = (float*)big;
  float* wqkv = (float*)big;                               // prep-phase alias (dead before QKV write)
  u16*   Ohi  = (u16*)(big + (size_t)TOK * 2304 * 4);
  u16*   Olo  = Ohi + (size_t)TOK * CDIM;
  u16*   T1c  = (u16*)big;
  u16*   T2c  = (u16*)(big + (size_t)TOK * FDIM * 2);
  float* Uc   = x1;
  u16* WqT_hi = (u16*)alloc(2304ull * CDIM * 2);
  u16* WqT_lo = (u16*)alloc(2304ull * CDIM * 2);
  u16* WpT_hi = (u16*)alloc((size_t)CDIM * CDIM * 2);
  u16* WpT_lo = (u16*)alloc((size_t)CDIM * CDIM * 2);
  u16* Hhi    = (u16*)alloc((size_t)TOK * CDIM * 2);
  u16* Hlo    = (u16*)alloc((size_t)TOK * CDIM * 2);

  size_t wsz_all = (2ull * FDIM * CDIM + 2ull * FDIM * FDIM + 2ull * CDIM * FDIM +
                    6ull * FDIM * CDIM + 6ull * CDIM * FDIM) * 2 + 16 * 256;
  bool big_ws = ws_size >= off + wsz_all;
  u16 *dW1T = nullptr, *dW2T = nullptr, *dW3T = nullptr, *sW1T = nullptr, *sW2T = nullptr, *wbuf = nullptr;
  if (big_ws) {
    dW1T = (u16*)alloc(2ull * FDIM * CDIM * 2);
    dW2T = (u16*)alloc(2ull * FDIM * FDIM * 2);
    dW3T = (u16*)alloc(2ull * CDIM * FDIM * 2);
    sW1T = (u16*)alloc(6ull * FDIM * CDIM * 2);
    sW2T = (u16*)alloc(6ull * CDIM * FDIM * 2);
  } else {
    wbuf = (u16*)alloc((size_t)FDIM * FDIM * 2);
  }

  zero_counts<<<1, 64, 0, stream>>>(counts);
  // prep: pack qkv fp32 (into big), then split-transpose; w_proj split-transpose
  pack_qkv<<<dim3((768 * 2304 + 255) / 256), 256, 0, stream>>>(wq, wk, wv, wqkv);
  transpose_split_k<<<dim3(2304 / 32, CDIM / 32), 256, 0, stream>>>(wqkv, WqT_hi, WqT_lo, CDIM, 2304);
  transpose_split_k<<<dim3(CDIM / 32, CDIM / 32), 256, 0, stream>>>(w_proj, WpT_hi, WpT_lo, CDIM, CDIM);
  if (big_ws) {
    transpose_cast<<<dim3(FDIM / 32, CDIM / 32, 2), 256, 0, stream>>>(deep_w1, dW1T, CDIM, FDIM);
    transpose_cast<<<dim3(FDIM / 32, FDIM / 32, 2), 256, 0, stream>>>(deep_w2, dW2T, FDIM, FDIM);
    transpose_cast<<<dim3(CDIM / 32, FDIM / 32, 2), 256, 0, stream>>>(deep_w3, dW3T, FDIM, CDIM);
    transpose_cast<<<dim3(FDIM / 32, CDIM / 32, 6), 256, 0, stream>>>(simple_w1, sW1T, CDIM, FDIM);
    transpose_cast<<<dim3(CDIM / 32, FDIM / 32, 6), 256, 0, stream>>>(simple_w2, sW2T, FDIM, CDIM);
  }
  ln1_split_k<<<TOK, 256, 0, stream>>>(xin, ln1_g, ln1_b, Hhi, Hlo);
  gemm_bf16x3<0><<<dim3(2304 / 128, TOK / 128), 256, 0, stream>>>(
      Hhi, Hlo, WqT_hi, WqT_lo, nullptr, nullptr, QKV, 2304, CDIM);
  attn_k<<<dim3(16, 12, 8), 256, 0, stream>>>(QKV, Ohi, Olo);
  gemm_bf16x3<1><<<dim3(CDIM / 128, TOK / 128), 256, 0, stream>>>(
      Ohi, Olo, WpT_hi, WpT_lo, b_proj, xin, x1, CDIM, CDIM);
  ln2_k<<<TOK, 256, 0, stream>>>(x1, ln2_g, ln2_b, h2, h2b, (float*)d_out);
  router_k<<<128, 256, 0, stream>>>(h2, w_route, b_route, w_noise, b_noise, rnoise, temp, gate);
  assign_k<<<TOK / 256, 256, 0, stream>>>(gate, counts, idxbuf);

  const dim3 gF(FDIM / 128, TOK / 128);
  const dim3 gC(CDIM / 128, TOK / 128);

  for (int e = 0; e < 2; e++) {
    const int* cp = counts + e;
    const int* ri = idxbuf + e * TOK;
    const u16* W1;
    if (big_ws) W1 = dW1T + (size_t)e * FDIM * CDIM;
    else {
      transpose_cast<<<dim3(FDIM / 32, CDIM / 32, 1), 256, 0, stream>>>(deep_w1 + (size_t)e * CDIM * FDIM, wbuf, CDIM, FDIM);
      W1 = wbuf;
    }
    gemm_bf16_cnt<1, 1, 1><<<gF, 256, 0, stream>>>(h2b, W1, deep_b1 + e * FDIM, (void*)T1c, ri, cp, FDIM, CDIM);
    const u16* W2;
    if (big_ws) W2 = dW2T + (size_t)e * FDIM * FDIM;
    else {
      transpose_cast<<<dim3(FDIM / 32, FDIM / 32, 1), 256, 0, stream>>>(deep_w2 + (size_t)e * FDIM * FDIM, wbuf, FDIM, FDIM);
      W2 = wbuf;
    }
    gemm_bf16_cnt<1, 1, 0><<<gF, 256, 0, stream>>>(T1c, W2, deep_b2 + e * FDIM, (void*)T2c, ri, cp, FDIM, FDIM);
    const u16* W3;
    if (big_ws) W3 = dW3T + (size_t)e * CDIM * FDIM;
    else {
      transpose_cast<<<dim3(CDIM / 32, FDIM / 32, 1), 256, 0, stream>>>(deep_w3 + (size_t)e * FDIM * CDIM, wbuf, FDIM, CDIM);
      W3 = wbuf;
    }
    gemm_bf16_cnt<0, 0, 0><<<gC, 256, 0, stream>>>(T2c, W3, deep_b3 + e * CDIM, (void*)Uc, ri, cp, CDIM, FDIM);
    combine_sc_k<<<TOK, 256, 0, stream>>>(Uc, h2, gate, ri, cp, deep_ln_g + e * CDIM, deep_ln_b + e * CDIM, (float*)d_out, e);
  }
  for (int e = 0; e < 6; e++) {
    const int* cp = counts + 2 + e;
    const int* ri = idxbuf + (size_t)(2 + e) * TOK;
    const u16* W1;
    if (big_ws) W1 = sW1T + (size_t)e * FDIM * CDIM;
    else {
      transpose_cast<<<dim3(FDIM / 32, CDIM / 32, 1), 256, 0, stream>>>(simple_w1 + (size_t)e * CDIM * FDIM, wbuf, CDIM, FDIM);
      W1 = wbuf;
    }
    gemm_bf16_cnt<1, 1, 1><<<gF, 256, 0, stream>>>(h2b, W1, simple_b1 + e * FDIM, (void*)T1c, ri, cp, FDIM, CDIM);
    const u16* W2;
    if (big_ws) W2 = sW2T + (size_t)e * CDIM * FDIM;
    else {
      transpose_cast<<<dim3(CDIM / 32, FDIM / 32, 1), 256, 0, stream>>>(simple_w2 + (size_t)e * FDIM * CDIM, wbuf, FDIM, CDIM);
      W2 = wbuf;
    }
    gemm_bf16_cnt<0, 0, 0><<<gC, 256, 0, stream>>>(T1c, W2, simple_b2 + e * CDIM, (void*)Uc, ri, cp, CDIM, FDIM);
    combine_sc_k<<<TOK, 256, 0, stream>>>(Uc, h2, gate, ri, cp, simple_ln_g + e * CDIM, simple_ln_b + e * CDIM, (float*)d_out, 2 + e);
  }
}

// Round 8
// 2059.945 us; speedup vs baseline: 1.4672x; 1.0226x over previous
//
#include <hip/hip_runtime.h>
#include <cstdint>
#include <cstddef>
#include <math.h>

typedef uint16_t u16;
typedef __attribute__((ext_vector_type(8))) short short8;
typedef __attribute__((ext_vector_type(4))) float f32x4;

#define TOK 8192
#define CDIM 768
#define FDIM 3072
#define TOTAL_S 17152   // 16384 assignments + 6*128 pad, 128-aligned
#define ST_MAX 134      // TOTAL_S / 128

#define GLDS16(g, l) __builtin_amdgcn_global_load_lds((const __attribute__((address_space(1))) uint32_t*)(g), (__attribute__((address_space(3))) uint32_t*)(l), 16, 0, 0)

__device__ __forceinline__ u16 f2bf(float f) {
  union { float f; uint32_t u; } v; v.f = f;
  uint32_t u = v.u;
  return (u16)((u + 0x7FFFu + ((u >> 16) & 1u)) >> 16);
}

__device__ __forceinline__ float bf2f(u16 h) {
  union { uint32_t u; float f; } v; v.u = ((uint32_t)h) << 16;
  return v.f;
}

__device__ __forceinline__ void split2(float y, u16& hi, u16& lo) {
  u16 h = f2bf(y);
  hi = h;
  lo = f2bf(y - bf2f(h));
}

__device__ __forceinline__ float gelu_exact(float z) {
  return 0.5f * z * (1.0f + erff(z * 0.70710678118654752f));
}

__device__ __forceinline__ float softplus_f(float x) {
  return (x > 0.0f) ? (x + log1pf(expf(-x))) : log1pf(expf(x));
}

__device__ __forceinline__ float block_sum256(float v, float* sm) {
  #pragma unroll
  for (int m = 1; m < 64; m <<= 1) v += __shfl_xor(v, m);
  int w = threadIdx.x >> 6;
  if ((threadIdx.x & 63) == 0) sm[w] = v;
  __syncthreads();
  v = sm[0] + sm[1] + sm[2] + sm[3];
  __syncthreads();
  return v;
}

// ---------------- weight prep ----------------

__global__ __launch_bounds__(256) void pack_qkv(const float* __restrict__ wq,
    const float* __restrict__ wk, const float* __restrict__ wv, float* __restrict__ W) {
  int id = blockIdx.x * 256 + threadIdx.x;
  if (id >= 768 * 2304) return;
  int c = id / 2304, j = id - c * 2304;
  int which = j / 768, jj = j - which * 768;
  int hh = jj >> 6, d = jj & 63;
  const float* src = (which == 0) ? wq : (which == 1 ? wk : wv);
  W[id] = src[((size_t)hh * 768 + c) * 64 + d];
}

// src [K][N] fp32 -> dst [N][K] bf16 (expert weights)
__global__ __launch_bounds__(256) void transpose_cast(const float* __restrict__ src,
    u16* __restrict__ dst, int K, int N) {
  __shared__ float t[32][33];
  size_t eoff = (size_t)blockIdx.z * K * N;
  const float* S = src + eoff;
  u16* D = dst + eoff;
  int n0 = blockIdx.x * 32, k0 = blockIdx.y * 32;
  int tc = threadIdx.x & 31, tr = threadIdx.x >> 5;
  #pragma unroll
  for (int r = tr; r < 32; r += 8) t[r][tc] = S[(size_t)(k0 + r) * N + n0 + tc];
  __syncthreads();
  #pragma unroll
  for (int r = tr; r < 32; r += 8) D[(size_t)(n0 + r) * K + k0 + tc] = f2bf(t[tc][r]);
}

// src [K][N] fp32 -> dst [N][K] bf16 hi + lo (accuracy-critical weights)
__global__ __launch_bounds__(256) void transpose_split_k(const float* __restrict__ src,
    u16* __restrict__ Dhi, u16* __restrict__ Dlo, int K, int N) {
  __shared__ float t[32][33];
  int n0 = blockIdx.x * 32, k0 = blockIdx.y * 32;
  int tc = threadIdx.x & 31, tr = threadIdx.x >> 5;
  #pragma unroll
  for (int r = tr; r < 32; r += 8) t[r][tc] = src[(size_t)(k0 + r) * N + n0 + tc];
  __syncthreads();
  #pragma unroll
  for (int r = tr; r < 32; r += 8) {
    u16 hi, lo;
    split2(t[tc][r], hi, lo);
    size_t o = (size_t)(n0 + r) * K + k0 + tc;
    Dhi[o] = hi; Dlo[o] = lo;
  }
}

// ---------------- layernorms ----------------

__global__ __launch_bounds__(256) void ln1_split_k(const float* __restrict__ X,
    const float* __restrict__ g, const float* __restrict__ b,
    u16* __restrict__ Yhi, u16* __restrict__ Ylo) {
  __shared__ float sm[4];
  size_t row = blockIdx.x;
  const float* x = X + row * 768;
  int t = threadIdx.x;
  float v0 = x[t], v1 = x[t + 256], v2 = x[t + 512];
  float mean = block_sum256(v0 + v1 + v2, sm) * (1.0f / 768.0f);
  float d0 = v0 - mean, d1 = v1 - mean, d2 = v2 - mean;
  float var = block_sum256(d0 * d0 + d1 * d1 + d2 * d2, sm) * (1.0f / 768.0f);
  float rstd = 1.0f / sqrtf(var + 1e-5f);
  float y0 = d0 * rstd * g[t]       + b[t];
  float y1 = d1 * rstd * g[t + 256] + b[t + 256];
  float y2 = d2 * rstd * g[t + 512] + b[t + 512];
  u16 h, lo;
  split2(y0, h, lo); Yhi[row * 768 + t]       = h; Ylo[row * 768 + t]       = lo;
  split2(y1, h, lo); Yhi[row * 768 + t + 256] = h; Ylo[row * 768 + t + 256] = lo;
  split2(y2, h, lo); Yhi[row * 768 + t + 512] = h; Ylo[row * 768 + t + 512] = lo;
}

__global__ __launch_bounds__(256) void ln2_k(const float* __restrict__ X,
    const float* __restrict__ g, const float* __restrict__ b, float* __restrict__ H2,
    u16* __restrict__ H2b, float* __restrict__ OutInit) {
  __shared__ float sm[4];
  size_t row = blockIdx.x;
  const float* x = X + row * 768;
  int t = threadIdx.x;
  float v0 = x[t], v1 = x[t + 256], v2 = x[t + 512];
  float mean = block_sum256(v0 + v1 + v2, sm) * (1.0f / 768.0f);
  float d0 = v0 - mean, d1 = v1 - mean, d2 = v2 - mean;
  float var = block_sum256(d0 * d0 + d1 * d1 + d2 * d2, sm) * (1.0f / 768.0f);
  float rstd = 1.0f / sqrtf(var + 1e-5f);
  float y0 = d0 * rstd * g[t]       + b[t];
  float y1 = d1 * rstd * g[t + 256] + b[t + 256];
  float y2 = d2 * rstd * g[t + 512] + b[t + 512];
  float* h2r = H2 + row * 768;
  u16* hbr = H2b + row * 768;
  float* outr = OutInit + row * 768;
  h2r[t] = y0; h2r[t + 256] = y1; h2r[t + 512] = y2;
  hbr[t] = f2bf(y0); hbr[t + 256] = f2bf(y1); hbr[t + 512] = f2bf(y2);
  outr[t] = v0; outr[t + 256] = v1; outr[t + 512] = v2;
}

// ---------------- bf16x3 split MFMA GEMM (pre-router path) ----------------

template<int BIAS_RES>
__global__ __launch_bounds__(256) void gemm_bf16x3(
    const u16* __restrict__ Ahi, const u16* __restrict__ Alo,
    const u16* __restrict__ Bhi, const u16* __restrict__ Blo,
    const float* __restrict__ bias, const float* __restrict__ Res,
    float* __restrict__ Cout, int N, int K) {
  __shared__ __align__(16) u16 Ah[128 * 32];
  __shared__ __align__(16) u16 Al[128 * 32];
  __shared__ __align__(16) u16 Bh[128 * 32];
  __shared__ __align__(16) u16 Bl[128 * 32];
  const int tid = threadIdx.x;
  const int l = tid & 63, w = tid >> 6;
  const int m0 = blockIdx.y << 7, n0 = blockIdx.x << 7;
  const int wr = w >> 1, wc = w & 1;
  f32x4 zero = {0.0f, 0.0f, 0.0f, 0.0f};
  f32x4 acc[4][4];
  #pragma unroll
  for (int mi = 0; mi < 4; mi++)
    #pragma unroll
    for (int ni = 0; ni < 4; ni++) acc[mi][ni] = zero;

  const int c0 = (w << 7) + l, c1 = c0 + 64;
  for (int k0 = 0; k0 < K; k0 += 32) {
    {
      size_t ao0 = (size_t)(m0 + (c0 >> 2)) * K + k0 + ((c0 & 3) << 3);
      size_t bo0 = (size_t)(n0 + (c0 >> 2)) * K + k0 + ((c0 & 3) << 3);
      GLDS16(Ahi + ao0, Ah + c0 * 8);
      GLDS16(Alo + ao0, Al + c0 * 8);
      GLDS16(Bhi + bo0, Bh + c0 * 8);
      GLDS16(Blo + bo0, Bl + c0 * 8);
      size_t ao1 = (size_t)(m0 + (c1 >> 2)) * K + k0 + ((c1 & 3) << 3);
      size_t bo1 = (size_t)(n0 + (c1 >> 2)) * K + k0 + ((c1 & 3) << 3);
      GLDS16(Ahi + ao1, Ah + c1 * 8);
      GLDS16(Alo + ao1, Al + c1 * 8);
      GLDS16(Bhi + bo1, Bh + c1 * 8);
      GLDS16(Blo + bo1, Bl + c1 * 8);
    }
    __syncthreads();
    short8 avh[4], avl[4], bvh[4], bvl[4];
    const int ra = (wr << 6) + (l & 15);
    const int rb = (wc << 6) + (l & 15);
    const int ko = (l >> 4) << 3;
    #pragma unroll
    for (int mi = 0; mi < 4; mi++) {
      avh[mi] = *(const short8*)(Ah + (ra + mi * 16) * 32 + ko);
      avl[mi] = *(const short8*)(Al + (ra + mi * 16) * 32 + ko);
    }
    #pragma unroll
    for (int ni = 0; ni < 4; ni++) {
      bvh[ni] = *(const short8*)(Bh + (rb + ni * 16) * 32 + ko);
      bvl[ni] = *(const short8*)(Bl + (rb + ni * 16) * 32 + ko);
    }
    #pragma unroll
    for (int mi = 0; mi < 4; mi++)
      #pragma unroll
      for (int ni = 0; ni < 4; ni++) {
        acc[mi][ni] = __builtin_amdgcn_mfma_f32_16x16x32_bf16(avl[mi], bvh[ni], acc[mi][ni], 0, 0, 0);
        acc[mi][ni] = __builtin_amdgcn_mfma_f32_16x16x32_bf16(avh[mi], bvl[ni], acc[mi][ni], 0, 0, 0);
        acc[mi][ni] = __builtin_amdgcn_mfma_f32_16x16x32_bf16(avh[mi], bvh[ni], acc[mi][ni], 0, 0, 0);
      }
    __syncthreads();
  }
  const int lr = (l >> 4) << 2;
  const int lc = l & 15;
  #pragma unroll
  for (int mi = 0; mi < 4; mi++) {
    #pragma unroll
    for (int ni = 0; ni < 4; ni++) {
      const int col = n0 + (wc << 6) + ni * 16 + lc;
      const float bv2 = BIAS_RES ? bias[col] : 0.0f;
      #pragma unroll
      for (int v = 0; v < 4; v++) {
        const size_t row = (size_t)m0 + (wr << 6) + mi * 16 + lr + v;
        float val = acc[mi][ni][v] + bv2;
        if (BIAS_RES) val += Res[row * N + col];
        Cout[row * N + col] = val;
      }
    }
  }
}

// ---------------- fp32 causal flash attention (register-prefetch K/V dbuf) ----------------

__global__ __launch_bounds__(256) void attn_k(const float* __restrict__ QKV,
    u16* __restrict__ Ohi, u16* __restrict__ Olo) {
  __shared__ __align__(16) float Qs[64 * 68];
  __shared__ __align__(16) float Ks[64 * 68];   // reused as P buffer after scores
  __shared__ __align__(16) float Vs[64 * 64];
  const int qt = (int)gridDim.x - 1 - (int)blockIdx.x;  // big blocks first
  const int hh = blockIdx.y, bb = blockIdx.z;
  const int tid = threadIdx.x, tx = tid & 15, ty = tid >> 4;
  const int q0 = qt * 64;
  const float scale = 0.03608439182435161f;  // 768^-0.5
  const int r = tid & 63, kg = (tid >> 6) * 16;
  int vs_[4], vj_[4];
  #pragma unroll
  for (int kk = 0; kk < 4; kk++) {
    int f = tid + kk * 256;
    vs_[kk] = f >> 4; vj_[kk] = (f & 15) << 2;
  }
  {
    const float* g = QKV + ((size_t)bb * 1024 + q0 + r) * 2304 + hh * 64 + kg;
    #pragma unroll
    for (int jj = 0; jj < 16; jj += 4) {
      float4 p = *(const float4*)(g + jj);
      Qs[(kg + jj + 0) * 68 + r] = p.x;
      Qs[(kg + jj + 1) * 68 + r] = p.y;
      Qs[(kg + jj + 2) * 68 + r] = p.z;
      Qs[(kg + jj + 3) * 68 + r] = p.w;
    }
  }
  float4 kp[4], vp[4];
  {
    const float* gk = QKV + ((size_t)bb * 1024 + r) * 2304 + 768 + hh * 64 + kg;
    #pragma unroll
    for (int jj = 0; jj < 4; jj++) kp[jj] = *(const float4*)(gk + jj * 4);
    #pragma unroll
    for (int kk = 0; kk < 4; kk++)
      vp[kk] = *(const float4*)(QKV + ((size_t)bb * 1024 + vs_[kk]) * 2304 + 1536 + hh * 64 + vj_[kk]);
  }
  float o[4][4] = {};
  float mrun[4], lrun[4] = {};
  #pragma unroll
  for (int i = 0; i < 4; i++) mrun[i] = -__builtin_inff();

  for (int st = 0; st <= qt; st++) {
    __syncthreads();   // LDS free (prev PV done); also covers Q staging at st=0
    #pragma unroll
    for (int jj = 0; jj < 4; jj++) {
      Ks[(kg + jj * 4 + 0) * 68 + r] = kp[jj].x;
      Ks[(kg + jj * 4 + 1) * 68 + r] = kp[jj].y;
      Ks[(kg + jj * 4 + 2) * 68 + r] = kp[jj].z;
      Ks[(kg + jj * 4 + 3) * 68 + r] = kp[jj].w;
    }
    #pragma unroll
    for (int kk = 0; kk < 4; kk++)
      *(float4*)&Vs[(vs_[kk] << 6) + vj_[kk]] = vp[kk];
    if (st < qt) {  // prefetch next tile; latency hides under compute below
      const float* gk = QKV + ((size_t)bb * 1024 + (st + 1) * 64 + r) * 2304 + 768 + hh * 64 + kg;
      #pragma unroll
      for (int jj = 0; jj < 4; jj++) kp[jj] = *(const float4*)(gk + jj * 4);
      #pragma unroll
      for (int kk = 0; kk < 4; kk++)
        vp[kk] = *(const float4*)(QKV + ((size_t)bb * 1024 + (st + 1) * 64 + vs_[kk]) * 2304 + 1536 + hh * 64 + vj_[kk]);
    }
    __syncthreads();
    float sc[4][4] = {};
    #pragma unroll 4
    for (int k = 0; k < 64; k++) {
      float4 qv = *(const float4*)&Qs[k * 68 + (ty << 2)];
      float4 kv = *(const float4*)&Ks[k * 68 + (tx << 2)];
      float qa[4] = {qv.x, qv.y, qv.z, qv.w};
      float kb[4] = {kv.x, kv.y, kv.z, kv.w};
      #pragma unroll
      for (int i = 0; i < 4; i++)
        #pragma unroll
        for (int j = 0; j < 4; j++)
          sc[i][j] = fmaf(qa[i], kb[j], sc[i][j]);
    }
    const bool diag = (st == qt);
    float mt[4];
    #pragma unroll
    for (int i = 0; i < 4; i++) {
      float mrow = -3.0e38f;
      #pragma unroll
      for (int j = 0; j < 4; j++) {
        float v = sc[i][j] * scale;
        if (diag && ((tx << 2) + j > (ty << 2) + i)) v = -__builtin_inff();
        sc[i][j] = v;
        mrow = fmaxf(mrow, v);
      }
      mt[i] = mrow;
    }
    #pragma unroll
    for (int mk = 1; mk < 16; mk <<= 1)
      #pragma unroll
      for (int i = 0; i < 4; i++) mt[i] = fmaxf(mt[i], __shfl_xor(mt[i], mk));
    float sfv[4], psum[4];
    #pragma unroll
    for (int i = 0; i < 4; i++) {
      float mnew = fmaxf(mrun[i], mt[i]);
      sfv[i] = expf(mrun[i] - mnew);
      mrun[i] = mnew;
      float rs = 0.0f;
      #pragma unroll
      for (int j = 0; j < 4; j++) {
        float pv = expf(sc[i][j] - mnew);
        sc[i][j] = pv;
        rs += pv;
      }
      psum[i] = rs;
    }
    #pragma unroll
    for (int mk = 1; mk < 16; mk <<= 1)
      #pragma unroll
      for (int i = 0; i < 4; i++) psum[i] += __shfl_xor(psum[i], mk);
    #pragma unroll
    for (int i = 0; i < 4; i++) {
      lrun[i] = lrun[i] * sfv[i] + psum[i];
      #pragma unroll
      for (int j = 0; j < 4; j++) o[i][j] *= sfv[i];
    }
    __syncthreads();   // all threads done reading K from Ks
    {
      float pt[4][4];
      #pragma unroll
      for (int i = 0; i < 4; i++)
        #pragma unroll
        for (int j = 0; j < 4; j++) pt[j][i] = sc[i][j];
      #pragma unroll
      for (int j = 0; j < 4; j++)
        *(float4*)&Ks[((tx << 2) + j) * 68 + (ty << 2)] = *(const float4*)&pt[j][0];
    }
    __syncthreads();
    #pragma unroll 4
    for (int s2 = 0; s2 < 64; s2++) {
      float4 pv = *(const float4*)&Ks[s2 * 68 + (ty << 2)];
      float4 vv = *(const float4*)&Vs[(s2 << 6) + (tx << 2)];
      float pa[4] = {pv.x, pv.y, pv.z, pv.w};
      float vb4[4] = {vv.x, vv.y, vv.z, vv.w};
      #pragma unroll
      for (int i = 0; i < 4; i++)
        #pragma unroll
        for (int j = 0; j < 4; j++)
          o[i][j] = fmaf(pa[i], vb4[j], o[i][j]);
    }
  }
  #pragma unroll
  for (int i = 0; i < 4; i++) {
    float inv = 1.0f / lrun[i];
    ushort4 vh, vl;
    u16 h0, l0;
    split2(o[i][0] * inv, h0, l0); vh.x = h0; vl.x = l0;
    split2(o[i][1] * inv, h0, l0); vh.y = h0; vl.y = l0;
    split2(o[i][2] * inv, h0, l0); vh.z = h0; vl.z = l0;
    split2(o[i][3] * inv, h0, l0); vh.w = h0; vl.w = l0;
    size_t base = ((size_t)bb * 1024 + q0 + (ty << 2) + i) * 768 + hh * 64 + (tx << 2);
    *(ushort4*)&Ohi[base] = vh;
    *(ushort4*)&Olo[base] = vl;
  }
}

// ---------------- router (fp32, exact top-2 semantics) ----------------

__global__ __launch_bounds__(256) void router_k(const float* __restrict__ h2,
    const float* __restrict__ w_route, const float* __restrict__ b_route,
    const float* __restrict__ w_noise, const float* __restrict__ b_noise,
    const float* __restrict__ rnoise, const float* __restrict__ tp, float* __restrict__ gate) {
  __shared__ float Wl[6144], Wn[6144];
  int t = threadIdx.x;
  for (int i = t; i < 1536; i += 256) {
    ((float4*)Wl)[i] = ((const float4*)w_route)[i];
    ((float4*)Wn)[i] = ((const float4*)w_noise)[i];
  }
  __syncthreads();
  int tok = blockIdx.x * 64 + (t >> 2);
  int sub = t & 3;
  const float* hr = h2 + (size_t)tok * 768;
  float aL[8] = {}, aN[8] = {};
  for (int i = 0; i < 192; i++) {
    int c = sub + (i << 2);
    float hv = hr[c];
    const float* wl = &Wl[c * 8];
    const float* wn = &Wn[c * 8];
    #pragma unroll
    for (int e = 0; e < 8; e++) { aL[e] = fmaf(hv, wl[e], aL[e]); aN[e] = fmaf(hv, wn[e], aN[e]); }
  }
  #pragma unroll
  for (int e = 0; e < 8; e++) {
    aL[e] += __shfl_xor(aL[e], 1); aL[e] += __shfl_xor(aL[e], 2);
    aN[e] += __shfl_xor(aN[e], 1); aN[e] += __shfl_xor(aN[e], 2);
  }
  if (sub == 0) {
    float temp = fminf(fmaxf(tp[0], 0.5f), 2.0f);
    float noisy[8];
    #pragma unroll
    for (int e = 0; e < 8; e++) {
      float lg = aL[e] + b_route[e];
      float ns = softplus_f(aN[e] + b_noise[e]);
      noisy[e] = lg + temp * rnoise[(size_t)tok * 8 + e] * ns;
    }
    int i1 = 0; float v1 = noisy[0];
    #pragma unroll
    for (int e = 1; e < 8; e++) if (noisy[e] > v1) { v1 = noisy[e]; i1 = e; }
    int i2 = -1; float v2 = 0.0f;
    #pragma unroll
    for (int e = 0; e < 8; e++) {
      if (e == i1) continue;
      if (i2 < 0 || noisy[e] > v2) { v2 = noisy[e]; i2 = e; }
    }
    float e2 = expf(v2 - v1);
    float denom = 1.0f + e2;
    float* gr = gate + (size_t)tok * 8;
    #pragma unroll
    for (int e = 0; e < 8; e++) gr[e] = 0.0f;
    gr[i1] = 1.0f / denom;
    gr[i2] = e2 / denom;
  }
}

// ---------------- routing compaction ----------------

__global__ void zero_counts(int* counts) {
  if (threadIdx.x < 8) counts[threadIdx.x] = 0;
}

__global__ __launch_bounds__(256) void assign_k(const float* __restrict__ gate,
    int* __restrict__ counts, int* __restrict__ idxbuf) {
  int tok = blockIdx.x * 256 + threadIdx.x;
  const float* gr = gate + (size_t)tok * 8;
  #pragma unroll
  for (int e = 0; e < 8; e++) {
    if (gr[e] > 0.0f) {
      int s = atomicAdd(&counts[e], 1);
      idxbuf[e * TOK + s] = tok;
    }
  }
}

// 128-aligned segment offsets over the 6 simple experts
__global__ void scan_k(const int* __restrict__ counts, int* __restrict__ sstart) {
  if (threadIdx.x == 0) {
    int acc = 0;
    for (int j = 0; j < 6; j++) {
      sstart[j] = acc;
      acc += (counts[2 + j] + 127) & ~127;
    }
    sstart[6] = acc;
  }
}

__global__ __launch_bounds__(256) void ridx_fill_k(const int* __restrict__ counts,
    const int* __restrict__ sstart, const int* __restrict__ idxbuf, int* __restrict__ ridx_s) {
  int p = blockIdx.x * 256 + threadIdx.x;
  if (p >= sstart[6]) return;
  int j = 0;
  #pragma unroll
  for (int t = 1; t < 6; t++) if (p >= sstart[t]) j = t;
  int local = p - sstart[j];
  if (local >= counts[2 + j]) local = 0;   // pad row -> clamp (skipped at combine)
  ridx_s[p] = idxbuf[(2 + j) * TOK + local];
}

// ---------------- bf16 MFMA GEMM over compacted rows (deep experts / fallback) --------

template<int GELU_OUT, int BF16_OUT, int GATHER>
__global__ __launch_bounds__(256) void gemm_bf16_cnt(const u16* __restrict__ A,
    const u16* __restrict__ BT, const float* __restrict__ bias, void* __restrict__ Cout,
    const int* __restrict__ ridx, const int* __restrict__ cntp, int N, int K) {
  const int cnt = *cntp;
  const int mtiles = (cnt + 127) >> 7;
  if ((int)blockIdx.y >= mtiles) return;
  __shared__ __align__(16) u16 As[128 * 32];
  __shared__ __align__(16) u16 Bs[128 * 32];
  const int tid = threadIdx.x;
  const int l = tid & 63, w = tid >> 6;
  const int m0 = blockIdx.y << 7, n0 = blockIdx.x << 7;
  const int wr = w >> 1, wc = w & 1;
  const int ca = (w << 7) + l, cb = ca + 64;
  const int ra_ = m0 + (ca >> 2), rb_ = m0 + (cb >> 2);
  size_t ga, gb;
  if (GATHER) {
    ga = (size_t)ridx[ra_ < cnt ? ra_ : 0];
    gb = (size_t)ridx[rb_ < cnt ? rb_ : 0];
  } else {
    ga = (size_t)ra_; gb = (size_t)rb_;
  }
  f32x4 zero = {0.0f, 0.0f, 0.0f, 0.0f};
  f32x4 acc[4][4];
  #pragma unroll
  for (int mi = 0; mi < 4; mi++)
    #pragma unroll
    for (int ni = 0; ni < 4; ni++) acc[mi][ni] = zero;

  for (int k0 = 0; k0 < K; k0 += 32) {
    GLDS16(A + ga * K + k0 + ((ca & 3) << 3), As + ca * 8);
    GLDS16(BT + (size_t)(n0 + (ca >> 2)) * K + k0 + ((ca & 3) << 3), Bs + ca * 8);
    GLDS16(A + gb * K + k0 + ((cb & 3) << 3), As + cb * 8);
    GLDS16(BT + (size_t)(n0 + (cb >> 2)) * K + k0 + ((cb & 3) << 3), Bs + cb * 8);
    __syncthreads();
    short8 av[4], bv[4];
    const int ra = (wr << 6) + (l & 15);
    const int rb = (wc << 6) + (l & 15);
    const int ko = (l >> 4) << 3;
    #pragma unroll
    for (int mi = 0; mi < 4; mi++) av[mi] = *(const short8*)(As + (ra + mi * 16) * 32 + ko);
    #pragma unroll
    for (int ni = 0; ni < 4; ni++) bv[ni] = *(const short8*)(Bs + (rb + ni * 16) * 32 + ko);
    #pragma unroll
    for (int mi = 0; mi < 4; mi++)
      #pragma unroll
      for (int ni = 0; ni < 4; ni++)
        acc[mi][ni] = __builtin_amdgcn_mfma_f32_16x16x32_bf16(av[mi], bv[ni], acc[mi][ni], 0, 0, 0);
    __syncthreads();
  }
  const int lr = (l >> 4) << 2;
  const int lc = l & 15;
  #pragma unroll
  for (int mi = 0; mi < 4; mi++) {
    #pragma unroll
    for (int ni = 0; ni < 4; ni++) {
      const int col = n0 + (wc << 6) + ni * 16 + lc;
      const float bv2 = bias ? bias[col] : 0.0f;
      #pragma unroll
      for (int v = 0; v < 4; v++) {
        const size_t row = (size_t)m0 + (wr << 6) + mi * 16 + lr + v;
        float val = acc[mi][ni][v] + bv2;
        if (GELU_OUT) val = gelu_exact(val);
        if (BF16_OUT) ((u16*)Cout)[row * N + col] = f2bf(val);
        else          ((float*)Cout)[row * N + col] = val;
      }
    }
  }
}

// ---------------- consolidated simple-expert GEMMs ----------------
// stage 1: T1g[p][F] = GELU(h2b[ridx_s[p]] @ W1[j] + b1[j]), j from segment of p
__global__ __launch_bounds__(256) void gemm_moe1(const u16* __restrict__ A,
    const u16* __restrict__ W1T, const float* __restrict__ b1, u16* __restrict__ T1g,
    const int* __restrict__ ridx_s, const int* __restrict__ sstart) {
  const int m0 = (int)blockIdx.y << 7;
  if (m0 >= sstart[6]) return;
  int j = 0;
  #pragma unroll
  for (int t = 1; t < 6; t++) if (m0 >= sstart[t]) j = t;
  const u16* BT = W1T + (size_t)j * FDIM * CDIM;
  const float* bias = b1 + (size_t)j * FDIM;
  const int N = FDIM, K = CDIM;
  __shared__ __align__(16) u16 As[128 * 32];
  __shared__ __align__(16) u16 Bs[128 * 32];
  const int tid = threadIdx.x;
  const int l = tid & 63, w = tid >> 6;
  const int n0 = blockIdx.x << 7;
  const int wr = w >> 1, wc = w & 1;
  const int ca = (w << 7) + l, cb = ca + 64;
  size_t ga = (size_t)ridx_s[m0 + (ca >> 2)];
  size_t gb = (size_t)ridx_s[m0 + (cb >> 2)];
  f32x4 zero = {0.0f, 0.0f, 0.0f, 0.0f};
  f32x4 acc[4][4];
  #pragma unroll
  for (int mi = 0; mi < 4; mi++)
    #pragma unroll
    for (int ni = 0; ni < 4; ni++) acc[mi][ni] = zero;
  for (int k0 = 0; k0 < K; k0 += 32) {
    GLDS16(A + ga * K + k0 + ((ca & 3) << 3), As + ca * 8);
    GLDS16(BT + (size_t)(n0 + (ca >> 2)) * K + k0 + ((ca & 3) << 3), Bs + ca * 8);
    GLDS16(A + gb * K + k0 + ((cb & 3) << 3), As + cb * 8);
    GLDS16(BT + (size_t)(n0 + (cb >> 2)) * K + k0 + ((cb & 3) << 3), Bs + cb * 8);
    __syncthreads();
    short8 av[4], bv[4];
    const int ra = (wr << 6) + (l & 15);
    const int rb = (wc << 6) + (l & 15);
    const int ko = (l >> 4) << 3;
    #pragma unroll
    for (int mi = 0; mi < 4; mi++) av[mi] = *(const short8*)(As + (ra + mi * 16) * 32 + ko);
    #pragma unroll
    for (int ni = 0; ni < 4; ni++) bv[ni] = *(const short8*)(Bs + (rb + ni * 16) * 32 + ko);
    #pragma unroll
    for (int mi = 0; mi < 4; mi++)
      #pragma unroll
      for (int ni = 0; ni < 4; ni++)
        acc[mi][ni] = __builtin_amdgcn_mfma_f32_16x16x32_bf16(av[mi], bv[ni], acc[mi][ni], 0, 0, 0);
    __syncthreads();
  }
  const int lr = (l >> 4) << 2;
  const int lc = l & 15;
  #pragma unroll
  for (int mi = 0; mi < 4; mi++)
    #pragma unroll
    for (int ni = 0; ni < 4; ni++) {
      const int col = n0 + (wc << 6) + ni * 16 + lc;
      const float bv2 = bias[col];
      #pragma unroll
      for (int v = 0; v < 4; v++) {
        const size_t row = (size_t)m0 + (wr << 6) + mi * 16 + lr + v;
        T1g[row * N + col] = f2bf(gelu_exact(acc[mi][ni][v] + bv2));
      }
    }
}

// stage 2: Us[p][C] = T1g[p] @ W2[j] + b2[j]  (bf16 out; post-router precision ok)
__global__ __launch_bounds__(256) void gemm_moe2(const u16* __restrict__ A,
    const u16* __restrict__ W2T, const float* __restrict__ b2, u16* __restrict__ Us,
    const int* __restrict__ sstart) {
  const int m0 = (int)blockIdx.y << 7;
  if (m0 >= sstart[6]) return;
  int j = 0;
  #pragma unroll
  for (int t = 1; t < 6; t++) if (m0 >= sstart[t]) j = t;
  const u16* BT = W2T + (size_t)j * CDIM * FDIM;
  const float* bias = b2 + (size_t)j * CDIM;
  const int N = CDIM, K = FDIM;
  __shared__ __align__(16) u16 As[128 * 32];
  __shared__ __align__(16) u16 Bs[128 * 32];
  const int tid = threadIdx.x;
  const int l = tid & 63, w = tid >> 6;
  const int n0 = blockIdx.x << 7;
  const int wr = w >> 1, wc = w & 1;
  const int ca = (w << 7) + l, cb = ca + 64;
  size_t ga = (size_t)(m0 + (ca >> 2));
  size_t gb = (size_t)(m0 + (cb >> 2));
  f32x4 zero = {0.0f, 0.0f, 0.0f, 0.0f};
  f32x4 acc[4][4];
  #pragma unroll
  for (int mi = 0; mi < 4; mi++)
    #pragma unroll
    for (int ni = 0; ni < 4; ni++) acc[mi][ni] = zero;
  for (int k0 = 0; k0 < K; k0 += 32) {
    GLDS16(A + ga * K + k0 + ((ca & 3) << 3), As + ca * 8);
    GLDS16(BT + (size_t)(n0 + (ca >> 2)) * K + k0 + ((ca & 3) << 3), Bs + ca * 8);
    GLDS16(A + gb * K + k0 + ((cb & 3) << 3), As + cb * 8);
    GLDS16(BT + (size_t)(n0 + (cb >> 2)) * K + k0 + ((cb & 3) << 3), Bs + cb * 8);
    __syncthreads();
    short8 av[4], bv[4];
    const int ra = (wr << 6) + (l & 15);
    const int rb = (wc << 6) + (l & 15);
    const int ko = (l >> 4) << 3;
    #pragma unroll
    for (int mi = 0; mi < 4; mi++) av[mi] = *(const short8*)(As + (ra + mi * 16) * 32 + ko);
    #pragma unroll
    for (int ni = 0; ni < 4; ni++) bv[ni] = *(const short8*)(Bs + (rb + ni * 16) * 32 + ko);
    #pragma unroll
    for (int mi = 0; mi < 4; mi++)
      #pragma unroll
      for (int ni = 0; ni < 4; ni++)
        acc[mi][ni] = __builtin_amdgcn_mfma_f32_16x16x32_bf16(av[mi], bv[ni], acc[mi][ni], 0, 0, 0);
    __syncthreads();
  }
  const int lr = (l >> 4) << 2;
  const int lc = l & 15;
  #pragma unroll
  for (int mi = 0; mi < 4; mi++)
    #pragma unroll
    for (int ni = 0; ni < 4; ni++) {
      const int col = n0 + (wc << 6) + ni * 16 + lc;
      const float bv2 = bias[col];
      #pragma unroll
      for (int v = 0; v < 4; v++) {
        const size_t row = (size_t)m0 + (wr << 6) + mi * 16 + lr + v;
        Us[row * N + col] = f2bf(acc[mi][ni][v] + bv2);
      }
    }
}

// ---------------- residual-LN + gated scatter-accumulate ----------------

__global__ __launch_bounds__(256) void combine_sc_k(const float* __restrict__ U,
    const float* __restrict__ H2, const float* __restrict__ gate,
    const int* __restrict__ ridx, const int* __restrict__ cntp,
    const float* __restrict__ g, const float* __restrict__ b,
    float* __restrict__ Out, int eidx) {
  __shared__ float sm[4];
  int pos = blockIdx.x;
  if (pos >= *cntp) return;
  size_t tok = (size_t)ridx[pos];
  float gt = gate[tok * 8 + eidx];
  int t = threadIdx.x;
  const float* h = H2 + tok * 768;
  const float* u = U + (size_t)pos * 768;
  float v0 = h[t] + u[t], v1 = h[t + 256] + u[t + 256], v2 = h[t + 512] + u[t + 512];
  float mean = block_sum256(v0 + v1 + v2, sm) * (1.0f / 768.0f);
  float d0 = v0 - mean, d1 = v1 - mean, d2 = v2 - mean;
  float var = block_sum256(d0 * d0 + d1 * d1 + d2 * d2, sm) * (1.0f / 768.0f);
  float rstd = 1.0f / sqrtf(var + 1e-5f);
  float* o = Out + tok * 768;
  o[t]       += gt * (d0 * rstd * g[t]       + b[t]);
  o[t + 256] += gt * (d1 * rstd * g[t + 256] + b[t + 256]);
  o[t + 512] += gt * (d2 * rstd * g[t + 512] + b[t + 512]);
}

// merged combine for the 6 simple experts (bf16 U, segment lookup, pad-skip)
__global__ __launch_bounds__(256) void combine_s_k(const u16* __restrict__ Us,
    const float* __restrict__ H2, const float* __restrict__ gate,
    const int* __restrict__ ridx_s, const int* __restrict__ counts, const int* __restrict__ sstart,
    const float* __restrict__ sg, const float* __restrict__ sb, float* __restrict__ Out) {
  __shared__ float sm[4];
  int p = blockIdx.x;
  if (p >= sstart[6]) return;
  int j = 0;
  #pragma unroll
  for (int t2 = 1; t2 < 6; t2++) if (p >= sstart[t2]) j = t2;
  if (p - sstart[j] >= counts[2 + j]) return;   // pad row
  size_t tok = (size_t)ridx_s[p];
  float gt = gate[tok * 8 + 2 + j];
  int t = threadIdx.x;
  const float* h = H2 + tok * 768;
  const u16* u = Us + (size_t)p * 768;
  const float* g = sg + (size_t)j * 768;
  const float* b = sb + (size_t)j * 768;
  float v0 = h[t] + bf2f(u[t]);
  float v1 = h[t + 256] + bf2f(u[t + 256]);
  float v2 = h[t + 512] + bf2f(u[t + 512]);
  float mean = block_sum256(v0 + v1 + v2, sm) * (1.0f / 768.0f);
  float d0 = v0 - mean, d1 = v1 - mean, d2 = v2 - mean;
  float var = block_sum256(d0 * d0 + d1 * d1 + d2 * d2, sm) * (1.0f / 768.0f);
  float rstd = 1.0f / sqrtf(var + 1e-5f);
  float* o = Out + tok * 768;
  o[t]       += gt * (d0 * rstd * g[t]       + b[t]);
  o[t + 256] += gt * (d1 * rstd * g[t + 256] + b[t + 256]);
  o[t + 512] += gt * (d2 * rstd * g[t + 512] + b[t + 512]);
}

// ---------------- launch ----------------

extern "C" void kernel_launch(void* const* d_in, const int* in_sizes, int n_in,
                              void* d_out, int out_size, void* d_ws, size_t ws_size,
                              hipStream_t stream) {
  (void)in_sizes; (void)n_in; (void)out_size;
  const float* xin       = (const float*)d_in[0];
  const float* rnoise    = (const float*)d_in[1];
  const float* wq        = (const float*)d_in[2];
  const float* wk        = (const float*)d_in[3];
  const float* wv        = (const float*)d_in[4];
  const float* w_proj    = (const float*)d_in[5];
  const float* b_proj    = (const float*)d_in[6];
  const float* ln1_g     = (const float*)d_in[7];
  const float* ln1_b     = (const float*)d_in[8];
  const float* ln2_g     = (const float*)d_in[9];
  const float* ln2_b     = (const float*)d_in[10];
  const float* w_route   = (const float*)d_in[11];
  const float* b_route   = (const float*)d_in[12];
  const float* w_noise   = (const float*)d_in[13];
  const float* b_noise   = (const float*)d_in[14];
  const float* temp      = (const float*)d_in[15];
  const float* deep_w1   = (const float*)d_in[16];
  const float* deep_b1   = (const float*)d_in[17];
  const float* deep_w2   = (const float*)d_in[18];
  const float* deep_b2   = (const float*)d_in[19];
  const float* deep_w3   = (const float*)d_in[20];
  const float* deep_b3   = (const float*)d_in[21];
  const float* deep_ln_g = (const float*)d_in[22];
  const float* deep_ln_b = (const float*)d_in[23];
  const float* simple_w1 = (const float*)d_in[24];
  const float* simple_b1 = (const float*)d_in[25];
  const float* simple_w2 = (const float*)d_in[26];
  const float* simple_b2 = (const float*)d_in[27];
  const float* simple_ln_g = (const float*)d_in[28];
  const float* simple_ln_b = (const float*)d_in[29];

  char* ws = (char*)d_ws;
  size_t off = 0;
  auto alloc = [&](size_t bytes) -> char* {
    char* p = ws + off;
    off += (bytes + 255) & ~(size_t)255;
    return p;
  };
  float* gate = (float*)alloc((size_t)TOK * 8 * 4);
  int*   counts = (int*)alloc(8 * 4);
  int*   sstart = (int*)alloc(8 * 4);
  int*   idxbuf = (int*)alloc(8ull * TOK * 4);
  int*   ridx_s = (int*)alloc((size_t)TOTAL_S * 4);
  float* h2   = (float*)alloc((size_t)TOK * CDIM * 4);
  u16*   h2b  = (u16*)  alloc((size_t)TOK * CDIM * 2);
  float* x1   = (float*)alloc((size_t)TOK * CDIM * 4);     // reused as deep Uc
  // big region: QKV fp32 | Ohi | Olo -> deep T1c|T2c -> simple T1g
  size_t big_a = (size_t)TOK * 2304 * 4 + (size_t)TOK * CDIM * 2 * 2;   // 100.7 MB
  size_t big_b = (size_t)TOTAL_S * FDIM * 2;                            // 105.4 MB
  char*  big  = alloc(big_a > big_b ? big_a : big_b);
  float* QKV  = (float*)big;
  float* wqkv = (float*)big;                               // prep-phase alias (dead before QKV write)
  u16*   Ohi  = (u16*)(big + (size_t)TOK * 2304 * 4);
  u16*   Olo  = Ohi + (size_t)TOK * CDIM;
  u16*   T1c  = (u16*)big;
  u16*   T2c  = (u16*)(big + (size_t)TOK * FDIM * 2);
  u16*   T1g  = (u16*)big;
  float* Uc   = x1;
  u16* WqT_hi = (u16*)alloc(2304ull * CDIM * 2);
  u16* WqT_lo = (u16*)alloc(2304ull * CDIM * 2);
  u16* WpT_hi = (u16*)alloc((size_t)CDIM * CDIM * 2);
  u16* WpT_lo = (u16*)alloc((size_t)CDIM * CDIM * 2);
  u16* Hhi    = (u16*)alloc((size_t)TOK * CDIM * 2);
  u16* Hlo    = (u16*)alloc((size_t)TOK * CDIM * 2);
  // Us (simple stage-2 out, bf16, 26.3 MB) aliases [WqT_hi..Hlo] (37 MB, dead after proj)
  u16* Us = WqT_hi;

  size_t wsz_all = (2ull * FDIM * CDIM + 2ull * FDIM * FDIM + 2ull * CDIM * FDIM +
                    6ull * FDIM * CDIM + 6ull * CDIM * FDIM) * 2 + 16 * 256;
  bool big_ws = ws_size >= off + wsz_all;
  u16 *dW1T = nullptr, *dW2T = nullptr, *dW3T = nullptr, *sW1T = nullptr, *sW2T = nullptr, *wbuf = nullptr;
  if (big_ws) {
    dW1T = (u16*)alloc(2ull * FDIM * CDIM * 2);
    dW2T = (u16*)alloc(2ull * FDIM * FDIM * 2);
    dW3T = (u16*)alloc(2ull * CDIM * FDIM * 2);
    sW1T = (u16*)alloc(6ull * FDIM * CDIM * 2);
    sW2T = (u16*)alloc(6ull * CDIM * FDIM * 2);
  } else {
    wbuf = (u16*)alloc((size_t)FDIM * FDIM * 2);
  }

  zero_counts<<<1, 64, 0, stream>>>(counts);
  pack_qkv<<<dim3((768 * 2304 + 255) / 256), 256, 0, stream>>>(wq, wk, wv, wqkv);
  transpose_split_k<<<dim3(2304 / 32, CDIM / 32), 256, 0, stream>>>(wqkv, WqT_hi, WqT_lo, CDIM, 2304);
  transpose_split_k<<<dim3(CDIM / 32, CDIM / 32), 256, 0, stream>>>(w_proj, WpT_hi, WpT_lo, CDIM, CDIM);
  if (big_ws) {
    transpose_cast<<<dim3(FDIM / 32, CDIM / 32, 2), 256, 0, stream>>>(deep_w1, dW1T, CDIM, FDIM);
    transpose_cast<<<dim3(FDIM / 32, FDIM / 32, 2), 256, 0, stream>>>(deep_w2, dW2T, FDIM, FDIM);
    transpose_cast<<<dim3(CDIM / 32, FDIM / 32, 2), 256, 0, stream>>>(deep_w3, dW3T, FDIM, CDIM);
    transpose_cast<<<dim3(FDIM / 32, CDIM / 32, 6), 256, 0, stream>>>(simple_w1, sW1T, CDIM, FDIM);
    transpose_cast<<<dim3(CDIM / 32, FDIM / 32, 6), 256, 0, stream>>>(simple_w2, sW2T, FDIM, CDIM);
  }
  ln1_split_k<<<TOK, 256, 0, stream>>>(xin, ln1_g, ln1_b, Hhi, Hlo);
  gemm_bf16x3<0><<<dim3(2304 / 128, TOK / 128), 256, 0, stream>>>(
      Hhi, Hlo, WqT_hi, WqT_lo, nullptr, nullptr, QKV, 2304, CDIM);
  attn_k<<<dim3(16, 12, 8), 256, 0, stream>>>(QKV, Ohi, Olo);
  gemm_bf16x3<1><<<dim3(CDIM / 128, TOK / 128), 256, 0, stream>>>(
      Ohi, Olo, WpT_hi, WpT_lo, b_proj, xin, x1, CDIM, CDIM);
  ln2_k<<<TOK, 256, 0, stream>>>(x1, ln2_g, ln2_b, h2, h2b, (float*)d_out);
  router_k<<<128, 256, 0, stream>>>(h2, w_route, b_route, w_noise, b_noise, rnoise, temp, gate);
  assign_k<<<TOK / 256, 256, 0, stream>>>(gate, counts, idxbuf);
  scan_k<<<1, 64, 0, stream>>>(counts, sstart);
  ridx_fill_k<<<(TOTAL_S + 255) / 256, 256, 0, stream>>>(counts, sstart, idxbuf, ridx_s);

  const dim3 gF(FDIM / 128, TOK / 128);
  const dim3 gC(CDIM / 128, TOK / 128);

  // deep experts (0,1): per-expert chain, T1c/T2c in big, Uc fp32 in x1
  for (int e = 0; e < 2; e++) {
    const int* cp = counts + e;
    const int* ri = idxbuf + e * TOK;
    const u16* W1;
    if (big_ws) W1 = dW1T + (size_t)e * FDIM * CDIM;
    else {
      transpose_cast<<<dim3(FDIM / 32, CDIM / 32, 1), 256, 0, stream>>>(deep_w1 + (size_t)e * CDIM * FDIM, wbuf, CDIM, FDIM);
      W1 = wbuf;
    }
    gemm_bf16_cnt<1, 1, 1><<<gF, 256, 0, stream>>>(h2b, W1, deep_b1 + e * FDIM, (void*)T1c, ri, cp, FDIM, CDIM);
    const u16* W2;
    if (big_ws) W2 = dW2T + (size_t)e * FDIM * FDIM;
    else {
      transpose_cast<<<dim3(FDIM / 32, FDIM / 32, 1), 256, 0, stream>>>(deep_w2 + (size_t)e * FDIM * FDIM, wbuf, FDIM, FDIM);
      W2 = wbuf;
    }
    gemm_bf16_cnt<1, 1, 0><<<gF, 256, 0, stream>>>(T1c, W2, deep_b2 + e * FDIM, (void*)T2c, ri, cp, FDIM, FDIM);
    const u16* W3;
    if (big_ws) W3 = dW3T + (size_t)e * CDIM * FDIM;
    else {
      transpose_cast<<<dim3(CDIM / 32, FDIM / 32, 1), 256, 0, stream>>>(deep_w3 + (size_t)e * FDIM * CDIM, wbuf, FDIM, CDIM);
      W3 = wbuf;
    }
    gemm_bf16_cnt<0, 0, 0><<<gC, 256, 0, stream>>>(T2c, W3, deep_b3 + e * CDIM, (void*)Uc, ri, cp, CDIM, FDIM);
    combine_sc_k<<<TOK, 256, 0, stream>>>(Uc, h2, gate, ri, cp, deep_ln_g + e * CDIM, deep_ln_b + e * CDIM, (float*)d_out, e);
  }

  // simple experts (2..7): consolidated (big_ws) or per-expert fallback
  if (big_ws) {
    gemm_moe1<<<dim3(FDIM / 128, ST_MAX), 256, 0, stream>>>(h2b, sW1T, simple_b1, T1g, ridx_s, sstart);
    gemm_moe2<<<dim3(CDIM / 128, ST_MAX), 256, 0, stream>>>(T1g, sW2T, simple_b2, Us, sstart);
    combine_s_k<<<TOTAL_S, 256, 0, stream>>>(Us, h2, gate, ridx_s, counts, sstart,
                                             simple_ln_g, simple_ln_b, (float*)d_out);
  } else {
    for (int e = 0; e < 6; e++) {
      const int* cp = counts + 2 + e;
      const int* ri = idxbuf + (size_t)(2 + e) * TOK;
      transpose_cast<<<dim3(FDIM / 32, CDIM / 32, 1), 256, 0, stream>>>(simple_w1 + (size_t)e * CDIM * FDIM, wbuf, CDIM, FDIM);
      gemm_bf16_cnt<1, 1, 1><<<gF, 256, 0, stream>>>(h2b, wbuf, simple_b1 + e * FDIM, (void*)T1c, ri, cp, FDIM, CDIM);
      transpose_cast<<<dim3(CDIM / 32, FDIM / 32, 1), 256, 0, stream>>>(simple_w2 + (size_t)e * FDIM * CDIM, wbuf, FDIM, CDIM);
      gemm_bf16_cnt<0, 0, 0><<<gC, 256, 0, stream>>>(T1c, wbuf, simple_b2 + e * CDIM, (void*)Uc, ri, cp, CDIM, FDIM);
      combine_sc_k<<<TOK, 256, 0, stream>>>(Uc, h2, gate, ri, cp, simple_ln_g + e * CDIM, simple_ln_b + e * CDIM, (float*)d_out, 2 + e);
    }
  }
}

// Round 9
// 1846.704 us; speedup vs baseline: 1.6366x; 1.1155x over previous
//
#include <hip/hip_runtime.h>
#include <cstdint>
#include <cstddef>
#include <math.h>

typedef uint16_t u16;
typedef __attribute__((ext_vector_type(8))) short short8;
typedef __attribute__((ext_vector_type(4))) float f32x4;

#define TOK 8192
#define CDIM 768
#define FDIM 3072
#define TOTAL_S 17152   // 16384 assignments + 6*128 pad, 128-aligned
#define ST_MAX 134      // TOTAL_S / 128

#define GLDS16(g, l) __builtin_amdgcn_global_load_lds((const __attribute__((address_space(1))) uint32_t*)(g), (__attribute__((address_space(3))) uint32_t*)(l), 16, 0, 0)

__device__ __forceinline__ u16 f2bf(float f) {
  union { float f; uint32_t u; } v; v.f = f;
  uint32_t u = v.u;
  return (u16)((u + 0x7FFFu + ((u >> 16) & 1u)) >> 16);
}

__device__ __forceinline__ float bf2f(u16 h) {
  union { uint32_t u; float f; } v; v.u = ((uint32_t)h) << 16;
  return v.f;
}

__device__ __forceinline__ void split2(float y, u16& hi, u16& lo) {
  u16 h = f2bf(y);
  hi = h;
  lo = f2bf(y - bf2f(h));
}

__device__ __forceinline__ float gelu_exact(float z) {
  return 0.5f * z * (1.0f + erff(z * 0.70710678118654752f));
}

__device__ __forceinline__ float softplus_f(float x) {
  return (x > 0.0f) ? (x + log1pf(expf(-x))) : log1pf(expf(x));
}

__device__ __forceinline__ float block_sum256(float v, float* sm) {
  #pragma unroll
  for (int m = 1; m < 64; m <<= 1) v += __shfl_xor(v, m);
  int w = threadIdx.x >> 6;
  if ((threadIdx.x & 63) == 0) sm[w] = v;
  __syncthreads();
  v = sm[0] + sm[1] + sm[2] + sm[3];
  __syncthreads();
  return v;
}

// ---------------- weight prep ----------------

__global__ __launch_bounds__(256) void pack_qkv(const float* __restrict__ wq,
    const float* __restrict__ wk, const float* __restrict__ wv, float* __restrict__ W) {
  int id = blockIdx.x * 256 + threadIdx.x;
  if (id >= 768 * 2304) return;
  int c = id / 2304, j = id - c * 2304;
  int which = j / 768, jj = j - which * 768;
  int hh = jj >> 6, d = jj & 63;
  const float* src = (which == 0) ? wq : (which == 1 ? wk : wv);
  W[id] = src[((size_t)hh * 768 + c) * 64 + d];
}

// src [K][N] fp32 -> dst [N][K] bf16 (expert weights)
__global__ __launch_bounds__(256) void transpose_cast(const float* __restrict__ src,
    u16* __restrict__ dst, int K, int N) {
  __shared__ float t[32][33];
  size_t eoff = (size_t)blockIdx.z * K * N;
  const float* S = src + eoff;
  u16* D = dst + eoff;
  int n0 = blockIdx.x * 32, k0 = blockIdx.y * 32;
  int tc = threadIdx.x & 31, tr = threadIdx.x >> 5;
  #pragma unroll
  for (int r = tr; r < 32; r += 8) t[r][tc] = S[(size_t)(k0 + r) * N + n0 + tc];
  __syncthreads();
  #pragma unroll
  for (int r = tr; r < 32; r += 8) D[(size_t)(n0 + r) * K + k0 + tc] = f2bf(t[tc][r]);
}

// src [K][N] fp32 -> dst [N][K] bf16 hi + lo (accuracy-critical weights)
__global__ __launch_bounds__(256) void transpose_split_k(const float* __restrict__ src,
    u16* __restrict__ Dhi, u16* __restrict__ Dlo, int K, int N) {
  __shared__ float t[32][33];
  int n0 = blockIdx.x * 32, k0 = blockIdx.y * 32;
  int tc = threadIdx.x & 31, tr = threadIdx.x >> 5;
  #pragma unroll
  for (int r = tr; r < 32; r += 8) t[r][tc] = src[(size_t)(k0 + r) * N + n0 + tc];
  __syncthreads();
  #pragma unroll
  for (int r = tr; r < 32; r += 8) {
    u16 hi, lo;
    split2(t[tc][r], hi, lo);
    size_t o = (size_t)(n0 + r) * K + k0 + tc;
    Dhi[o] = hi; Dlo[o] = lo;
  }
}

// ---------------- layernorms ----------------

__global__ __launch_bounds__(256) void ln1_split_k(const float* __restrict__ X,
    const float* __restrict__ g, const float* __restrict__ b,
    u16* __restrict__ Yhi, u16* __restrict__ Ylo) {
  __shared__ float sm[4];
  size_t row = blockIdx.x;
  const float* x = X + row * 768;
  int t = threadIdx.x;
  float v0 = x[t], v1 = x[t + 256], v2 = x[t + 512];
  float mean = block_sum256(v0 + v1 + v2, sm) * (1.0f / 768.0f);
  float d0 = v0 - mean, d1 = v1 - mean, d2 = v2 - mean;
  float var = block_sum256(d0 * d0 + d1 * d1 + d2 * d2, sm) * (1.0f / 768.0f);
  float rstd = 1.0f / sqrtf(var + 1e-5f);
  float y0 = d0 * rstd * g[t]       + b[t];
  float y1 = d1 * rstd * g[t + 256] + b[t + 256];
  float y2 = d2 * rstd * g[t + 512] + b[t + 512];
  u16 h, lo;
  split2(y0, h, lo); Yhi[row * 768 + t]       = h; Ylo[row * 768 + t]       = lo;
  split2(y1, h, lo); Yhi[row * 768 + t + 256] = h; Ylo[row * 768 + t + 256] = lo;
  split2(y2, h, lo); Yhi[row * 768 + t + 512] = h; Ylo[row * 768 + t + 512] = lo;
}

__global__ __launch_bounds__(256) void ln2_k(const float* __restrict__ X,
    const float* __restrict__ g, const float* __restrict__ b, float* __restrict__ H2,
    u16* __restrict__ H2b, float* __restrict__ OutInit) {
  __shared__ float sm[4];
  size_t row = blockIdx.x;
  const float* x = X + row * 768;
  int t = threadIdx.x;
  float v0 = x[t], v1 = x[t + 256], v2 = x[t + 512];
  float mean = block_sum256(v0 + v1 + v2, sm) * (1.0f / 768.0f);
  float d0 = v0 - mean, d1 = v1 - mean, d2 = v2 - mean;
  float var = block_sum256(d0 * d0 + d1 * d1 + d2 * d2, sm) * (1.0f / 768.0f);
  float rstd = 1.0f / sqrtf(var + 1e-5f);
  float y0 = d0 * rstd * g[t]       + b[t];
  float y1 = d1 * rstd * g[t + 256] + b[t + 256];
  float y2 = d2 * rstd * g[t + 512] + b[t + 512];
  float* h2r = H2 + row * 768;
  u16* hbr = H2b + row * 768;
  float* outr = OutInit + row * 768;
  h2r[t] = y0; h2r[t + 256] = y1; h2r[t + 512] = y2;
  hbr[t] = f2bf(y0); hbr[t + 256] = f2bf(y1); hbr[t + 512] = f2bf(y2);
  outr[t] = v0; outr[t + 256] = v1; outr[t + 512] = v2;
}

// ---------------- bf16x3 split MFMA GEMM (pre-router path) ----------------
// MODE 1: fp32 out + bias + residual (proj). MODE 2: attn-out — split hi/lo,
// Q/K cols -> QKh/QKl [row][col], V cols -> transposed VTh/VTl [b,h,d,s].

template<int MODE>
__global__ __launch_bounds__(256) void gemm_bf16x3(
    const u16* __restrict__ Ahi, const u16* __restrict__ Alo,
    const u16* __restrict__ Bhi, const u16* __restrict__ Blo,
    const float* __restrict__ bias, const float* __restrict__ Res,
    float* __restrict__ Cout,
    u16* __restrict__ QKh, u16* __restrict__ QKl,
    u16* __restrict__ VTh, u16* __restrict__ VTl, int N, int K) {
  __shared__ __align__(16) u16 Ah[128 * 32];
  __shared__ __align__(16) u16 Al[128 * 32];
  __shared__ __align__(16) u16 Bh[128 * 32];
  __shared__ __align__(16) u16 Bl[128 * 32];
  const int tid = threadIdx.x;
  const int l = tid & 63, w = tid >> 6;
  const int m0 = blockIdx.y << 7, n0 = blockIdx.x << 7;
  const int wr = w >> 1, wc = w & 1;
  f32x4 zero = {0.0f, 0.0f, 0.0f, 0.0f};
  f32x4 acc[4][4];
  #pragma unroll
  for (int mi = 0; mi < 4; mi++)
    #pragma unroll
    for (int ni = 0; ni < 4; ni++) acc[mi][ni] = zero;

  const int c0 = (w << 7) + l, c1 = c0 + 64;
  for (int k0 = 0; k0 < K; k0 += 32) {
    {
      size_t ao0 = (size_t)(m0 + (c0 >> 2)) * K + k0 + ((c0 & 3) << 3);
      size_t bo0 = (size_t)(n0 + (c0 >> 2)) * K + k0 + ((c0 & 3) << 3);
      GLDS16(Ahi + ao0, Ah + c0 * 8);
      GLDS16(Alo + ao0, Al + c0 * 8);
      GLDS16(Bhi + bo0, Bh + c0 * 8);
      GLDS16(Blo + bo0, Bl + c0 * 8);
      size_t ao1 = (size_t)(m0 + (c1 >> 2)) * K + k0 + ((c1 & 3) << 3);
      size_t bo1 = (size_t)(n0 + (c1 >> 2)) * K + k0 + ((c1 & 3) << 3);
      GLDS16(Ahi + ao1, Ah + c1 * 8);
      GLDS16(Alo + ao1, Al + c1 * 8);
      GLDS16(Bhi + bo1, Bh + c1 * 8);
      GLDS16(Blo + bo1, Bl + c1 * 8);
    }
    __syncthreads();
    short8 avh[4], avl[4], bvh[4], bvl[4];
    const int ra = (wr << 6) + (l & 15);
    const int rb = (wc << 6) + (l & 15);
    const int ko = (l >> 4) << 3;
    #pragma unroll
    for (int mi = 0; mi < 4; mi++) {
      avh[mi] = *(const short8*)(Ah + (ra + mi * 16) * 32 + ko);
      avl[mi] = *(const short8*)(Al + (ra + mi * 16) * 32 + ko);
    }
    #pragma unroll
    for (int ni = 0; ni < 4; ni++) {
      bvh[ni] = *(const short8*)(Bh + (rb + ni * 16) * 32 + ko);
      bvl[ni] = *(const short8*)(Bl + (rb + ni * 16) * 32 + ko);
    }
    #pragma unroll
    for (int mi = 0; mi < 4; mi++)
      #pragma unroll
      for (int ni = 0; ni < 4; ni++) {
        acc[mi][ni] = __builtin_amdgcn_mfma_f32_16x16x32_bf16(avl[mi], bvh[ni], acc[mi][ni], 0, 0, 0);
        acc[mi][ni] = __builtin_amdgcn_mfma_f32_16x16x32_bf16(avh[mi], bvl[ni], acc[mi][ni], 0, 0, 0);
        acc[mi][ni] = __builtin_amdgcn_mfma_f32_16x16x32_bf16(avh[mi], bvh[ni], acc[mi][ni], 0, 0, 0);
      }
    __syncthreads();
  }
  const int lr = (l >> 4) << 2;
  const int lc = l & 15;
  #pragma unroll
  for (int mi = 0; mi < 4; mi++) {
    #pragma unroll
    for (int ni = 0; ni < 4; ni++) {
      const int col = n0 + (wc << 6) + ni * 16 + lc;
      const float bv2 = (MODE == 1) ? bias[col] : 0.0f;
      #pragma unroll
      for (int v = 0; v < 4; v++) {
        const size_t row = (size_t)m0 + (wr << 6) + mi * 16 + lr + v;
        float val = acc[mi][ni][v] + bv2;
        if (MODE == 1) {
          val += Res[row * N + col];
          Cout[row * N + col] = val;
        } else {
          u16 hi, lo;
          split2(val, hi, lo);
          if (col < 1536) {
            size_t o = row * (size_t)N + col;
            QKh[o] = hi; QKl[o] = lo;
          } else {
            int cc = col - 1536;
            size_t o = (((size_t)(row >> 10) * 12 + (cc >> 6)) * 64 + (cc & 63)) * 1024 + (row & 1023);
            VTh[o] = hi; VTl[o] = lo;
          }
        }
      }
    }
  }
}

// ---------------- bf16x3 MFMA causal flash attention ----------------
// QK hi/lo [8192][2304] (q|k), VT hi/lo [b,h,d=64,s=1024]; out split bf16 hi/lo.
// Block = (q-tile 64, head, batch); 4 waves, wave w owns q-rows w*16..w*16+15.
// LDS: K hi/lo + VT hi/lo tiles [64][72] bf16; P overlays K region after scores.

__global__ __launch_bounds__(256, 4) void attn_mfma(
    const u16* __restrict__ QKhi, const u16* __restrict__ QKlo,
    const u16* __restrict__ VThi, const u16* __restrict__ VTlo,
    u16* __restrict__ Ohi, u16* __restrict__ Olo) {
  __shared__ __align__(16) u16 lds[4 * 64 * 72];   // 36864 B
  u16* Kh = lds;
  u16* Kl = lds + 4608;
  u16* Vh = lds + 9216;
  u16* Vl = lds + 13824;
  const int qt = (int)gridDim.x - 1 - (int)blockIdx.x;   // big blocks first
  const int hh = blockIdx.y, bb = blockIdx.z;
  const int tid = threadIdx.x, l = tid & 63, w = tid >> 6;
  const int q0 = qt * 64;
  const float scale = 0.03608439182435161f;   // 768^-0.5
  float* Pw = (float*)lds + w * 1088;          // [16][68] fp32 per wave, overlays Kh/Kl

  // Q fragments (A-layout: row=l&15 within wave tile, k=(l>>4)*8 per 32-wide kstep)
  short8 qh[2], ql[2];
  {
    size_t qoff = ((size_t)(bb * 1024 + q0 + w * 16 + (l & 15))) * 2304 + hh * 64 + ((l >> 4) << 3);
    qh[0] = *(const short8*)(QKhi + qoff);
    qh[1] = *(const short8*)(QKhi + qoff + 32);
    ql[0] = *(const short8*)(QKlo + qoff);
    ql[1] = *(const short8*)(QKlo + qoff + 32);
  }
  const int srow = tid >> 2, sseg = tid & 3;   // staging: 4 threads/row, 16 bf16 each
  f32x4 zero = {0.0f, 0.0f, 0.0f, 0.0f};
  f32x4 acco[4] = {zero, zero, zero, zero};
  float mrun[4], lrun[4] = {0.0f, 0.0f, 0.0f, 0.0f};
  #pragma unroll
  for (int v = 0; v < 4; v++) mrun[v] = -__builtin_inff();

  for (int st = 0; st <= qt; st++) {
    __syncthreads();   // A: prev tile's P/V reads done -> safe to restage
    {
      size_t kgo = ((size_t)(bb * 1024 + st * 64 + srow)) * 2304 + 768 + hh * 64 + sseg * 16;
      size_t vgo = (((size_t)(bb * 12 + hh)) * 64 + srow) * 1024 + st * 64 + sseg * 16;
      short8 k0 = *(const short8*)(QKhi + kgo), k1 = *(const short8*)(QKhi + kgo + 8);
      short8 k2 = *(const short8*)(QKlo + kgo), k3 = *(const short8*)(QKlo + kgo + 8);
      short8 v0 = *(const short8*)(VThi + vgo), v1 = *(const short8*)(VThi + vgo + 8);
      short8 v2 = *(const short8*)(VTlo + vgo), v3 = *(const short8*)(VTlo + vgo + 8);
      int lo2 = srow * 72 + sseg * 16;
      *(short8*)(Kh + lo2) = k0; *(short8*)(Kh + lo2 + 8) = k1;
      *(short8*)(Kl + lo2) = k2; *(short8*)(Kl + lo2 + 8) = k3;
      *(short8*)(Vh + lo2) = v0; *(short8*)(Vh + lo2 + 8) = v1;
      *(short8*)(Vl + lo2) = v2; *(short8*)(Vl + lo2 + 8) = v3;
    }
    __syncthreads();   // B: staging visible
    // ---- scores: wave's 16 q-rows x 64 k-cols ----
    f32x4 accs[4] = {zero, zero, zero, zero};
    #pragma unroll
    for (int ks = 0; ks < 2; ks++) {
      #pragma unroll
      for (int ni = 0; ni < 4; ni++) {
        const int rb = (ni << 4) + (l & 15);
        const int off = rb * 72 + (ks << 5) + ((l >> 4) << 3);
        short8 bh = *(const short8*)(Kh + off);
        short8 bl = *(const short8*)(Kl + off);
        accs[ni] = __builtin_amdgcn_mfma_f32_16x16x32_bf16(ql[ks], bh, accs[ni], 0, 0, 0);
        accs[ni] = __builtin_amdgcn_mfma_f32_16x16x32_bf16(qh[ks], bl, accs[ni], 0, 0, 0);
        accs[ni] = __builtin_amdgcn_mfma_f32_16x16x32_bf16(qh[ks], bh, accs[ni], 0, 0, 0);
      }
    }
    // ---- wave-local online softmax (row = (l>>4)*4+v, col = (l&15)+16*ni) ----
    const bool diag = (st == qt);
    const int r16b = (l >> 4) << 2;
    float mt[4];
    #pragma unroll
    for (int v = 0; v < 4; v++) {
      float m = -3.0e38f;
      #pragma unroll
      for (int ni = 0; ni < 4; ni++) {
        float s = accs[ni][v] * scale;
        if (diag && ((l & 15) + (ni << 4)) > (w * 16 + r16b + v)) s = -__builtin_inff();
        accs[ni][v] = s;
        m = fmaxf(m, s);
      }
      mt[v] = m;
    }
    #pragma unroll
    for (int mk = 1; mk < 16; mk <<= 1)
      #pragma unroll
      for (int v = 0; v < 4; v++) mt[v] = fmaxf(mt[v], __shfl_xor(mt[v], mk));
    float sf[4], ps[4];
    #pragma unroll
    for (int v = 0; v < 4; v++) {
      float mnew = fmaxf(mrun[v], mt[v]);
      sf[v] = expf(mrun[v] - mnew);
      mrun[v] = mnew;
      float rs = 0.0f;
      #pragma unroll
      for (int ni = 0; ni < 4; ni++) {
        float p = expf(accs[ni][v] - mnew);
        accs[ni][v] = p;
        rs += p;
      }
      ps[v] = rs;
    }
    #pragma unroll
    for (int mk = 1; mk < 16; mk <<= 1)
      #pragma unroll
      for (int v = 0; v < 4; v++) ps[v] += __shfl_xor(ps[v], mk);
    #pragma unroll
    for (int v = 0; v < 4; v++) {
      lrun[v] = lrun[v] * sf[v] + ps[v];
      #pragma unroll
      for (int dt = 0; dt < 4; dt++) acco[dt][v] *= sf[v];
    }
    __syncthreads();   // C: all waves done reading K -> safe to overlay P
    #pragma unroll
    for (int ni = 0; ni < 4; ni++)
      #pragma unroll
      for (int v = 0; v < 4; v++)
        Pw[(r16b + v) * 68 + (l & 15) + (ni << 4)] = accs[ni][v];
    // read own P slice in A-layout, split to hi/lo
    short8 pah[2], pal[2];
    #pragma unroll
    for (int ks = 0; ks < 2; ks++) {
      const float* pr = Pw + (l & 15) * 68 + (ks << 5) + ((l >> 4) << 3);
      float4 p0 = *(const float4*)pr;
      float4 p1 = *(const float4*)(pr + 4);
      float p8[8] = {p0.x, p0.y, p0.z, p0.w, p1.x, p1.y, p1.z, p1.w};
      short8 th, tl;
      #pragma unroll
      for (int j = 0; j < 8; j++) {
        u16 hi, lo;
        split2(p8[j], hi, lo);
        th[j] = (short)hi; tl[j] = (short)lo;
      }
      pah[ks] = th; pal[ks] = tl;
    }
    // ---- PV: O[16 x 64d] += P[16 x 64s] * V[64s x 64d] ----
    #pragma unroll
    for (int ks = 0; ks < 2; ks++) {
      #pragma unroll
      for (int dt = 0; dt < 4; dt++) {
        const int off = ((dt << 4) + (l & 15)) * 72 + (ks << 5) + ((l >> 4) << 3);
        short8 bh = *(const short8*)(Vh + off);
        short8 bl = *(const short8*)(Vl + off);
        acco[dt] = __builtin_amdgcn_mfma_f32_16x16x32_bf16(pal[ks], bh, acco[dt], 0, 0, 0);
        acco[dt] = __builtin_amdgcn_mfma_f32_16x16x32_bf16(pah[ks], bl, acco[dt], 0, 0, 0);
        acco[dt] = __builtin_amdgcn_mfma_f32_16x16x32_bf16(pah[ks], bh, acco[dt], 0, 0, 0);
      }
    }
  }
  // epilogue: O /= lrun, split hi/lo, store
  #pragma unroll
  for (int v = 0; v < 4; v++) {
    float inv = 1.0f / lrun[v];
    size_t row = (size_t)bb * 1024 + q0 + w * 16 + ((l >> 4) << 2) + v;
    #pragma unroll
    for (int dt = 0; dt < 4; dt++) {
      u16 hi, lo;
      split2(acco[dt][v] * inv, hi, lo);
      size_t o = row * 768 + hh * 64 + (dt << 4) + (l & 15);
      Ohi[o] = hi; Olo[o] = lo;
    }
  }
}

// ---------------- router (fp32, exact top-2 semantics) ----------------

__global__ __launch_bounds__(256) void router_k(const float* __restrict__ h2,
    const float* __restrict__ w_route, const float* __restrict__ b_route,
    const float* __restrict__ w_noise, const float* __restrict__ b_noise,
    const float* __restrict__ rnoise, const float* __restrict__ tp, float* __restrict__ gate) {
  __shared__ float Wl[6144], Wn[6144];
  int t = threadIdx.x;
  for (int i = t; i < 1536; i += 256) {
    ((float4*)Wl)[i] = ((const float4*)w_route)[i];
    ((float4*)Wn)[i] = ((const float4*)w_noise)[i];
  }
  __syncthreads();
  int tok = blockIdx.x * 64 + (t >> 2);
  int sub = t & 3;
  const float* hr = h2 + (size_t)tok * 768;
  float aL[8] = {}, aN[8] = {};
  for (int i = 0; i < 192; i++) {
    int c = sub + (i << 2);
    float hv = hr[c];
    const float* wl = &Wl[c * 8];
    const float* wn = &Wn[c * 8];
    #pragma unroll
    for (int e = 0; e < 8; e++) { aL[e] = fmaf(hv, wl[e], aL[e]); aN[e] = fmaf(hv, wn[e], aN[e]); }
  }
  #pragma unroll
  for (int e = 0; e < 8; e++) {
    aL[e] += __shfl_xor(aL[e], 1); aL[e] += __shfl_xor(aL[e], 2);
    aN[e] += __shfl_xor(aN[e], 1); aN[e] += __shfl_xor(aN[e], 2);
  }
  if (sub == 0) {
    float temp = fminf(fmaxf(tp[0], 0.5f), 2.0f);
    float noisy[8];
    #pragma unroll
    for (int e = 0; e < 8; e++) {
      float lg = aL[e] + b_route[e];
      float ns = softplus_f(aN[e] + b_noise[e]);
      noisy[e] = lg + temp * rnoise[(size_t)tok * 8 + e] * ns;
    }
    int i1 = 0; float v1 = noisy[0];
    #pragma unroll
    for (int e = 1; e < 8; e++) if (noisy[e] > v1) { v1 = noisy[e]; i1 = e; }
    int i2 = -1; float v2 = 0.0f;
    #pragma unroll
    for (int e = 0; e < 8; e++) {
      if (e == i1) continue;
      if (i2 < 0 || noisy[e] > v2) { v2 = noisy[e]; i2 = e; }
    }
    float e2 = expf(v2 - v1);
    float denom = 1.0f + e2;
    float* gr = gate + (size_t)tok * 8;
    #pragma unroll
    for (int e = 0; e < 8; e++) gr[e] = 0.0f;
    gr[i1] = 1.0f / denom;
    gr[i2] = e2 / denom;
  }
}

// ---------------- routing compaction ----------------

__global__ void zero_counts(int* counts) {
  if (threadIdx.x < 8) counts[threadIdx.x] = 0;
}

__global__ __launch_bounds__(256) void assign_k(const float* __restrict__ gate,
    int* __restrict__ counts, int* __restrict__ idxbuf) {
  int tok = blockIdx.x * 256 + threadIdx.x;
  const float* gr = gate + (size_t)tok * 8;
  #pragma unroll
  for (int e = 0; e < 8; e++) {
    if (gr[e] > 0.0f) {
      int s = atomicAdd(&counts[e], 1);
      idxbuf[e * TOK + s] = tok;
    }
  }
}

// 128-aligned segment offsets over the 6 simple experts
__global__ void scan_k(const int* __restrict__ counts, int* __restrict__ sstart) {
  if (threadIdx.x == 0) {
    int acc = 0;
    for (int j = 0; j < 6; j++) {
      sstart[j] = acc;
      acc += (counts[2 + j] + 127) & ~127;
    }
    sstart[6] = acc;
  }
}

__global__ __launch_bounds__(256) void ridx_fill_k(const int* __restrict__ counts,
    const int* __restrict__ sstart, const int* __restrict__ idxbuf, int* __restrict__ ridx_s) {
  int p = blockIdx.x * 256 + threadIdx.x;
  if (p >= sstart[6]) return;
  int j = 0;
  #pragma unroll
  for (int t = 1; t < 6; t++) if (p >= sstart[t]) j = t;
  int local = p - sstart[j];
  if (local >= counts[2 + j]) local = 0;   // pad row -> clamp (skipped at combine)
  ridx_s[p] = idxbuf[(2 + j) * TOK + local];
}

// ---------------- bf16 MFMA GEMM over compacted rows (deep experts / fallback) --------

template<int GELU_OUT, int BF16_OUT, int GATHER>
__global__ __launch_bounds__(256) void gemm_bf16_cnt(const u16* __restrict__ A,
    const u16* __restrict__ BT, const float* __restrict__ bias, void* __restrict__ Cout,
    const int* __restrict__ ridx, const int* __restrict__ cntp, int N, int K) {
  const int cnt = *cntp;
  const int mtiles = (cnt + 127) >> 7;
  if ((int)blockIdx.y >= mtiles) return;
  __shared__ __align__(16) u16 As[128 * 32];
  __shared__ __align__(16) u16 Bs[128 * 32];
  const int tid = threadIdx.x;
  const int l = tid & 63, w = tid >> 6;
  const int m0 = blockIdx.y << 7, n0 = blockIdx.x << 7;
  const int wr = w >> 1, wc = w & 1;
  const int ca = (w << 7) + l, cb = ca + 64;
  const int ra_ = m0 + (ca >> 2), rb_ = m0 + (cb >> 2);
  size_t ga, gb;
  if (GATHER) {
    ga = (size_t)ridx[ra_ < cnt ? ra_ : 0];
    gb = (size_t)ridx[rb_ < cnt ? rb_ : 0];
  } else {
    ga = (size_t)ra_; gb = (size_t)rb_;
  }
  f32x4 zero = {0.0f, 0.0f, 0.0f, 0.0f};
  f32x4 acc[4][4];
  #pragma unroll
  for (int mi = 0; mi < 4; mi++)
    #pragma unroll
    for (int ni = 0; ni < 4; ni++) acc[mi][ni] = zero;

  for (int k0 = 0; k0 < K; k0 += 32) {
    GLDS16(A + ga * K + k0 + ((ca & 3) << 3), As + ca * 8);
    GLDS16(BT + (size_t)(n0 + (ca >> 2)) * K + k0 + ((ca & 3) << 3), Bs + ca * 8);
    GLDS16(A + gb * K + k0 + ((cb & 3) << 3), As + cb * 8);
    GLDS16(BT + (size_t)(n0 + (cb >> 2)) * K + k0 + ((cb & 3) << 3), Bs + cb * 8);
    __syncthreads();
    short8 av[4], bv[4];
    const int ra = (wr << 6) + (l & 15);
    const int rb = (wc << 6) + (l & 15);
    const int ko = (l >> 4) << 3;
    #pragma unroll
    for (int mi = 0; mi < 4; mi++) av[mi] = *(const short8*)(As + (ra + mi * 16) * 32 + ko);
    #pragma unroll
    for (int ni = 0; ni < 4; ni++) bv[ni] = *(const short8*)(Bs + (rb + ni * 16) * 32 + ko);
    #pragma unroll
    for (int mi = 0; mi < 4; mi++)
      #pragma unroll
      for (int ni = 0; ni < 4; ni++)
        acc[mi][ni] = __builtin_amdgcn_mfma_f32_16x16x32_bf16(av[mi], bv[ni], acc[mi][ni], 0, 0, 0);
    __syncthreads();
  }
  const int lr = (l >> 4) << 2;
  const int lc = l & 15;
  #pragma unroll
  for (int mi = 0; mi < 4; mi++) {
    #pragma unroll
    for (int ni = 0; ni < 4; ni++) {
      const int col = n0 + (wc << 6) + ni * 16 + lc;
      const float bv2 = bias ? bias[col] : 0.0f;
      #pragma unroll
      for (int v = 0; v < 4; v++) {
        const size_t row = (size_t)m0 + (wr << 6) + mi * 16 + lr + v;
        float val = acc[mi][ni][v] + bv2;
        if (GELU_OUT) val = gelu_exact(val);
        if (BF16_OUT) ((u16*)Cout)[row * N + col] = f2bf(val);
        else          ((float*)Cout)[row * N + col] = val;
      }
    }
  }
}

// ---------------- consolidated simple-expert GEMMs ----------------

__global__ __launch_bounds__(256) void gemm_moe1(const u16* __restrict__ A,
    const u16* __restrict__ W1T, const float* __restrict__ b1, u16* __restrict__ T1g,
    const int* __restrict__ ridx_s, const int* __restrict__ sstart) {
  const int m0 = (int)blockIdx.y << 7;
  if (m0 >= sstart[6]) return;
  int j = 0;
  #pragma unroll
  for (int t = 1; t < 6; t++) if (m0 >= sstart[t]) j = t;
  const u16* BT = W1T + (size_t)j * FDIM * CDIM;
  const float* bias = b1 + (size_t)j * FDIM;
  const int N = FDIM, K = CDIM;
  __shared__ __align__(16) u16 As[128 * 32];
  __shared__ __align__(16) u16 Bs[128 * 32];
  const int tid = threadIdx.x;
  const int l = tid & 63, w = tid >> 6;
  const int n0 = blockIdx.x << 7;
  const int wr = w >> 1, wc = w & 1;
  const int ca = (w << 7) + l, cb = ca + 64;
  size_t ga = (size_t)ridx_s[m0 + (ca >> 2)];
  size_t gb = (size_t)ridx_s[m0 + (cb >> 2)];
  f32x4 zero = {0.0f, 0.0f, 0.0f, 0.0f};
  f32x4 acc[4][4];
  #pragma unroll
  for (int mi = 0; mi < 4; mi++)
    #pragma unroll
    for (int ni = 0; ni < 4; ni++) acc[mi][ni] = zero;
  for (int k0 = 0; k0 < K; k0 += 32) {
    GLDS16(A + ga * K + k0 + ((ca & 3) << 3), As + ca * 8);
    GLDS16(BT + (size_t)(n0 + (ca >> 2)) * K + k0 + ((ca & 3) << 3), Bs + ca * 8);
    GLDS16(A + gb * K + k0 + ((cb & 3) << 3), As + cb * 8);
    GLDS16(BT + (size_t)(n0 + (cb >> 2)) * K + k0 + ((cb & 3) << 3), Bs + cb * 8);
    __syncthreads();
    short8 av[4], bv[4];
    const int ra = (wr << 6) + (l & 15);
    const int rb = (wc << 6) + (l & 15);
    const int ko = (l >> 4) << 3;
    #pragma unroll
    for (int mi = 0; mi < 4; mi++) av[mi] = *(const short8*)(As + (ra + mi * 16) * 32 + ko);
    #pragma unroll
    for (int ni = 0; ni < 4; ni++) bv[ni] = *(const short8*)(Bs + (rb + ni * 16) * 32 + ko);
    #pragma unroll
    for (int mi = 0; mi < 4; mi++)
      #pragma unroll
      for (int ni = 0; ni < 4; ni++)
        acc[mi][ni] = __builtin_amdgcn_mfma_f32_16x16x32_bf16(av[mi], bv[ni], acc[mi][ni], 0, 0, 0);
    __syncthreads();
  }
  const int lr = (l >> 4) << 2;
  const int lc = l & 15;
  #pragma unroll
  for (int mi = 0; mi < 4; mi++)
    #pragma unroll
    for (int ni = 0; ni < 4; ni++) {
      const int col = n0 + (wc << 6) + ni * 16 + lc;
      const float bv2 = bias[col];
      #pragma unroll
      for (int v = 0; v < 4; v++) {
        const size_t row = (size_t)m0 + (wr << 6) + mi * 16 + lr + v;
        T1g[row * N + col] = f2bf(gelu_exact(acc[mi][ni][v] + bv2));
      }
    }
}

__global__ __launch_bounds__(256) void gemm_moe2(const u16* __restrict__ A,
    const u16* __restrict__ W2T, const float* __restrict__ b2, u16* __restrict__ Us,
    const int* __restrict__ sstart) {
  const int m0 = (int)blockIdx.y << 7;
  if (m0 >= sstart[6]) return;
  int j = 0;
  #pragma unroll
  for (int t = 1; t < 6; t++) if (m0 >= sstart[t]) j = t;
  const u16* BT = W2T + (size_t)j * CDIM * FDIM;
  const float* bias = b2 + (size_t)j * CDIM;
  const int N = CDIM, K = FDIM;
  __shared__ __align__(16) u16 As[128 * 32];
  __shared__ __align__(16) u16 Bs[128 * 32];
  const int tid = threadIdx.x;
  const int l = tid & 63, w = tid >> 6;
  const int n0 = blockIdx.x << 7;
  const int wr = w >> 1, wc = w & 1;
  const int ca = (w << 7) + l, cb = ca + 64;
  size_t ga = (size_t)(m0 + (ca >> 2));
  size_t gb = (size_t)(m0 + (cb >> 2));
  f32x4 zero = {0.0f, 0.0f, 0.0f, 0.0f};
  f32x4 acc[4][4];
  #pragma unroll
  for (int mi = 0; mi < 4; mi++)
    #pragma unroll
    for (int ni = 0; ni < 4; ni++) acc[mi][ni] = zero;
  for (int k0 = 0; k0 < K; k0 += 32) {
    GLDS16(A + ga * K + k0 + ((ca & 3) << 3), As + ca * 8);
    GLDS16(BT + (size_t)(n0 + (ca >> 2)) * K + k0 + ((ca & 3) << 3), Bs + ca * 8);
    GLDS16(A + gb * K + k0 + ((cb & 3) << 3), As + cb * 8);
    GLDS16(BT + (size_t)(n0 + (cb >> 2)) * K + k0 + ((cb & 3) << 3), Bs + cb * 8);
    __syncthreads();
    short8 av[4], bv[4];
    const int ra = (wr << 6) + (l & 15);
    const int rb = (wc << 6) + (l & 15);
    const int ko = (l >> 4) << 3;
    #pragma unroll
    for (int mi = 0; mi < 4; mi++) av[mi] = *(const short8*)(As + (ra + mi * 16) * 32 + ko);
    #pragma unroll
    for (int ni = 0; ni < 4; ni++) bv[ni] = *(const short8*)(Bs + (rb + ni * 16) * 32 + ko);
    #pragma unroll
    for (int mi = 0; mi < 4; mi++)
      #pragma unroll
      for (int ni = 0; ni < 4; ni++)
        acc[mi][ni] = __builtin_amdgcn_mfma_f32_16x16x32_bf16(av[mi], bv[ni], acc[mi][ni], 0, 0, 0);
    __syncthreads();
  }
  const int lr = (l >> 4) << 2;
  const int lc = l & 15;
  #pragma unroll
  for (int mi = 0; mi < 4; mi++)
    #pragma unroll
    for (int ni = 0; ni < 4; ni++) {
      const int col = n0 + (wc << 6) + ni * 16 + lc;
      const float bv2 = bias[col];
      #pragma unroll
      for (int v = 0; v < 4; v++) {
        const size_t row = (size_t)m0 + (wr << 6) + mi * 16 + lr + v;
        Us[row * N + col] = f2bf(acc[mi][ni][v] + bv2);
      }
    }
}

// ---------------- residual-LN + gated scatter-accumulate ----------------

__global__ __launch_bounds__(256) void combine_sc_k(const float* __restrict__ U,
    const float* __restrict__ H2, const float* __restrict__ gate,
    const int* __restrict__ ridx, const int* __restrict__ cntp,
    const float* __restrict__ g, const float* __restrict__ b,
    float* __restrict__ Out, int eidx) {
  __shared__ float sm[4];
  int pos = blockIdx.x;
  if (pos >= *cntp) return;
  size_t tok = (size_t)ridx[pos];
  float gt = gate[tok * 8 + eidx];
  int t = threadIdx.x;
  const float* h = H2 + tok * 768;
  const float* u = U + (size_t)pos * 768;
  float v0 = h[t] + u[t], v1 = h[t + 256] + u[t + 256], v2 = h[t + 512] + u[t + 512];
  float mean = block_sum256(v0 + v1 + v2, sm) * (1.0f / 768.0f);
  float d0 = v0 - mean, d1 = v1 - mean, d2 = v2 - mean;
  float var = block_sum256(d0 * d0 + d1 * d1 + d2 * d2, sm) * (1.0f / 768.0f);
  float rstd = 1.0f / sqrtf(var + 1e-5f);
  float* o = Out + tok * 768;
  o[t]       += gt * (d0 * rstd * g[t]       + b[t]);
  o[t + 256] += gt * (d1 * rstd * g[t + 256] + b[t + 256]);
  o[t + 512] += gt * (d2 * rstd * g[t + 512] + b[t + 512]);
}

__global__ __launch_bounds__(256) void combine_s_k(const u16* __restrict__ Us,
    const float* __restrict__ H2, const float* __restrict__ gate,
    const int* __restrict__ ridx_s, const int* __restrict__ counts, const int* __restrict__ sstart,
    const float* __restrict__ sg, const float* __restrict__ sb, float* __restrict__ Out) {
  __shared__ float sm[4];
  int p = blockIdx.x;
  if (p >= sstart[6]) return;
  int j = 0;
  #pragma unroll
  for (int t2 = 1; t2 < 6; t2++) if (p >= sstart[t2]) j = t2;
  if (p - sstart[j] >= counts[2 + j]) return;   // pad row
  size_t tok = (size_t)ridx_s[p];
  float gt = gate[tok * 8 + 2 + j];
  int t = threadIdx.x;
  const float* h = H2 + tok * 768;
  const u16* u = Us + (size_t)p * 768;
  const float* g = sg + (size_t)j * 768;
  const float* b = sb + (size_t)j * 768;
  float v0 = h[t] + bf2f(u[t]);
  float v1 = h[t + 256] + bf2f(u[t + 256]);
  float v2 = h[t + 512] + bf2f(u[t + 512]);
  float mean = block_sum256(v0 + v1 + v2, sm) * (1.0f / 768.0f);
  float d0 = v0 - mean, d1 = v1 - mean, d2 = v2 - mean;
  float var = block_sum256(d0 * d0 + d1 * d1 + d2 * d2, sm) * (1.0f / 768.0f);
  float rstd = 1.0f / sqrtf(var + 1e-5f);
  float* o = Out + tok * 768;
  o[t]       += gt * (d0 * rstd * g[t]       + b[t]);
  o[t + 256] += gt * (d1 * rstd * g[t + 256] + b[t + 256]);
  o[t + 512] += gt * (d2 * rstd * g[t + 512] + b[t + 512]);
}

// ---------------- launch ----------------

extern "C" void kernel_launch(void* const* d_in, const int* in_sizes, int n_in,
                              void* d_out, int out_size, void* d_ws, size_t ws_size,
                              hipStream_t stream) {
  (void)in_sizes; (void)n_in; (void)out_size;
  const float* xin       = (const float*)d_in[0];
  const float* rnoise    = (const float*)d_in[1];
  const float* wq        = (const float*)d_in[2];
  const float* wk        = (const float*)d_in[3];
  const float* wv        = (const float*)d_in[4];
  const float* w_proj    = (const float*)d_in[5];
  const float* b_proj    = (const float*)d_in[6];
  const float* ln1_g     = (const float*)d_in[7];
  const float* ln1_b     = (const float*)d_in[8];
  const float* ln2_g     = (const float*)d_in[9];
  const float* ln2_b     = (const float*)d_in[10];
  const float* w_route   = (const float*)d_in[11];
  const float* b_route   = (const float*)d_in[12];
  const float* w_noise   = (const float*)d_in[13];
  const float* b_noise   = (const float*)d_in[14];
  const float* temp      = (const float*)d_in[15];
  const float* deep_w1   = (const float*)d_in[16];
  const float* deep_b1   = (const float*)d_in[17];
  const float* deep_w2   = (const float*)d_in[18];
  const float* deep_b2   = (const float*)d_in[19];
  const float* deep_w3   = (const float*)d_in[20];
  const float* deep_b3   = (const float*)d_in[21];
  const float* deep_ln_g = (const float*)d_in[22];
  const float* deep_ln_b = (const float*)d_in[23];
  const float* simple_w1 = (const float*)d_in[24];
  const float* simple_b1 = (const float*)d_in[25];
  const float* simple_w2 = (const float*)d_in[26];
  const float* simple_b2 = (const float*)d_in[27];
  const float* simple_ln_g = (const float*)d_in[28];
  const float* simple_ln_b = (const float*)d_in[29];

  char* ws = (char*)d_ws;
  size_t off = 0;
  auto alloc = [&](size_t bytes) -> char* {
    char* p = ws + off;
    off += (bytes + 255) & ~(size_t)255;
    return p;
  };
  float* gate = (float*)alloc((size_t)TOK * 8 * 4);
  int*   counts = (int*)alloc(8 * 4);
  int*   sstart = (int*)alloc(8 * 4);
  int*   idxbuf = (int*)alloc(8ull * TOK * 4);
  int*   ridx_s = (int*)alloc((size_t)TOTAL_S * 4);
  float* h2   = (float*)alloc((size_t)TOK * CDIM * 4);
  u16*   h2b  = (u16*)  alloc((size_t)TOK * CDIM * 2);
  float* x1   = (float*)alloc((size_t)TOK * CDIM * 4);   // attn: VT hi/lo; then proj out; then deep Uc
  size_t big_a = (size_t)TOK * 2304 * 2 * 2 + (size_t)TOK * CDIM * 2 * 2;   // QKhi|QKlo|Ohi|Olo 100.7MB
  size_t big_b = (size_t)TOTAL_S * FDIM * 2;                                // simple T1g 105.4MB
  char*  big  = alloc(big_a > big_b ? big_a : big_b);
  float* wqkv = (float*)big;                    // prep-phase alias (dead before QK writes)
  u16*   QKhi = (u16*)big;
  u16*   QKlo = QKhi + (size_t)TOK * 2304;
  u16*   Ohi  = (u16*)(big + (size_t)TOK * 2304 * 2 * 2);
  u16*   Olo  = Ohi + (size_t)TOK * CDIM;
  u16*   VThi = (u16*)x1;                       // 96*64*1024 = TOK*CDIM exactly
  u16*   VTlo = VThi + (size_t)TOK * CDIM;
  u16*   T1c  = (u16*)big;
  u16*   T2c  = (u16*)(big + (size_t)TOK * FDIM * 2);
  u16*   T1g  = (u16*)big;
  float* Uc   = x1;
  u16* WqT_hi = (u16*)alloc(2304ull * CDIM * 2);
  u16* WqT_lo = (u16*)alloc(2304ull * CDIM * 2);
  u16* WpT_hi = (u16*)alloc((size_t)CDIM * CDIM * 2);
  u16* WpT_lo = (u16*)alloc((size_t)CDIM * CDIM * 2);
  u16* Hhi    = (u16*)alloc((size_t)TOK * CDIM * 2);
  u16* Hlo    = (u16*)alloc((size_t)TOK * CDIM * 2);
  u16* Us = WqT_hi;   // simple stage-2 out (26.3MB) aliases WqT/WpT/H (dead after proj)

  size_t wsz_all = (2ull * FDIM * CDIM + 2ull * FDIM * FDIM + 2ull * CDIM * FDIM +
                    6ull * FDIM * CDIM + 6ull * CDIM * FDIM) * 2 + 16 * 256;
  bool big_ws = ws_size >= off + wsz_all;
  u16 *dW1T = nullptr, *dW2T = nullptr, *dW3T = nullptr, *sW1T = nullptr, *sW2T = nullptr, *wbuf = nullptr;
  if (big_ws) {
    dW1T = (u16*)alloc(2ull * FDIM * CDIM * 2);
    dW2T = (u16*)alloc(2ull * FDIM * FDIM * 2);
    dW3T = (u16*)alloc(2ull * CDIM * FDIM * 2);
    sW1T = (u16*)alloc(6ull * FDIM * CDIM * 2);
    sW2T = (u16*)alloc(6ull * CDIM * FDIM * 2);
  } else {
    wbuf = (u16*)alloc((size_t)FDIM * FDIM * 2);
  }

  zero_counts<<<1, 64, 0, stream>>>(counts);
  pack_qkv<<<dim3((768 * 2304 + 255) / 256), 256, 0, stream>>>(wq, wk, wv, wqkv);
  transpose_split_k<<<dim3(2304 / 32, CDIM / 32), 256, 0, stream>>>(wqkv, WqT_hi, WqT_lo, CDIM, 2304);
  transpose_split_k<<<dim3(CDIM / 32, CDIM / 32), 256, 0, stream>>>(w_proj, WpT_hi, WpT_lo, CDIM, CDIM);
  if (big_ws) {
    transpose_cast<<<dim3(FDIM / 32, CDIM / 32, 2), 256, 0, stream>>>(deep_w1, dW1T, CDIM, FDIM);
    transpose_cast<<<dim3(FDIM / 32, FDIM / 32, 2), 256, 0, stream>>>(deep_w2, dW2T, FDIM, FDIM);
    transpose_cast<<<dim3(CDIM / 32, FDIM / 32, 2), 256, 0, stream>>>(deep_w3, dW3T, FDIM, CDIM);
    transpose_cast<<<dim3(FDIM / 32, CDIM / 32, 6), 256, 0, stream>>>(simple_w1, sW1T, CDIM, FDIM);
    transpose_cast<<<dim3(CDIM / 32, FDIM / 32, 6), 256, 0, stream>>>(simple_w2, sW2T, FDIM, CDIM);
  }
  ln1_split_k<<<TOK, 256, 0, stream>>>(xin, ln1_g, ln1_b, Hhi, Hlo);
  gemm_bf16x3<2><<<dim3(2304 / 128, TOK / 128), 256, 0, stream>>>(
      Hhi, Hlo, WqT_hi, WqT_lo, nullptr, nullptr, nullptr, QKhi, QKlo, VThi, VTlo, 2304, CDIM);
  attn_mfma<<<dim3(16, 12, 8), 256, 0, stream>>>(QKhi, QKlo, VThi, VTlo, Ohi, Olo);
  gemm_bf16x3<1><<<dim3(CDIM / 128, TOK / 128), 256, 0, stream>>>(
      Ohi, Olo, WpT_hi, WpT_lo, b_proj, xin, x1, nullptr, nullptr, nullptr, nullptr, CDIM, CDIM);
  ln2_k<<<TOK, 256, 0, stream>>>(x1, ln2_g, ln2_b, h2, h2b, (float*)d_out);
  router_k<<<128, 256, 0, stream>>>(h2, w_route, b_route, w_noise, b_noise, rnoise, temp, gate);
  assign_k<<<TOK / 256, 256, 0, stream>>>(gate, counts, idxbuf);
  scan_k<<<1, 64, 0, stream>>>(counts, sstart);
  ridx_fill_k<<<(TOTAL_S + 255) / 256, 256, 0, stream>>>(counts, sstart, idxbuf, ridx_s);

  const dim3 gF(FDIM / 128, TOK / 128);
  const dim3 gC(CDIM / 128, TOK / 128);

  for (int e = 0; e < 2; e++) {
    const int* cp = counts + e;
    const int* ri = idxbuf + e * TOK;
    const u16* W1;
    if (big_ws) W1 = dW1T + (size_t)e * FDIM * CDIM;
    else {
      transpose_cast<<<dim3(FDIM / 32, CDIM / 32, 1), 256, 0, stream>>>(deep_w1 + (size_t)e * CDIM * FDIM, wbuf, CDIM, FDIM);
      W1 = wbuf;
    }
    gemm_bf16_cnt<1, 1, 1><<<gF, 256, 0, stream>>>(h2b, W1, deep_b1 + e * FDIM, (void*)T1c, ri, cp, FDIM, CDIM);
    const u16* W2;
    if (big_ws) W2 = dW2T + (size_t)e * FDIM * FDIM;
    else {
      transpose_cast<<<dim3(FDIM / 32, FDIM / 32, 1), 256, 0, stream>>>(deep_w2 + (size_t)e * FDIM * FDIM, wbuf, FDIM, FDIM);
      W2 = wbuf;
    }
    gemm_bf16_cnt<1, 1, 0><<<gF, 256, 0, stream>>>(T1c, W2, deep_b2 + e * FDIM, (void*)T2c, ri, cp, FDIM, FDIM);
    const u16* W3;
    if (big_ws) W3 = dW3T + (size_t)e * CDIM * FDIM;
    else {
      transpose_cast<<<dim3(CDIM / 32, FDIM / 32, 1), 256, 0, stream>>>(deep_w3 + (size_t)e * FDIM * CDIM, wbuf, FDIM, CDIM);
      W3 = wbuf;
    }
    gemm_bf16_cnt<0, 0, 0><<<gC, 256, 0, stream>>>(T2c, W3, deep_b3 + e * CDIM, (void*)Uc, ri, cp, CDIM, FDIM);
    combine_sc_k<<<TOK, 256, 0, stream>>>(Uc, h2, gate, ri, cp, deep_ln_g + e * CDIM, deep_ln_b + e * CDIM, (float*)d_out, e);
  }

  if (big_ws) {
    gemm_moe1<<<dim3(FDIM / 128, ST_MAX), 256, 0, stream>>>(h2b, sW1T, simple_b1, T1g, ridx_s, sstart);
    gemm_moe2<<<dim3(CDIM / 128, ST_MAX), 256, 0, stream>>>(T1g, sW2T, simple_b2, Us, sstart);
    combine_s_k<<<TOTAL_S, 256, 0, stream>>>(Us, h2, gate, ridx_s, counts, sstart,
                                             simple_ln_g, simple_ln_b, (float*)d_out);
  } else {
    for (int e = 0; e < 6; e++) {
      const int* cp = counts + 2 + e;
      const int* ri = idxbuf + (size_t)(2 + e) * TOK;
      transpose_cast<<<dim3(FDIM / 32, CDIM / 32, 1), 256, 0, stream>>>(simple_w1 + (size_t)e * CDIM * FDIM, wbuf, CDIM, FDIM);
      gemm_bf16_cnt<1, 1, 1><<<gF, 256, 0, stream>>>(h2b, wbuf, simple_b1 + e * FDIM, (void*)T1c, ri, cp, FDIM, CDIM);
      transpose_cast<<<dim3(CDIM / 32, FDIM / 32, 1), 256, 0, stream>>>(simple_w2 + (size_t)e * FDIM * CDIM, wbuf, FDIM, CDIM);
      gemm_bf16_cnt<0, 0, 0><<<gC, 256, 0, stream>>>(T1c, wbuf, simple_b2 + e * CDIM, (void*)Uc, ri, cp, CDIM, FDIM);
      combine_sc_k<<<TOK, 256, 0, stream>>>(Uc, h2, gate, ri, cp, simple_ln_g + e * CDIM, simple_ln_b + e * CDIM, (float*)d_out, 2 + e);
    }
  }
}